// Round 12
// baseline (2671.642 us; speedup 1.0000x reference)
//
#include <hip/hip_runtime.h>

// ContinuousLatticeGPT: B=32 S=1024 D=512 H=8 NL=6 DFF=2048 C=128 K=8
// bf16 MFMA; fp32 residual stream with deferred (bf16 delta) residual adds.
// GEMM assignment (solved from r5-r11 additive ledger, exact to ~us):
//  - FF1 / Wo / FF2 / qk_proj -> ring-3 + register-frag prefetch (48KB LDS).
//  - v_proj -> 2-buffer 32KB (r11: operand-SWAPPED MFMA body under ring-3's
//    LOADF/sched_barrier structure costs +39us; normal-order bodies gain).
//  - gelu epilogue (FF1): log2e folded into sigmoid-gelu constants -> raw
//    v_exp_f32 + v_rcp_f32 (r11: -96us total, VALUBusy 48->38%).
// All GEMMs: lane-adjacent 64B-row staging + chunk^=((row>>1)&3) swizzle
// (TA-coalesced AND bank-conflict-free).
// attn: swapped-QK (mfma(K,Q)) with in-register P transpose via cvt_pk+permlane;
// exp2-folded softmax (log2e in q-scale & bias). No setprio (r9: +12us).
// Delta routing: Wo-delta -> vtb (dead V^T);  FF2-delta -> hbuf (dead FF1 input,
// disjoint from qf). AdaLN/fln read delta from those and may write h over hbuf.
// ws layout (bytes): unchanged. REQ 242,814,976 B

typedef short s8v __attribute__((ext_vector_type(8)));
typedef float f4v __attribute__((ext_vector_type(4)));
typedef unsigned u2v __attribute__((ext_vector_type(2)));
typedef unsigned u4v __attribute__((ext_vector_type(4)));

#define Q_SCALE 0.18033688011112042f  // 0.125 * log2(e)
#define LOG2E   1.4426950408889634f

static __device__ __forceinline__ short f2bf(float f) {
  union { float f; unsigned u; } v; v.f = f;
  unsigned r = v.u + 0x7fffu + ((v.u >> 16) & 1u);
  return (short)(r >> 16);
}
static __device__ __forceinline__ float bf2f(unsigned short s) {
  union { unsigned u; float f; } v; v.u = ((unsigned)s) << 16;
  return v.f;
}
static __device__ __forceinline__ unsigned cvtpk(float lo, float hi) {
  unsigned r;
  asm("v_cvt_pk_bf16_f32 %0, %1, %2" : "=v"(r) : "v"(lo), "v"(hi));
  return r;
}
static __device__ __forceinline__ float fexp2(float x) {  // 2^x, single v_exp_f32
  float r;
  asm("v_exp_f32 %0, %1" : "=v"(r) : "v"(x));
  return r;
}
static __device__ __forceinline__ float frcp(float x) {  // ~1ulp reciprocal
  float r;
  asm("v_rcp_f32 %0, %1" : "=v"(r) : "v"(x));
  return r;
}
static __device__ __forceinline__ void gl_lds16(const short* g, short* l) {
  __builtin_amdgcn_global_load_lds(
      (const __attribute__((address_space(1))) unsigned int*)g,
      (__attribute__((address_space(3))) unsigned int*)l, 16, 0, 0);
}

// ---------------- prep kernels ----------------
__global__ void transpose_all_k(const float* __restrict__ Wq, const float* __restrict__ Wk,
                                const float* __restrict__ Wv, const float* __restrict__ Wo,
                                const float* __restrict__ W1, const float* __restrict__ W2,
                                int l, short* __restrict__ wbf) {
  int id = blockIdx.x;
  const float* in; short* out; int K, N, tx, ty;
  if (id < 1024) {
    int m = id >> 8, t = id & 255;
    in = (m == 0 ? Wq : m == 1 ? Wk : m == 2 ? Wv : Wo) + (size_t)l * 262144;
    out = wbf + (size_t)m * 262144;
    K = 512; N = 512; tx = t & 15; ty = t >> 4;
  } else if (id < 2048) {
    int t = id - 1024;
    in = W1 + (size_t)l * 1048576; out = wbf + 1048576;
    K = 512; N = 2048; tx = t & 63; ty = t >> 6;
  } else {
    int t = id - 2048;
    in = W2 + (size_t)l * 1048576; out = wbf + 2097152;
    K = 2048; N = 512; tx = t & 15; ty = t >> 4;
  }
  __shared__ float tb[32][33];
  int n0 = tx * 32, k0 = ty * 32;
  int cx = threadIdx.x & 31, cy = threadIdx.x >> 5;
#pragma unroll
  for (int r = 0; r < 4; r++)
    tb[cy + r * 8][cx] = in[(size_t)(k0 + cy + r * 8) * N + n0 + cx];
  __syncthreads();
#pragma unroll
  for (int r = 0; r < 4; r++)
    out[(size_t)(n0 + cy + r * 8) * K + k0 + cx] = f2bf(tb[cx][cy + r * 8]);
}

// f32 -> bf16 copy of attn_bias, folding log2(e) for the exp2 softmax
__global__ void bias_cvt_k(const float* __restrict__ in, short* __restrict__ out) {
  int i = blockIdx.x * 256 + threadIdx.x;  // float4 index; grid covers 8M floats
  float4 v = ((const float4*)in)[i];
  ushort4 o;
  o.x = (unsigned short)f2bf(v.x * LOG2E);
  o.y = (unsigned short)f2bf(v.y * LOG2E);
  o.z = (unsigned short)f2bf(v.z * LOG2E);
  o.w = (unsigned short)f2bf(v.w * LOG2E);
  ((ushort4*)out)[i] = o;
}

__global__ void hwt_k(const float* __restrict__ hW, short* __restrict__ hWT) {
  int i = blockIdx.x * 256 + threadIdx.x;
  int n = i >> 9, k = i & 511;
  hWT[i] = (n < 24) ? f2bf(hW[(size_t)k * 24 + n]) : (short)0;
}

__global__ void concat_qkvb_k(const float* bq, const float* bk, const float* bv, float* out) {
  int l = blockIdx.x;
  for (int i = threadIdx.x; i < 1536; i += 256) {
    float v = (i < 512) ? bq[l * 512 + i] * Q_SCALE  // fold 1/sqrt(HD)*log2e into q bias
            : (i < 1024 ? bk[l * 512 + i - 512] : bv[l * 512 + i - 1024]);
    out[l * 1536 + i] = v;
  }
}

__global__ void cond_proj_k(const float* __restrict__ cond,
                            const float* __restrict__ a1W, const float* __restrict__ a1b,
                            const float* __restrict__ a2W, const float* __restrict__ a2b,
                            float* __restrict__ ss) {
  int lw = blockIdx.y, which = lw & 1, l = lw >> 1;
  const float* W = (which ? a2W : a1W) + (size_t)l * 128 * 1024;
  const float* bb = (which ? a2b : a1b) + (size_t)l * 1024;
  __shared__ float cs[32 * 128];
  for (int i = threadIdx.x; i < 32 * 128; i += 256) cs[i] = cond[i];
  __syncthreads();
  int n = blockIdx.x * 256 + threadIdx.x;
  float bias = bb[n];
  for (int g = 0; g < 4; g++) {
    float acc[8];
#pragma unroll
    for (int i = 0; i < 8; i++) acc[i] = 0.f;
    for (int c = 0; c < 128; c++) {
      float w = W[(size_t)c * 1024 + n];
#pragma unroll
      for (int i = 0; i < 8; i++) acc[i] += cs[(g * 8 + i) * 128 + c] * w;
    }
#pragma unroll
    for (int i = 0; i < 8; i++)
      ss[((size_t)lw * 32 + g * 8 + i) * 1024 + n] = acc[i] + bias;
  }
}

__global__ void embed_k(const float* __restrict__ theta, const float* __restrict__ eW,
                        const float* __restrict__ eb, float* __restrict__ x) {
  int row = blockIdx.x * 4 + (threadIdx.x >> 6), lane = threadIdx.x & 63;
  float th = theta[row], sn, cn;
  sincosf(th, &sn, &cn);
  int d = lane * 8;
  float* xo = x + (size_t)row * 512 + d;
#pragma unroll
  for (int i = 0; i < 8; i++) xo[i] = cn * eW[d + i] + sn * eW[512 + d + i] + eb[d + i];
}

// AdaLN; optionally folds a deferred bf16 residual delta (may ALIAS h!) and updates xw.
template<bool HASDEL>
__global__ void adaln_k(float* __restrict__ x, const short* delta,
                        const float* __restrict__ ss,
                        const float* __restrict__ g, const float* __restrict__ be,
                        short* h) {
  int row = blockIdx.x * 4 + (threadIdx.x >> 6), lane = threadIdx.x & 63;
  int b = row >> 10;
  float* xr = x + (size_t)row * 512 + lane * 8;
  float4 va = ((const float4*)xr)[0], vb = ((const float4*)xr)[1];
  float v[8] = {va.x, va.y, va.z, va.w, vb.x, vb.y, vb.z, vb.w};
  if (HASDEL) {
    s8v dv = *(const s8v*)(delta + (size_t)row * 512 + lane * 8);
#pragma unroll
    for (int i = 0; i < 8; i++) v[i] += bf2f((unsigned short)dv[i]);
    float4 o0 = {v[0], v[1], v[2], v[3]}, o1 = {v[4], v[5], v[6], v[7]};
    ((float4*)xr)[0] = o0; ((float4*)xr)[1] = o1;
  }
  float sm = 0.f;
#pragma unroll
  for (int i = 0; i < 8; i++) sm += v[i];
#pragma unroll
  for (int off = 1; off < 64; off <<= 1) sm += __shfl_xor(sm, off);
  float mean = sm * (1.f / 512.f);
  float sq = 0.f;
#pragma unroll
  for (int i = 0; i < 8; i++) { float d = v[i] - mean; sq += d * d; }
#pragma unroll
  for (int off = 1; off < 64; off <<= 1) sq += __shfl_xor(sq, off);
  float rs = rsqrtf(sq * (1.f / 512.f) + 1e-5f);
  const float* sb = ss + (size_t)b * 1024 + lane * 8;
  const float* gp = g + lane * 8;
  const float* bp = be + lane * 8;
  s8v o;
#pragma unroll
  for (int i = 0; i < 8; i++) {
    float xh = (v[i] - mean) * rs * gp[i] + bp[i];
    o[i] = f2bf((1.f + sb[i]) * xh + sb[i + 512]);
  }
  *(s8v*)(h + (size_t)row * 512 + lane * 8) = o;
}

// final LN, folding FF2's delta (delta may ALIAS h)
__global__ void fln_k(const float* __restrict__ x, const short* delta,
                      const float* __restrict__ g, const float* __restrict__ be,
                      short* h) {
  int row = blockIdx.x * 4 + (threadIdx.x >> 6), lane = threadIdx.x & 63;
  const float* xr = x + (size_t)row * 512 + lane * 8;
  float4 va = ((const float4*)xr)[0], vb = ((const float4*)xr)[1];
  float v[8] = {va.x, va.y, va.z, va.w, vb.x, vb.y, vb.z, vb.w};
  s8v dv = *(const s8v*)(delta + (size_t)row * 512 + lane * 8);
#pragma unroll
  for (int i = 0; i < 8; i++) v[i] += bf2f((unsigned short)dv[i]);
  float sm = 0.f;
#pragma unroll
  for (int i = 0; i < 8; i++) sm += v[i];
#pragma unroll
  for (int off = 1; off < 64; off <<= 1) sm += __shfl_xor(sm, off);
  float mean = sm * (1.f / 512.f);
  float sq = 0.f;
#pragma unroll
  for (int i = 0; i < 8; i++) { float d = v[i] - mean; sq += d * d; }
#pragma unroll
  for (int off = 1; off < 64; off <<= 1) sq += __shfl_xor(sq, off);
  float rs = rsqrtf(sq * (1.f / 512.f) + 1e-5f);
  const float* gp = g + lane * 8;
  const float* bp = be + lane * 8;
  s8v o;
#pragma unroll
  for (int i = 0; i < 8; i++) o[i] = f2bf((v[i] - mean) * rs * gp[i] + bp[i]);
  *(s8v*)(h + (size_t)row * 512 + lane * 8) = o;
}

// --- GEMM 128x128, BK=32, ring-3 + register-frag prefetch (FF1/Wo/FF2) ---
// iter t: STAGE(t+2) -> 16 MFMA on in-reg frags (zero wait) -> counted vmcnt
// -> barrier -> ds_read frags(t+1). EPI 0: bf16 (+bias); 1: gelu bf16
// (exp2-folded constants + v_rcp).
template<int EPI>
__global__ __launch_bounds__(256, 3) void gemm_r3_k(const short* __restrict__ A,
                                                    const short* __restrict__ BT,
                                                    const float* __restrict__ bias,
                                                    short* __restrict__ outb,
                                                    int N, int K) {
  __shared__ __align__(16) short lsA[3][4096];  // 3 x 8KB
  __shared__ __align__(16) short lsB[3][4096];
  int tid = threadIdx.x, lane = tid & 63, w = tid >> 6;
  int wm = w >> 1, wn = w & 1;
  int l15 = lane & 15, l4 = lane >> 4;
  int lrow = lane >> 2, lchunk = lane & 3;
  int poff = ((l15 << 2) + (l4 ^ ((l15 >> 1) & 3))) << 3;
  int nb = N >> 7;
  int bid = blockIdx.x;
  int xcd = bid & 7, rr = bid >> 3;
  int mloc = rr / nb, nidx = rr - mloc * nb;
  int m0 = (xcd * 32 + mloc) << 7, n0 = nidx << 7;

  f4v z4 = {0.f, 0.f, 0.f, 0.f};
  f4v acc[4][4];
#pragma unroll
  for (int i = 0; i < 4; i++)
#pragma unroll
    for (int j = 0; j < 4; j++) acc[i][j] = z4;

  int co = (lchunk ^ ((lrow >> 1) & 3)) << 3;

  auto STAGE = [&](int t) {
    int slot = t % 3;
    int ko = t << 5;
#pragma unroll
    for (int tt = 0; tt < 2; tt++) {
      int r0 = w * 32 + tt * 16;
      int row = r0 + lrow;
      gl_lds16(A + (size_t)(m0 + row) * K + ko + co, lsA[slot] + r0 * 32);
      gl_lds16(BT + (size_t)(n0 + row) * K + ko + co, lsB[slot] + r0 * 32);
    }
  };
  auto LOADF = [&](int t, s8v* af, s8v* bfr) {
    int slot = t % 3;
    const short* At = lsA[slot] + (wm * 4) * 512 + poff;
    const short* Bt = lsB[slot] + (wn * 4) * 512 + poff;
#pragma unroll
    for (int i = 0; i < 4; i++) {
      af[i] = *(const s8v*)(At + i * 512);
      bfr[i] = *(const s8v*)(Bt + i * 512);
    }
  };

  int NT = K >> 5;
  STAGE(0); STAGE(1);
  asm volatile("s_waitcnt vmcnt(4)" ::: "memory");  // tile 0 landed
  __builtin_amdgcn_s_barrier();
  s8v af[4], bfr[4];
  LOADF(0, af, bfr);
  for (int t = 0; t < NT; ++t) {
    if (t + 2 < NT) STAGE(t + 2);
    __builtin_amdgcn_sched_barrier(0);   // pin VMEM issue before the MFMA burst
#pragma unroll
    for (int i = 0; i < 4; i++)
#pragma unroll
      for (int j = 0; j < 4; j++)
        acc[i][j] = __builtin_amdgcn_mfma_f32_16x16x32_bf16(af[i], bfr[j], acc[i][j], 0, 0, 0);
    if (t + 1 < NT) {
      if (t + 2 < NT) asm volatile("s_waitcnt vmcnt(4)" ::: "memory");  // t+1 landed
      else            asm volatile("s_waitcnt vmcnt(0)" ::: "memory");  // tail
      __builtin_amdgcn_s_barrier();
      LOADF(t + 1, af, bfr);   // frags for next iter; latency covered by backedge
    }
  }
#pragma unroll
  for (int i = 0; i < 4; i++) {
    int gr0 = m0 + wm * 64 + i * 16 + l4 * 4;
#pragma unroll
    for (int j = 0; j < 4; j++) {
      int gc = n0 + wn * 64 + j * 16 + l15;
      float bv = bias[gc];
#pragma unroll
      for (int r = 0; r < 4; r++) {
        float v = acc[i][j][r] + bv;
        if (EPI == 1) {
          // sigmoid-gelu with log2e prefolded: v * sigmoid(1.5958v + 0.07135v^3)
          float tg = v * (-2.3022083f - 0.10294325f * v * v);
          v = v * frcp(1.f + fexp2(tg));
        }
        outb[(size_t)(gr0 + r) * N + gc] = f2bf(v);
      }
    }
  }
}

// --- QK projection: branch-free ring-3 (FF1-proven body). grid 2048. ---
// n0 in [0,1024); output qk row stride 1024; q cols scaled by Q_SCALE.
__global__ __launch_bounds__(256, 3) void qk_proj_k(const short* __restrict__ A,
                                                    const short* __restrict__ BT,
                                                    const float* __restrict__ bias,
                                                    short* __restrict__ qk) {
  __shared__ __align__(16) short lsA[3][4096];
  __shared__ __align__(16) short lsB[3][4096];
  int tid = threadIdx.x, lane = tid & 63, w = tid >> 6;
  int wm = w >> 1, wn = w & 1;
  int l15 = lane & 15, l4 = lane >> 4;
  int lrow = lane >> 2, lchunk = lane & 3;
  int poff = ((l15 << 2) + (l4 ^ ((l15 >> 1) & 3))) << 3;
  int bid = blockIdx.x;
  int xcd = bid & 7, rr = bid >> 3;
  int mloc = rr >> 3, nidx = rr & 7;
  int m0 = (xcd * 32 + mloc) << 7, n0 = nidx << 7;
  bool isQ = (n0 < 512);

  f4v z4 = {0.f, 0.f, 0.f, 0.f};
  f4v acc[4][4];
#pragma unroll
  for (int i = 0; i < 4; i++)
#pragma unroll
    for (int j = 0; j < 4; j++) acc[i][j] = z4;

  int co = (lchunk ^ ((lrow >> 1) & 3)) << 3;

  auto STAGE = [&](int t) {
    int slot = t % 3;
    int ko = t << 5;
#pragma unroll
    for (int tt = 0; tt < 2; tt++) {
      int r0 = w * 32 + tt * 16;
      int row = r0 + lrow;
      gl_lds16(A + (size_t)(m0 + row) * 512 + ko + co, lsA[slot] + r0 * 32);
      gl_lds16(BT + (size_t)(n0 + row) * 512 + ko + co, lsB[slot] + r0 * 32);
    }
  };
  auto LOADF = [&](int t, s8v* af, s8v* bfr) {
    int slot = t % 3;
    const short* At = lsA[slot] + (wm * 4) * 512 + poff;
    const short* Bt = lsB[slot] + (wn * 4) * 512 + poff;
#pragma unroll
    for (int i = 0; i < 4; i++) {
      af[i] = *(const s8v*)(At + i * 512);
      bfr[i] = *(const s8v*)(Bt + i * 512);
    }
  };

  const int NT = 16;
  STAGE(0); STAGE(1);
  asm volatile("s_waitcnt vmcnt(4)" ::: "memory");
  __builtin_amdgcn_s_barrier();
  s8v af[4], bfr[4];
  LOADF(0, af, bfr);
  for (int t = 0; t < NT; ++t) {
    if (t + 2 < NT) STAGE(t + 2);
    __builtin_amdgcn_sched_barrier(0);
#pragma unroll
    for (int i = 0; i < 4; i++)
#pragma unroll
      for (int j = 0; j < 4; j++)
        acc[i][j] = __builtin_amdgcn_mfma_f32_16x16x32_bf16(af[i], bfr[j], acc[i][j], 0, 0, 0);
    if (t + 1 < NT) {
      if (t + 2 < NT) asm volatile("s_waitcnt vmcnt(4)" ::: "memory");
      else            asm volatile("s_waitcnt vmcnt(0)" ::: "memory");
      __builtin_amdgcn_s_barrier();
      LOADF(t + 1, af, bfr);
    }
  }
  float scl = isQ ? Q_SCALE : 1.f;  // fold 1/sqrt(HD)*log2e into q
#pragma unroll
  for (int i = 0; i < 4; i++) {
    int gr0 = m0 + wm * 64 + i * 16 + l4 * 4;
#pragma unroll
    for (int j = 0; j < 4; j++) {
      int gc = n0 + wn * 64 + j * 16 + l15;
      float bv = bias[gc];
#pragma unroll
      for (int r = 0; r < 4; r++)
        qk[(size_t)(gr0 + r) * 1024 + gc] = f2bf(acc[i][j][r] * scl + bv);
    }
  }
}

// --- V projection: 2-buffer 32KB, operand-swapped MFMA -> V^T scatter. grid 1024. ---
// (r12: reverted from ring-3; r11 measured the swapped-operand body +39us
// under ring-3's LOADF structure. This exact 2-buffer body measured good in r10.)
__global__ __launch_bounds__(256) void v_proj_k(const short* __restrict__ A,
                                                const short* __restrict__ BT,
                                                const float* __restrict__ bias,
                                                short* __restrict__ vtb) {
  __shared__ __align__(16) short lsA[2][4096];
  __shared__ __align__(16) short lsB[2][4096];
  int tid = threadIdx.x, lane = tid & 63, w = tid >> 6;
  int wm = w >> 1, wn = w & 1;
  int l15 = lane & 15, l4 = lane >> 4;
  int lrow = lane >> 2, lchunk = lane & 3;
  int poff = ((l15 << 2) + (l4 ^ ((l15 >> 1) & 3))) << 3;
  int bid = blockIdx.x;
  int xcd = bid & 7, rr = bid >> 3;
  int mloc = rr >> 2, nidx = rr & 3;
  int m0 = (xcd * 32 + mloc) << 7, n0 = 1024 + (nidx << 7);

  f4v z4 = {0.f, 0.f, 0.f, 0.f};
  f4v acc[4][4];
#pragma unroll
  for (int i = 0; i < 4; i++)
#pragma unroll
    for (int j = 0; j < 4; j++) acc[i][j] = z4;

  int co = (lchunk ^ ((lrow >> 1) & 3)) << 3;

  auto STAGE = [&](int t) {
    int slot = t & 1;
    int ko = t << 5;
#pragma unroll
    for (int tt = 0; tt < 2; tt++) {
      int r0 = w * 32 + tt * 16;
      int row = r0 + lrow;
      gl_lds16(A + (size_t)(m0 + row) * 512 + ko + co, lsA[slot] + r0 * 32);
      gl_lds16(BT + (size_t)(n0 + row) * 512 + ko + co, lsB[slot] + r0 * 32);
    }
  };

  const int NT = 16;
  STAGE(0);
  for (int t = 0; t < NT; ++t) {
    if (t + 1 < NT) {
      STAGE(t + 1);
      asm volatile("s_waitcnt vmcnt(4)" ::: "memory");
    } else {
      asm volatile("s_waitcnt vmcnt(0)" ::: "memory");
    }
    __builtin_amdgcn_s_barrier();
    int slot = t & 1;
    const short* At = lsA[slot] + (wm * 4) * 512 + poff;
    const short* Bt = lsB[slot] + (wn * 4) * 512 + poff;
    s8v af[4], bfr[4];
#pragma unroll
    for (int i = 0; i < 4; i++) {
      af[i] = *(const s8v*)(At + i * 512);
      bfr[i] = *(const s8v*)(Bt + i * 512);
    }
#pragma unroll
    for (int j = 0; j < 4; j++)
#pragma unroll
      for (int i = 0; i < 4; i++)
        acc[j][i] = __builtin_amdgcn_mfma_f32_16x16x32_bf16(bfr[j], af[i], acc[j][i], 0, 0, 0);
    __builtin_amdgcn_s_barrier();
  }
  int b = m0 >> 10, s0 = m0 & 1023;
#pragma unroll
  for (int j = 0; j < 4; j++) {
    int col = n0 + wn * 64 + j * 16 + l4 * 4;
#pragma unroll
    for (int i = 0; i < 4; i++) {
      int scol = s0 + wm * 64 + i * 16 + l15;
#pragma unroll
      for (int r = 0; r < 4; r++) {
        float v = acc[j][i][r] + bias[col + r];
        vtb[((size_t)b * 512 + col - 1024 + r) * 1024 + scol] = f2bf(v);
      }
    }
  }
}

// ---------------- flash attention (QBLK=128, no-max exp2 softmax, bias-as-C) ----------------
// Swapped QK^T: s^T = mfma(K, Q, bias); P transposed back in registers via
// cvt_pk_bf16 + permlane{32,16}_swap. K/V double-buffered, counted vmcnt(4).
// q & bias pre-scaled by log2e -> softmax uses raw v_exp_f32 (2^x).
__global__ __launch_bounds__(256, 4) void attn_k(const short* __restrict__ qk,
                                                 const short* __restrict__ vt,
                                                 const short* __restrict__ biasNT,
                                                 short* __restrict__ ao) {
  __shared__ __align__(16) short Kl[2][64 * 64];
  __shared__ __align__(16) short Vl[2][64 * 64];
  int tid = threadIdx.x, lane = tid & 63, w = tid >> 6;
  int bid = blockIdx.x;
  int qt = 7 - (bid >> 8), b = (bid >> 3) & 31, h = bid & 7;
  int l15 = lane & 15, l4 = lane >> 4;
  int lrow = lane >> 3, lchunk = lane & 7;

  f4v z4 = {0.f, 0.f, 0.f, 0.f};
  s8v qf[2][2];
#pragma unroll
  for (int g = 0; g < 2; g++) {
    const short* qp = qk + (size_t)(b * 1024 + qt * 128 + g * 64 + w * 16 + l15) * 1024 + h * 64;
    qf[g][0] = *(const s8v*)(qp + l4 * 8);
    qf[g][1] = *(const s8v*)(qp + 32 + l4 * 8);
  }
  f4v o[2][4], lac[2];
#pragma unroll
  for (int g = 0; g < 2; g++) {
    lac[g] = z4;
#pragma unroll
    for (int j = 0; j < 4; j++) o[g][j] = z4;
  }
  s8v ones;
#pragma unroll
  for (int e = 0; e < 8; e++) ones[e] = (short)0x3F80;

  auto STAGE = [&](int buf, int kt) {
#pragma unroll
    for (int t = 0; t < 2; t++) {
      int r0 = (w * 2 + t) * 8;
      int row = r0 + lrow;
      gl_lds16(qk + (size_t)(b * 1024 + kt * 64 + row) * 1024 + 512 + h * 64 +
                   ((lchunk ^ (row & 7)) << 3),
               &Kl[buf][r0 * 64]);
      gl_lds16(vt + (size_t)(b * 512 + h * 64 + row) * 1024 + kt * 64 +
                   ((lchunk ^ (row & 7)) << 3),
               &Vl[buf][r0 * 64]);
    }
  };

  int nkt = 2 * qt + 2;
  STAGE(0, 0);
  for (int kt = 0; kt < nkt; kt++) {
    int cur = kt & 1;
    ushort4 bh[2][4];
#pragma unroll
    for (int g = 0; g < 2; g++) {
      if (kt > 2 * qt + g) continue;
      const short* bp = biasNT + ((size_t)h * 1024 + qt * 128 + g * 64 + w * 16 + l15) * 1024 +
                        kt * 64 + l4 * 4;
#pragma unroll
      for (int j = 0; j < 4; j++) bh[g][j] = *(const ushort4*)(bp + j * 16);
    }
    __builtin_amdgcn_sched_barrier(0);  // keep bias loads ahead of the staging DMA
    if (kt + 1 < nkt) {
      STAGE(cur ^ 1, kt + 1);
      asm volatile("s_waitcnt vmcnt(4)" ::: "memory");
    } else {
      asm volatile("s_waitcnt vmcnt(0)" ::: "memory");
    }
    __builtin_amdgcn_s_barrier();
    const short* Kc = &Kl[cur][0];
    const short* Vc = &Vl[cur][0];
#pragma unroll
    for (int g = 0; g < 2; g++) {
      int diag = 2 * qt + g;
      if (kt > diag) continue;
      f4v s[4];
#pragma unroll
      for (int j = 0; j < 4; j++) {
        f4v bc;
        bc[0] = bf2f(bh[g][j].x); bc[1] = bf2f(bh[g][j].y);
        bc[2] = bf2f(bh[g][j].z); bc[3] = bf2f(bh[g][j].w);
        int kr = j * 16 + l15;
        s8v kf0 = *(const s8v*)(Kc + kr * 64 + ((l4 ^ (kr & 7)) << 3));
        s8v kf1 = *(const s8v*)(Kc + kr * 64 + (((l4 + 4) ^ (kr & 7)) << 3));
        s[j] = __builtin_amdgcn_mfma_f32_16x16x32_bf16(kf0, qf[g][0], bc, 0, 0, 0);
        s[j] = __builtin_amdgcn_mfma_f32_16x16x32_bf16(kf1, qf[g][1], s[j], 0, 0, 0);
      }
      if (kt == diag) {
#pragma unroll
        for (int j = 0; j < 4; j++)
#pragma unroll
          for (int r = 0; r < 4; r++) {
            int kk = j * 16 + l4 * 4 + r, qq = w * 16 + l15;
            s[j][r] = (kk > qq) ? 0.f : fexp2(s[j][r]);
          }
      } else {
#pragma unroll
        for (int j = 0; j < 4; j++)
#pragma unroll
          for (int r = 0; r < 4; r++) s[j][r] = fexp2(s[j][r]);
      }
      unsigned X0[4], X1[4];
#pragma unroll
      for (int j = 0; j < 4; j++) {
        X0[j] = cvtpk(s[j][0], s[j][1]);
        X1[j] = cvtpk(s[j][2], s[j][3]);
      }
      u2v a0 = __builtin_amdgcn_permlane32_swap(X0[0], X0[1], false, false);
      u2v a1 = __builtin_amdgcn_permlane16_swap(a0[0], a0[1], false, false);
      u2v b0 = __builtin_amdgcn_permlane32_swap(X1[0], X1[1], false, false);
      u2v b1 = __builtin_amdgcn_permlane16_swap(b0[0], b0[1], false, false);
      u2v c0 = __builtin_amdgcn_permlane32_swap(X0[2], X0[3], false, false);
      u2v c1 = __builtin_amdgcn_permlane16_swap(c0[0], c0[1], false, false);
      u2v d0 = __builtin_amdgcn_permlane32_swap(X1[2], X1[3], false, false);
      u2v d1 = __builtin_amdgcn_permlane16_swap(d0[0], d0[1], false, false);
      u4v P0 = {a1[0], b1[0], a1[1], b1[1]};  // k 0..31
      u4v P1 = {c1[0], d1[0], c1[1], d1[1]};  // k 32..63
      s8v pf0 = __builtin_bit_cast(s8v, P0);
      s8v pf1 = __builtin_bit_cast(s8v, P1);
      lac[g] = __builtin_amdgcn_mfma_f32_16x16x32_bf16(pf0, ones, lac[g], 0, 0, 0);
      lac[g] = __builtin_amdgcn_mfma_f32_16x16x32_bf16(pf1, ones, lac[g], 0, 0, 0);
#pragma unroll
      for (int j = 0; j < 4; j++) {
        int dr = j * 16 + l15;
        s8v vf0 = *(const s8v*)(Vc + dr * 64 + ((l4 ^ (dr & 7)) << 3));
        s8v vf1 = *(const s8v*)(Vc + dr * 64 + (((l4 + 4) ^ (dr & 7)) << 3));
        o[g][j] = __builtin_amdgcn_mfma_f32_16x16x32_bf16(pf0, vf0, o[g][j], 0, 0, 0);
        o[g][j] = __builtin_amdgcn_mfma_f32_16x16x32_bf16(pf1, vf1, o[g][j], 0, 0, 0);
      }
    }
    __builtin_amdgcn_s_barrier();
  }
#pragma unroll
  for (int g = 0; g < 2; g++)
#pragma unroll
    for (int r = 0; r < 4; r++) {
      float rl = frcp(lac[g][r]);
      int qr = qt * 128 + g * 64 + w * 16 + l4 * 4 + r;
#pragma unroll
      for (int j = 0; j < 4; j++) {
        int d = j * 16 + l15;
        ao[(size_t)(b * 1024 + qr) * 512 + h * 64 + d] = f2bf(o[g][j][r] * rl);
      }
    }
}

// ---------------- head GEMM ----------------
__global__ __launch_bounds__(256) void head_k(const short* __restrict__ X,
                                              const short* __restrict__ hWT,
                                              const float* __restrict__ hb,
                                              float* __restrict__ out) {
  __shared__ __align__(16) short lA[128 * 64];
  int tid = threadIdx.x, lane = tid & 63, w = tid >> 6;
  int l15 = lane & 15, l4 = lane >> 4;
  int lrow = lane >> 3, lchunk = lane & 7;
  int m0 = blockIdx.x * 128;
  f4v z4 = {0.f, 0.f, 0.f, 0.f};
  f4v acc[2][2];
#pragma unroll
  for (int i = 0; i < 2; i++)
#pragma unroll
    for (int j = 0; j < 2; j++) acc[i][j] = z4;

  for (int k0 = 0; k0 < 512; k0 += 64) {
#pragma unroll
    for (int t = 0; t < 4; t++) {
      int r0 = (w * 4 + t) * 8;
      int row = r0 + lrow;
      gl_lds16(X + (size_t)(m0 + row) * 512 + k0 + ((lchunk ^ (row & 7)) << 3), lA + r0 * 64);
    }
    __syncthreads();
#pragma unroll
    for (int kk = 0; kk < 2; kk++) {
      s8v af[2], bfr[2];
#pragma unroll
      for (int i = 0; i < 2; i++) {
        int ra = w * 32 + i * 16 + l15;
        af[i] = *(const s8v*)(lA + ra * 64 + (((l4 + kk * 4) ^ (ra & 7)) << 3));
      }
#pragma unroll
      for (int j = 0; j < 2; j++)
        bfr[j] = *(const s8v*)(hWT + (size_t)(j * 16 + l15) * 512 + k0 + kk * 32 + l4 * 8);
#pragma unroll
      for (int i = 0; i < 2; i++)
#pragma unroll
        for (int j = 0; j < 2; j++)
          acc[i][j] = __builtin_amdgcn_mfma_f32_16x16x32_bf16(af[i], bfr[j], acc[i][j], 0, 0, 0);
    }
    __syncthreads();
  }
#pragma unroll
  for (int i = 0; i < 2; i++) {
#pragma unroll
    for (int j = 0; j < 2; j++) {
      int col = j * 16 + l15;
      if (col < 24) {
        float bv = hb[col];
#pragma unroll
        for (int r = 0; r < 4; r++) {
          int row = m0 + w * 32 + i * 16 + l4 * 4 + r;
          out[(size_t)row * 24 + col] = acc[i][j][r] + bv;
        }
      }
    }
  }
}

// ---------------- launch ----------------
extern "C" void kernel_launch(void* const* d_in, const int* in_sizes, int n_in,
                              void* d_out, int out_size, void* d_ws, size_t ws_size,
                              hipStream_t stream) {
  (void)in_sizes; (void)n_in; (void)out_size;
  const float* theta   = (const float*)d_in[0];
  const float* cond    = (const float*)d_in[1];
  const float* attn_b  = (const float*)d_in[2];
  const float* embed_W = (const float*)d_in[3];
  const float* embed_b = (const float*)d_in[4];
  const float* ln1_g   = (const float*)d_in[5];
  const float* ln1_b   = (const float*)d_in[6];
  const float* ada1_W  = (const float*)d_in[7];
  const float* ada1_b  = (const float*)d_in[8];
  const float* Wq      = (const float*)d_in[9];
  const float* bq      = (const float*)d_in[10];
  const float* Wk      = (const float*)d_in[11];
  const float* bk      = (const float*)d_in[12];
  const float* Wv      = (const float*)d_in[13];
  const float* bv      = (const float*)d_in[14];
  const float* Wo      = (const float*)d_in[15];
  const float* bo      = (const float*)d_in[16];
  const float* ln2_g   = (const float*)d_in[17];
  const float* ln2_b   = (const float*)d_in[18];
  const float* ada2_W  = (const float*)d_in[19];
  const float* ada2_b  = (const float*)d_in[20];
  const float* W1      = (const float*)d_in[21];
  const float* b1      = (const float*)d_in[22];
  const float* W2      = (const float*)d_in[23];
  const float* b2      = (const float*)d_in[24];
  const float* fn_g    = (const float*)d_in[25];
  const float* fn_b    = (const float*)d_in[26];
  const float* head_W  = (const float*)d_in[27];
  const float* head_b  = (const float*)d_in[28];

  const size_t REQ = 242814976ull;
  const size_t REQ2 = 259592192ull;
  if (ws_size < REQ) return;
  bool bias_once = (ws_size >= REQ2);

  char* ws = (char*)d_ws;
  float* xw    = (float*)(ws + 0ull);
  short* qk    = (short*)(ws + 67108864ull);
  short* vtb   = (short*)(ws + 134217728ull);   // V^T, then Wo-delta
  short* biasT = (short*)(ws + (bias_once ? 242814976ull : 167772160ull));
  short* qf    = (short*)(ws + 67108864ull);
  short* hbuf  = (short*)(ws + 201326592ull);   // adaln out / attn out / FF2 delta
  short* wbf   = (short*)(ws + 234881024ull);
  float* ssb   = (float*)(ws + 241172480ull);
  float* bqkv  = (float*)(ws + 242745344ull);
  short* hWT   = (short*)(ws + 242782208ull);

  concat_qkvb_k<<<6, 256, 0, stream>>>(bq, bk, bv, bqkv);
  cond_proj_k<<<dim3(4, 12), 256, 0, stream>>>(cond, ada1_W, ada1_b, ada2_W, ada2_b, ssb);
  hwt_k<<<64, 256, 0, stream>>>(head_W, hWT);
  embed_k<<<8192, 256, 0, stream>>>(theta, embed_W, embed_b, xw);
  if (bias_once) bias_cvt_k<<<8192, 256, 0, stream>>>(attn_b, biasT);

  for (int l = 0; l < 6; l++) {
    transpose_all_k<<<3072, 256, 0, stream>>>(Wq, Wk, Wv, Wo, W1, W2, l, wbf);
    if (!bias_once) bias_cvt_k<<<8192, 256, 0, stream>>>(attn_b, biasT);

    if (l == 0)
      adaln_k<false><<<8192, 256, 0, stream>>>(xw, nullptr, ssb + (size_t)(l * 2) * 32768,
                                               ln1_g + l * 512, ln1_b + l * 512, hbuf);
    else  // delta = FF2 delta from layer l-1, lives in hbuf; h also hbuf (safe)
      adaln_k<true><<<8192, 256, 0, stream>>>(xw, hbuf, ssb + (size_t)(l * 2) * 32768,
                                              ln1_g + l * 512, ln1_b + l * 512, hbuf);
    qk_proj_k<<<2048, 256, 0, stream>>>(hbuf, wbf, bqkv + l * 1536, qk);
    v_proj_k<<<1024, 256, 0, stream>>>(hbuf, wbf, bqkv + l * 1536, vtb);
    attn_k<<<2048, 256, 0, stream>>>(qk, vtb, biasT, hbuf);
    // Wo: delta = attn_out @ Wo^T + bo -> vtb (dead V^T); ring-3
    gemm_r3_k<0><<<1024, 256, 0, stream>>>(hbuf, wbf + 786432, bo + l * 512, vtb, 512, 512);
    adaln_k<true><<<8192, 256, 0, stream>>>(xw, vtb, ssb + (size_t)(l * 2 + 1) * 32768,
                                            ln2_g + l * 512, ln2_b + l * 512, hbuf);
    // FF1: ring-3 (exp2-gelu epilogue)
    gemm_r3_k<1><<<4096, 256, 0, stream>>>(hbuf, wbf + 1048576, b1 + l * 2048, qf, 2048, 512);
    // FF2: delta -> hbuf (disjoint from qf); ring-3
    gemm_r3_k<0><<<1024, 256, 0, stream>>>(qf, wbf + 2097152, b2 + l * 512, hbuf, 512, 2048);
  }
  fln_k<<<8192, 256, 0, stream>>>(xw, hbuf, fn_g, fn_b, hbuf);
  head_k<<<256, 256, 0, stream>>>(hbuf, hWT, head_b, (float*)d_out);
}

// Round 14
// 2663.136 us; speedup vs baseline: 1.0032x; 1.0032x over previous
//
#include <hip/hip_runtime.h>

// ContinuousLatticeGPT: B=32 S=1024 D=512 H=8 NL=6 DFF=2048 C=128 K=8
// bf16 MFMA; fp32 residual stream with deferred (bf16 delta) residual adds.
// == Round-11 configuration (best passing, 2660us) ==
// GEMM assignment (solved from r5-r11 measurements):
//  - FF1 / Wo / FF2 / qk_proj / v_proj -> ring-3 + register-frag prefetch
//    (48KB LDS). r7's qkvt ring-3 regression was the dual-MFMA-path branch
//    (confirmed r10: branch-free ring-3 qk_proj is fine).
//  - gelu epilogue (FF1): log2e folded into sigmoid-gelu constants -> raw
//    v_exp_f32 + v_rcp_f32 (r11: -96us, VALUBusy 48->38%).
// All GEMMs: lane-adjacent 64B-row staging + chunk^=((row>>1)&3) swizzle
// (TA-coalesced AND bank-conflict-free).
// attn: swapped-QK (mfma(K,Q)) with in-register P transpose via cvt_pk+permlane;
// exp2-folded softmax (log2e in q-scale & bias). No setprio (r9: +12us).
// Delta routing: Wo-delta -> vtb (dead V^T), folded IMMEDIATELY by adaln2
// (r13 lesson: vtb must NOT outlive FF1 - qf's 128MB output [64MB,192MB past
// qk base) overwrites vtb's region); FF2-delta -> hbuf (dead FF1 input,
// disjoint from qf), folded by next adaln1 / fln.
// ws layout (bytes): unchanged. REQ 242,814,976 B

typedef short s8v __attribute__((ext_vector_type(8)));
typedef float f4v __attribute__((ext_vector_type(4)));
typedef unsigned u2v __attribute__((ext_vector_type(2)));
typedef unsigned u4v __attribute__((ext_vector_type(4)));

#define Q_SCALE 0.18033688011112042f  // 0.125 * log2(e)
#define LOG2E   1.4426950408889634f

static __device__ __forceinline__ short f2bf(float f) {
  union { float f; unsigned u; } v; v.f = f;
  unsigned r = v.u + 0x7fffu + ((v.u >> 16) & 1u);
  return (short)(r >> 16);
}
static __device__ __forceinline__ float bf2f(unsigned short s) {
  union { unsigned u; float f; } v; v.u = ((unsigned)s) << 16;
  return v.f;
}
static __device__ __forceinline__ unsigned cvtpk(float lo, float hi) {
  unsigned r;
  asm("v_cvt_pk_bf16_f32 %0, %1, %2" : "=v"(r) : "v"(lo), "v"(hi));
  return r;
}
static __device__ __forceinline__ float fexp2(float x) {  // 2^x, single v_exp_f32
  float r;
  asm("v_exp_f32 %0, %1" : "=v"(r) : "v"(x));
  return r;
}
static __device__ __forceinline__ float frcp(float x) {  // ~1ulp reciprocal
  float r;
  asm("v_rcp_f32 %0, %1" : "=v"(r) : "v"(x));
  return r;
}
static __device__ __forceinline__ void gl_lds16(const short* g, short* l) {
  __builtin_amdgcn_global_load_lds(
      (const __attribute__((address_space(1))) unsigned int*)g,
      (__attribute__((address_space(3))) unsigned int*)l, 16, 0, 0);
}

// ---------------- prep kernels ----------------
__global__ void transpose_all_k(const float* __restrict__ Wq, const float* __restrict__ Wk,
                                const float* __restrict__ Wv, const float* __restrict__ Wo,
                                const float* __restrict__ W1, const float* __restrict__ W2,
                                int l, short* __restrict__ wbf) {
  int id = blockIdx.x;
  const float* in; short* out; int K, N, tx, ty;
  if (id < 1024) {
    int m = id >> 8, t = id & 255;
    in = (m == 0 ? Wq : m == 1 ? Wk : m == 2 ? Wv : Wo) + (size_t)l * 262144;
    out = wbf + (size_t)m * 262144;
    K = 512; N = 512; tx = t & 15; ty = t >> 4;
  } else if (id < 2048) {
    int t = id - 1024;
    in = W1 + (size_t)l * 1048576; out = wbf + 1048576;
    K = 512; N = 2048; tx = t & 63; ty = t >> 6;
  } else {
    int t = id - 2048;
    in = W2 + (size_t)l * 1048576; out = wbf + 2097152;
    K = 2048; N = 512; tx = t & 15; ty = t >> 4;
  }
  __shared__ float tb[32][33];
  int n0 = tx * 32, k0 = ty * 32;
  int cx = threadIdx.x & 31, cy = threadIdx.x >> 5;
#pragma unroll
  for (int r = 0; r < 4; r++)
    tb[cy + r * 8][cx] = in[(size_t)(k0 + cy + r * 8) * N + n0 + cx];
  __syncthreads();
#pragma unroll
  for (int r = 0; r < 4; r++)
    out[(size_t)(n0 + cy + r * 8) * K + k0 + cx] = f2bf(tb[cx][cy + r * 8]);
}

// f32 -> bf16 copy of attn_bias, folding log2(e) for the exp2 softmax
__global__ void bias_cvt_k(const float* __restrict__ in, short* __restrict__ out) {
  int i = blockIdx.x * 256 + threadIdx.x;  // float4 index; grid covers 8M floats
  float4 v = ((const float4*)in)[i];
  ushort4 o;
  o.x = (unsigned short)f2bf(v.x * LOG2E);
  o.y = (unsigned short)f2bf(v.y * LOG2E);
  o.z = (unsigned short)f2bf(v.z * LOG2E);
  o.w = (unsigned short)f2bf(v.w * LOG2E);
  ((ushort4*)out)[i] = o;
}

__global__ void hwt_k(const float* __restrict__ hW, short* __restrict__ hWT) {
  int i = blockIdx.x * 256 + threadIdx.x;
  int n = i >> 9, k = i & 511;
  hWT[i] = (n < 24) ? f2bf(hW[(size_t)k * 24 + n]) : (short)0;
}

__global__ void concat_qkvb_k(const float* bq, const float* bk, const float* bv, float* out) {
  int l = blockIdx.x;
  for (int i = threadIdx.x; i < 1536; i += 256) {
    float v = (i < 512) ? bq[l * 512 + i] * Q_SCALE  // fold 1/sqrt(HD)*log2e into q bias
            : (i < 1024 ? bk[l * 512 + i - 512] : bv[l * 512 + i - 1024]);
    out[l * 1536 + i] = v;
  }
}

__global__ void cond_proj_k(const float* __restrict__ cond,
                            const float* __restrict__ a1W, const float* __restrict__ a1b,
                            const float* __restrict__ a2W, const float* __restrict__ a2b,
                            float* __restrict__ ss) {
  int lw = blockIdx.y, which = lw & 1, l = lw >> 1;
  const float* W = (which ? a2W : a1W) + (size_t)l * 128 * 1024;
  const float* bb = (which ? a2b : a1b) + (size_t)l * 1024;
  __shared__ float cs[32 * 128];
  for (int i = threadIdx.x; i < 32 * 128; i += 256) cs[i] = cond[i];
  __syncthreads();
  int n = blockIdx.x * 256 + threadIdx.x;
  float bias = bb[n];
  for (int g = 0; g < 4; g++) {
    float acc[8];
#pragma unroll
    for (int i = 0; i < 8; i++) acc[i] = 0.f;
    for (int c = 0; c < 128; c++) {
      float w = W[(size_t)c * 1024 + n];
#pragma unroll
      for (int i = 0; i < 8; i++) acc[i] += cs[(g * 8 + i) * 128 + c] * w;
    }
#pragma unroll
    for (int i = 0; i < 8; i++)
      ss[((size_t)lw * 32 + g * 8 + i) * 1024 + n] = acc[i] + bias;
  }
}

__global__ void embed_k(const float* __restrict__ theta, const float* __restrict__ eW,
                        const float* __restrict__ eb, float* __restrict__ x) {
  int row = blockIdx.x * 4 + (threadIdx.x >> 6), lane = threadIdx.x & 63;
  float th = theta[row], sn, cn;
  sincosf(th, &sn, &cn);
  int d = lane * 8;
  float* xo = x + (size_t)row * 512 + d;
#pragma unroll
  for (int i = 0; i < 8; i++) xo[i] = cn * eW[d + i] + sn * eW[512 + d + i] + eb[d + i];
}

// AdaLN; optionally folds a deferred bf16 residual delta (may ALIAS h!) and updates xw.
template<bool HASDEL>
__global__ void adaln_k(float* __restrict__ x, const short* delta,
                        const float* __restrict__ ss,
                        const float* __restrict__ g, const float* __restrict__ be,
                        short* h) {
  int row = blockIdx.x * 4 + (threadIdx.x >> 6), lane = threadIdx.x & 63;
  int b = row >> 10;
  float* xr = x + (size_t)row * 512 + lane * 8;
  float4 va = ((const float4*)xr)[0], vb = ((const float4*)xr)[1];
  float v[8] = {va.x, va.y, va.z, va.w, vb.x, vb.y, vb.z, vb.w};
  if (HASDEL) {
    s8v dv = *(const s8v*)(delta + (size_t)row * 512 + lane * 8);
#pragma unroll
    for (int i = 0; i < 8; i++) v[i] += bf2f((unsigned short)dv[i]);
    float4 o0 = {v[0], v[1], v[2], v[3]}, o1 = {v[4], v[5], v[6], v[7]};
    ((float4*)xr)[0] = o0; ((float4*)xr)[1] = o1;
  }
  float sm = 0.f;
#pragma unroll
  for (int i = 0; i < 8; i++) sm += v[i];
#pragma unroll
  for (int off = 1; off < 64; off <<= 1) sm += __shfl_xor(sm, off);
  float mean = sm * (1.f / 512.f);
  float sq = 0.f;
#pragma unroll
  for (int i = 0; i < 8; i++) { float d = v[i] - mean; sq += d * d; }
#pragma unroll
  for (int off = 1; off < 64; off <<= 1) sq += __shfl_xor(sq, off);
  float rs = rsqrtf(sq * (1.f / 512.f) + 1e-5f);
  const float* sb = ss + (size_t)b * 1024 + lane * 8;
  const float* gp = g + lane * 8;
  const float* bp = be + lane * 8;
  s8v o;
#pragma unroll
  for (int i = 0; i < 8; i++) {
    float xh = (v[i] - mean) * rs * gp[i] + bp[i];
    o[i] = f2bf((1.f + sb[i]) * xh + sb[i + 512]);
  }
  *(s8v*)(h + (size_t)row * 512 + lane * 8) = o;
}

// final LN, folding FF2's delta (delta may ALIAS h)
__global__ void fln_k(const float* __restrict__ x, const short* delta,
                      const float* __restrict__ g, const float* __restrict__ be,
                      short* h) {
  int row = blockIdx.x * 4 + (threadIdx.x >> 6), lane = threadIdx.x & 63;
  const float* xr = x + (size_t)row * 512 + lane * 8;
  float4 va = ((const float4*)xr)[0], vb = ((const float4*)xr)[1];
  float v[8] = {va.x, va.y, va.z, va.w, vb.x, vb.y, vb.z, vb.w};
  s8v dv = *(const s8v*)(delta + (size_t)row * 512 + lane * 8);
#pragma unroll
  for (int i = 0; i < 8; i++) v[i] += bf2f((unsigned short)dv[i]);
  float sm = 0.f;
#pragma unroll
  for (int i = 0; i < 8; i++) sm += v[i];
#pragma unroll
  for (int off = 1; off < 64; off <<= 1) sm += __shfl_xor(sm, off);
  float mean = sm * (1.f / 512.f);
  float sq = 0.f;
#pragma unroll
  for (int i = 0; i < 8; i++) { float d = v[i] - mean; sq += d * d; }
#pragma unroll
  for (int off = 1; off < 64; off <<= 1) sq += __shfl_xor(sq, off);
  float rs = rsqrtf(sq * (1.f / 512.f) + 1e-5f);
  const float* gp = g + lane * 8;
  const float* bp = be + lane * 8;
  s8v o;
#pragma unroll
  for (int i = 0; i < 8; i++) o[i] = f2bf((v[i] - mean) * rs * gp[i] + bp[i]);
  *(s8v*)(h + (size_t)row * 512 + lane * 8) = o;
}

// --- GEMM 128x128, BK=32, ring-3 + register-frag prefetch (FF1/Wo/FF2) ---
// iter t: STAGE(t+2) -> 16 MFMA on in-reg frags (zero wait) -> counted vmcnt
// -> barrier -> ds_read frags(t+1). EPI 0: bf16 (+bias); 1: gelu bf16
// (exp2-folded constants + v_rcp, pure algebra vs __expf form).
template<int EPI>
__global__ __launch_bounds__(256, 3) void gemm_r3_k(const short* __restrict__ A,
                                                    const short* __restrict__ BT,
                                                    const float* __restrict__ bias,
                                                    short* __restrict__ outb,
                                                    int N, int K) {
  __shared__ __align__(16) short lsA[3][4096];  // 3 x 8KB
  __shared__ __align__(16) short lsB[3][4096];
  int tid = threadIdx.x, lane = tid & 63, w = tid >> 6;
  int wm = w >> 1, wn = w & 1;
  int l15 = lane & 15, l4 = lane >> 4;
  int lrow = lane >> 2, lchunk = lane & 3;
  int poff = ((l15 << 2) + (l4 ^ ((l15 >> 1) & 3))) << 3;
  int nb = N >> 7;
  int bid = blockIdx.x;
  int xcd = bid & 7, rr = bid >> 3;
  int mloc = rr / nb, nidx = rr - mloc * nb;
  int m0 = (xcd * 32 + mloc) << 7, n0 = nidx << 7;

  f4v z4 = {0.f, 0.f, 0.f, 0.f};
  f4v acc[4][4];
#pragma unroll
  for (int i = 0; i < 4; i++)
#pragma unroll
    for (int j = 0; j < 4; j++) acc[i][j] = z4;

  int co = (lchunk ^ ((lrow >> 1) & 3)) << 3;

  auto STAGE = [&](int t) {
    int slot = t % 3;
    int ko = t << 5;
#pragma unroll
    for (int tt = 0; tt < 2; tt++) {
      int r0 = w * 32 + tt * 16;
      int row = r0 + lrow;
      gl_lds16(A + (size_t)(m0 + row) * K + ko + co, lsA[slot] + r0 * 32);
      gl_lds16(BT + (size_t)(n0 + row) * K + ko + co, lsB[slot] + r0 * 32);
    }
  };
  auto LOADF = [&](int t, s8v* af, s8v* bfr) {
    int slot = t % 3;
    const short* At = lsA[slot] + (wm * 4) * 512 + poff;
    const short* Bt = lsB[slot] + (wn * 4) * 512 + poff;
#pragma unroll
    for (int i = 0; i < 4; i++) {
      af[i] = *(const s8v*)(At + i * 512);
      bfr[i] = *(const s8v*)(Bt + i * 512);
    }
  };

  int NT = K >> 5;
  STAGE(0); STAGE(1);
  asm volatile("s_waitcnt vmcnt(4)" ::: "memory");  // tile 0 landed
  __builtin_amdgcn_s_barrier();
  s8v af[4], bfr[4];
  LOADF(0, af, bfr);
  for (int t = 0; t < NT; ++t) {
    if (t + 2 < NT) STAGE(t + 2);
    __builtin_amdgcn_sched_barrier(0);   // pin VMEM issue before the MFMA burst
#pragma unroll
    for (int i = 0; i < 4; i++)
#pragma unroll
      for (int j = 0; j < 4; j++)
        acc[i][j] = __builtin_amdgcn_mfma_f32_16x16x32_bf16(af[i], bfr[j], acc[i][j], 0, 0, 0);
    if (t + 1 < NT) {
      if (t + 2 < NT) asm volatile("s_waitcnt vmcnt(4)" ::: "memory");  // t+1 landed
      else            asm volatile("s_waitcnt vmcnt(0)" ::: "memory");  // tail
      __builtin_amdgcn_s_barrier();
      LOADF(t + 1, af, bfr);   // frags for next iter; latency covered by backedge
    }
  }
#pragma unroll
  for (int i = 0; i < 4; i++) {
    int gr0 = m0 + wm * 64 + i * 16 + l4 * 4;
#pragma unroll
    for (int j = 0; j < 4; j++) {
      int gc = n0 + wn * 64 + j * 16 + l15;
      float bv = bias[gc];
#pragma unroll
      for (int r = 0; r < 4; r++) {
        float v = acc[i][j][r] + bv;
        if (EPI == 1) {
          // sigmoid-gelu with log2e prefolded: v * sigmoid(1.5958v + 0.07135v^3)
          float tg = v * (-2.3022083f - 0.10294325f * v * v);
          v = v * frcp(1.f + fexp2(tg));
        }
        outb[(size_t)(gr0 + r) * N + gc] = f2bf(v);
      }
    }
  }
}

// --- QK projection: branch-free ring-3 (FF1-proven body). grid 2048. ---
// n0 in [0,1024); output qk row stride 1024; q cols scaled by Q_SCALE.
__global__ __launch_bounds__(256, 3) void qk_proj_k(const short* __restrict__ A,
                                                    const short* __restrict__ BT,
                                                    const float* __restrict__ bias,
                                                    short* __restrict__ qk) {
  __shared__ __align__(16) short lsA[3][4096];
  __shared__ __align__(16) short lsB[3][4096];
  int tid = threadIdx.x, lane = tid & 63, w = tid >> 6;
  int wm = w >> 1, wn = w & 1;
  int l15 = lane & 15, l4 = lane >> 4;
  int lrow = lane >> 2, lchunk = lane & 3;
  int poff = ((l15 << 2) + (l4 ^ ((l15 >> 1) & 3))) << 3;
  int bid = blockIdx.x;
  int xcd = bid & 7, rr = bid >> 3;
  int mloc = rr >> 3, nidx = rr & 7;
  int m0 = (xcd * 32 + mloc) << 7, n0 = nidx << 7;
  bool isQ = (n0 < 512);

  f4v z4 = {0.f, 0.f, 0.f, 0.f};
  f4v acc[4][4];
#pragma unroll
  for (int i = 0; i < 4; i++)
#pragma unroll
    for (int j = 0; j < 4; j++) acc[i][j] = z4;

  int co = (lchunk ^ ((lrow >> 1) & 3)) << 3;

  auto STAGE = [&](int t) {
    int slot = t % 3;
    int ko = t << 5;
#pragma unroll
    for (int tt = 0; tt < 2; tt++) {
      int r0 = w * 32 + tt * 16;
      int row = r0 + lrow;
      gl_lds16(A + (size_t)(m0 + row) * 512 + ko + co, lsA[slot] + r0 * 32);
      gl_lds16(BT + (size_t)(n0 + row) * 512 + ko + co, lsB[slot] + r0 * 32);
    }
  };
  auto LOADF = [&](int t, s8v* af, s8v* bfr) {
    int slot = t % 3;
    const short* At = lsA[slot] + (wm * 4) * 512 + poff;
    const short* Bt = lsB[slot] + (wn * 4) * 512 + poff;
#pragma unroll
    for (int i = 0; i < 4; i++) {
      af[i] = *(const s8v*)(At + i * 512);
      bfr[i] = *(const s8v*)(Bt + i * 512);
    }
  };

  const int NT = 16;
  STAGE(0); STAGE(1);
  asm volatile("s_waitcnt vmcnt(4)" ::: "memory");
  __builtin_amdgcn_s_barrier();
  s8v af[4], bfr[4];
  LOADF(0, af, bfr);
  for (int t = 0; t < NT; ++t) {
    if (t + 2 < NT) STAGE(t + 2);
    __builtin_amdgcn_sched_barrier(0);
#pragma unroll
    for (int i = 0; i < 4; i++)
#pragma unroll
      for (int j = 0; j < 4; j++)
        acc[i][j] = __builtin_amdgcn_mfma_f32_16x16x32_bf16(af[i], bfr[j], acc[i][j], 0, 0, 0);
    if (t + 1 < NT) {
      if (t + 2 < NT) asm volatile("s_waitcnt vmcnt(4)" ::: "memory");
      else            asm volatile("s_waitcnt vmcnt(0)" ::: "memory");
      __builtin_amdgcn_s_barrier();
      LOADF(t + 1, af, bfr);
    }
  }
  float scl = isQ ? Q_SCALE : 1.f;  // fold 1/sqrt(HD)*log2e into q
#pragma unroll
  for (int i = 0; i < 4; i++) {
    int gr0 = m0 + wm * 64 + i * 16 + l4 * 4;
#pragma unroll
    for (int j = 0; j < 4; j++) {
      int gc = n0 + wn * 64 + j * 16 + l15;
      float bv = bias[gc];
#pragma unroll
      for (int r = 0; r < 4; r++)
        qk[(size_t)(gr0 + r) * 1024 + gc] = f2bf(acc[i][j][r] * scl + bv);
    }
  }
}

// --- V projection: ring-3, operand-swapped MFMA -> V^T scatter. grid 1024. ---
__global__ __launch_bounds__(256, 3) void v_proj_k(const short* __restrict__ A,
                                                   const short* __restrict__ BT,
                                                   const float* __restrict__ bias,
                                                   short* __restrict__ vtb) {
  __shared__ __align__(16) short lsA[3][4096];
  __shared__ __align__(16) short lsB[3][4096];
  int tid = threadIdx.x, lane = tid & 63, w = tid >> 6;
  int wm = w >> 1, wn = w & 1;
  int l15 = lane & 15, l4 = lane >> 4;
  int lrow = lane >> 2, lchunk = lane & 3;
  int poff = ((l15 << 2) + (l4 ^ ((l15 >> 1) & 3))) << 3;
  int bid = blockIdx.x;
  int xcd = bid & 7, rr = bid >> 3;
  int mloc = rr >> 2, nidx = rr & 3;
  int m0 = (xcd * 32 + mloc) << 7, n0 = 1024 + (nidx << 7);

  f4v z4 = {0.f, 0.f, 0.f, 0.f};
  f4v acc[4][4];
#pragma unroll
  for (int i = 0; i < 4; i++)
#pragma unroll
    for (int j = 0; j < 4; j++) acc[i][j] = z4;

  int co = (lchunk ^ ((lrow >> 1) & 3)) << 3;

  auto STAGE = [&](int t) {
    int slot = t % 3;
    int ko = t << 5;
#pragma unroll
    for (int tt = 0; tt < 2; tt++) {
      int r0 = w * 32 + tt * 16;
      int row = r0 + lrow;
      gl_lds16(A + (size_t)(m0 + row) * 512 + ko + co, lsA[slot] + r0 * 32);
      gl_lds16(BT + (size_t)(n0 + row) * 512 + ko + co, lsB[slot] + r0 * 32);
    }
  };
  auto LOADF = [&](int t, s8v* af, s8v* bfr) {
    int slot = t % 3;
    const short* At = lsA[slot] + (wm * 4) * 512 + poff;
    const short* Bt = lsB[slot] + (wn * 4) * 512 + poff;
#pragma unroll
    for (int i = 0; i < 4; i++) {
      af[i] = *(const s8v*)(At + i * 512);
      bfr[i] = *(const s8v*)(Bt + i * 512);
    }
  };

  const int NT = 16;
  STAGE(0); STAGE(1);
  asm volatile("s_waitcnt vmcnt(4)" ::: "memory");
  __builtin_amdgcn_s_barrier();
  s8v af[4], bfr[4];
  LOADF(0, af, bfr);
  for (int t = 0; t < NT; ++t) {
    if (t + 2 < NT) STAGE(t + 2);
    __builtin_amdgcn_sched_barrier(0);
#pragma unroll
    for (int j = 0; j < 4; j++)
#pragma unroll
      for (int i = 0; i < 4; i++)
        acc[j][i] = __builtin_amdgcn_mfma_f32_16x16x32_bf16(bfr[j], af[i], acc[j][i], 0, 0, 0);
    if (t + 1 < NT) {
      if (t + 2 < NT) asm volatile("s_waitcnt vmcnt(4)" ::: "memory");
      else            asm volatile("s_waitcnt vmcnt(0)" ::: "memory");
      __builtin_amdgcn_s_barrier();
      LOADF(t + 1, af, bfr);
    }
  }
  int b = m0 >> 10, s0 = m0 & 1023;
#pragma unroll
  for (int j = 0; j < 4; j++) {
    int col = n0 + wn * 64 + j * 16 + l4 * 4;
#pragma unroll
    for (int i = 0; i < 4; i++) {
      int scol = s0 + wm * 64 + i * 16 + l15;
#pragma unroll
      for (int r = 0; r < 4; r++) {
        float v = acc[j][i][r] + bias[col + r];
        vtb[((size_t)b * 512 + col - 1024 + r) * 1024 + scol] = f2bf(v);
      }
    }
  }
}

// ---------------- flash attention (QBLK=128, no-max exp2 softmax, bias-as-C) ----------------
// Swapped QK^T: s^T = mfma(K, Q, bias); P transposed back in registers via
// cvt_pk_bf16 + permlane{32,16}_swap. K/V double-buffered, counted vmcnt(4).
// q & bias pre-scaled by log2e -> softmax uses raw v_exp_f32 (2^x).
__global__ __launch_bounds__(256, 4) void attn_k(const short* __restrict__ qk,
                                                 const short* __restrict__ vt,
                                                 const short* __restrict__ biasNT,
                                                 short* __restrict__ ao) {
  __shared__ __align__(16) short Kl[2][64 * 64];
  __shared__ __align__(16) short Vl[2][64 * 64];
  int tid = threadIdx.x, lane = tid & 63, w = tid >> 6;
  int bid = blockIdx.x;
  int qt = 7 - (bid >> 8), b = (bid >> 3) & 31, h = bid & 7;
  int l15 = lane & 15, l4 = lane >> 4;
  int lrow = lane >> 3, lchunk = lane & 7;

  f4v z4 = {0.f, 0.f, 0.f, 0.f};
  s8v qf[2][2];
#pragma unroll
  for (int g = 0; g < 2; g++) {
    const short* qp = qk + (size_t)(b * 1024 + qt * 128 + g * 64 + w * 16 + l15) * 1024 + h * 64;
    qf[g][0] = *(const s8v*)(qp + l4 * 8);
    qf[g][1] = *(const s8v*)(qp + 32 + l4 * 8);
  }
  f4v o[2][4], lac[2];
#pragma unroll
  for (int g = 0; g < 2; g++) {
    lac[g] = z4;
#pragma unroll
    for (int j = 0; j < 4; j++) o[g][j] = z4;
  }
  s8v ones;
#pragma unroll
  for (int e = 0; e < 8; e++) ones[e] = (short)0x3F80;

  auto STAGE = [&](int buf, int kt) {
#pragma unroll
    for (int t = 0; t < 2; t++) {
      int r0 = (w * 2 + t) * 8;
      int row = r0 + lrow;
      gl_lds16(qk + (size_t)(b * 1024 + kt * 64 + row) * 1024 + 512 + h * 64 +
                   ((lchunk ^ (row & 7)) << 3),
               &Kl[buf][r0 * 64]);
      gl_lds16(vt + (size_t)(b * 512 + h * 64 + row) * 1024 + kt * 64 +
                   ((lchunk ^ (row & 7)) << 3),
               &Vl[buf][r0 * 64]);
    }
  };

  int nkt = 2 * qt + 2;
  STAGE(0, 0);
  for (int kt = 0; kt < nkt; kt++) {
    int cur = kt & 1;
    ushort4 bh[2][4];
#pragma unroll
    for (int g = 0; g < 2; g++) {
      if (kt > 2 * qt + g) continue;
      const short* bp = biasNT + ((size_t)h * 1024 + qt * 128 + g * 64 + w * 16 + l15) * 1024 +
                        kt * 64 + l4 * 4;
#pragma unroll
      for (int j = 0; j < 4; j++) bh[g][j] = *(const ushort4*)(bp + j * 16);
    }
    __builtin_amdgcn_sched_barrier(0);  // keep bias loads ahead of the staging DMA
    if (kt + 1 < nkt) {
      STAGE(cur ^ 1, kt + 1);
      asm volatile("s_waitcnt vmcnt(4)" ::: "memory");
    } else {
      asm volatile("s_waitcnt vmcnt(0)" ::: "memory");
    }
    __builtin_amdgcn_s_barrier();
    const short* Kc = &Kl[cur][0];
    const short* Vc = &Vl[cur][0];
#pragma unroll
    for (int g = 0; g < 2; g++) {
      int diag = 2 * qt + g;
      if (kt > diag) continue;
      f4v s[4];
#pragma unroll
      for (int j = 0; j < 4; j++) {
        f4v bc;
        bc[0] = bf2f(bh[g][j].x); bc[1] = bf2f(bh[g][j].y);
        bc[2] = bf2f(bh[g][j].z); bc[3] = bf2f(bh[g][j].w);
        int kr = j * 16 + l15;
        s8v kf0 = *(const s8v*)(Kc + kr * 64 + ((l4 ^ (kr & 7)) << 3));
        s8v kf1 = *(const s8v*)(Kc + kr * 64 + (((l4 + 4) ^ (kr & 7)) << 3));
        s[j] = __builtin_amdgcn_mfma_f32_16x16x32_bf16(kf0, qf[g][0], bc, 0, 0, 0);
        s[j] = __builtin_amdgcn_mfma_f32_16x16x32_bf16(kf1, qf[g][1], s[j], 0, 0, 0);
      }
      if (kt == diag) {
#pragma unroll
        for (int j = 0; j < 4; j++)
#pragma unroll
          for (int r = 0; r < 4; r++) {
            int kk = j * 16 + l4 * 4 + r, qq = w * 16 + l15;
            s[j][r] = (kk > qq) ? 0.f : fexp2(s[j][r]);
          }
      } else {
#pragma unroll
        for (int j = 0; j < 4; j++)
#pragma unroll
          for (int r = 0; r < 4; r++) s[j][r] = fexp2(s[j][r]);
      }
      unsigned X0[4], X1[4];
#pragma unroll
      for (int j = 0; j < 4; j++) {
        X0[j] = cvtpk(s[j][0], s[j][1]);
        X1[j] = cvtpk(s[j][2], s[j][3]);
      }
      u2v a0 = __builtin_amdgcn_permlane32_swap(X0[0], X0[1], false, false);
      u2v a1 = __builtin_amdgcn_permlane16_swap(a0[0], a0[1], false, false);
      u2v b0 = __builtin_amdgcn_permlane32_swap(X1[0], X1[1], false, false);
      u2v b1 = __builtin_amdgcn_permlane16_swap(b0[0], b0[1], false, false);
      u2v c0 = __builtin_amdgcn_permlane32_swap(X0[2], X0[3], false, false);
      u2v c1 = __builtin_amdgcn_permlane16_swap(c0[0], c0[1], false, false);
      u2v d0 = __builtin_amdgcn_permlane32_swap(X1[2], X1[3], false, false);
      u2v d1 = __builtin_amdgcn_permlane16_swap(d0[0], d0[1], false, false);
      u4v P0 = {a1[0], b1[0], a1[1], b1[1]};  // k 0..31
      u4v P1 = {c1[0], d1[0], c1[1], d1[1]};  // k 32..63
      s8v pf0 = __builtin_bit_cast(s8v, P0);
      s8v pf1 = __builtin_bit_cast(s8v, P1);
      lac[g] = __builtin_amdgcn_mfma_f32_16x16x32_bf16(pf0, ones, lac[g], 0, 0, 0);
      lac[g] = __builtin_amdgcn_mfma_f32_16x16x32_bf16(pf1, ones, lac[g], 0, 0, 0);
#pragma unroll
      for (int j = 0; j < 4; j++) {
        int dr = j * 16 + l15;
        s8v vf0 = *(const s8v*)(Vc + dr * 64 + ((l4 ^ (dr & 7)) << 3));
        s8v vf1 = *(const s8v*)(Vc + dr * 64 + (((l4 + 4) ^ (dr & 7)) << 3));
        o[g][j] = __builtin_amdgcn_mfma_f32_16x16x32_bf16(pf0, vf0, o[g][j], 0, 0, 0);
        o[g][j] = __builtin_amdgcn_mfma_f32_16x16x32_bf16(pf1, vf1, o[g][j], 0, 0, 0);
      }
    }
    __builtin_amdgcn_s_barrier();
  }
#pragma unroll
  for (int g = 0; g < 2; g++)
#pragma unroll
    for (int r = 0; r < 4; r++) {
      float rl = 1.f / lac[g][r];
      int qr = qt * 128 + g * 64 + w * 16 + l4 * 4 + r;
#pragma unroll
      for (int j = 0; j < 4; j++) {
        int d = j * 16 + l15;
        ao[(size_t)(b * 1024 + qr) * 512 + h * 64 + d] = f2bf(o[g][j][r] * rl);
      }
    }
}

// ---------------- head GEMM ----------------
__global__ __launch_bounds__(256) void head_k(const short* __restrict__ X,
                                              const short* __restrict__ hWT,
                                              const float* __restrict__ hb,
                                              float* __restrict__ out) {
  __shared__ __align__(16) short lA[128 * 64];
  int tid = threadIdx.x, lane = tid & 63, w = tid >> 6;
  int l15 = lane & 15, l4 = lane >> 4;
  int lrow = lane >> 3, lchunk = lane & 7;
  int m0 = blockIdx.x * 128;
  f4v z4 = {0.f, 0.f, 0.f, 0.f};
  f4v acc[2][2];
#pragma unroll
  for (int i = 0; i < 2; i++)
#pragma unroll
    for (int j = 0; j < 2; j++) acc[i][j] = z4;

  for (int k0 = 0; k0 < 512; k0 += 64) {
#pragma unroll
    for (int t = 0; t < 4; t++) {
      int r0 = (w * 4 + t) * 8;
      int row = r0 + lrow;
      gl_lds16(X + (size_t)(m0 + row) * 512 + k0 + ((lchunk ^ (row & 7)) << 3), lA + r0 * 64);
    }
    __syncthreads();
#pragma unroll
    for (int kk = 0; kk < 2; kk++) {
      s8v af[2], bfr[2];
#pragma unroll
      for (int i = 0; i < 2; i++) {
        int ra = w * 32 + i * 16 + l15;
        af[i] = *(const s8v*)(lA + ra * 64 + (((l4 + kk * 4) ^ (ra & 7)) << 3));
      }
#pragma unroll
      for (int j = 0; j < 2; j++)
        bfr[j] = *(const s8v*)(hWT + (size_t)(j * 16 + l15) * 512 + k0 + kk * 32 + l4 * 8);
#pragma unroll
      for (int i = 0; i < 2; i++)
#pragma unroll
        for (int j = 0; j < 2; j++)
          acc[i][j] = __builtin_amdgcn_mfma_f32_16x16x32_bf16(af[i], bfr[j], acc[i][j], 0, 0, 0);
    }
    __syncthreads();
  }
#pragma unroll
  for (int i = 0; i < 2; i++) {
#pragma unroll
    for (int j = 0; j < 2; j++) {
      int col = j * 16 + l15;
      if (col < 24) {
        float bv = hb[col];
#pragma unroll
        for (int r = 0; r < 4; r++) {
          int row = m0 + w * 32 + i * 16 + l4 * 4 + r;
          out[(size_t)row * 24 + col] = acc[i][j][r] + bv;
        }
      }
    }
  }
}

// ---------------- launch ----------------
extern "C" void kernel_launch(void* const* d_in, const int* in_sizes, int n_in,
                              void* d_out, int out_size, void* d_ws, size_t ws_size,
                              hipStream_t stream) {
  (void)in_sizes; (void)n_in; (void)out_size;
  const float* theta   = (const float*)d_in[0];
  const float* cond    = (const float*)d_in[1];
  const float* attn_b  = (const float*)d_in[2];
  const float* embed_W = (const float*)d_in[3];
  const float* embed_b = (const float*)d_in[4];
  const float* ln1_g   = (const float*)d_in[5];
  const float* ln1_b   = (const float*)d_in[6];
  const float* ada1_W  = (const float*)d_in[7];
  const float* ada1_b  = (const float*)d_in[8];
  const float* Wq      = (const float*)d_in[9];
  const float* bq      = (const float*)d_in[10];
  const float* Wk      = (const float*)d_in[11];
  const float* bk      = (const float*)d_in[12];
  const float* Wv      = (const float*)d_in[13];
  const float* bv      = (const float*)d_in[14];
  const float* Wo      = (const float*)d_in[15];
  const float* bo      = (const float*)d_in[16];
  const float* ln2_g   = (const float*)d_in[17];
  const float* ln2_b   = (const float*)d_in[18];
  const float* ada2_W  = (const float*)d_in[19];
  const float* ada2_b  = (const float*)d_in[20];
  const float* W1      = (const float*)d_in[21];
  const float* b1      = (const float*)d_in[22];
  const float* W2      = (const float*)d_in[23];
  const float* b2      = (const float*)d_in[24];
  const float* fn_g    = (const float*)d_in[25];
  const float* fn_b    = (const float*)d_in[26];
  const float* head_W  = (const float*)d_in[27];
  const float* head_b  = (const float*)d_in[28];

  const size_t REQ = 242814976ull;
  const size_t REQ2 = 259592192ull;
  if (ws_size < REQ) return;
  bool bias_once = (ws_size >= REQ2);

  char* ws = (char*)d_ws;
  float* xw    = (float*)(ws + 0ull);
  short* qk    = (short*)(ws + 67108864ull);
  short* vtb   = (short*)(ws + 134217728ull);   // V^T, then Wo-delta
  short* biasT = (short*)(ws + (bias_once ? 242814976ull : 167772160ull));
  short* qf    = (short*)(ws + 67108864ull);
  short* hbuf  = (short*)(ws + 201326592ull);   // adaln out / attn out / FF2 delta
  short* wbf   = (short*)(ws + 234881024ull);
  float* ssb   = (float*)(ws + 241172480ull);
  float* bqkv  = (float*)(ws + 242745344ull);
  short* hWT   = (short*)(ws + 242782208ull);

  concat_qkvb_k<<<6, 256, 0, stream>>>(bq, bk, bv, bqkv);
  cond_proj_k<<<dim3(4, 12), 256, 0, stream>>>(cond, ada1_W, ada1_b, ada2_W, ada2_b, ssb);
  hwt_k<<<64, 256, 0, stream>>>(head_W, hWT);
  embed_k<<<8192, 256, 0, stream>>>(theta, embed_W, embed_b, xw);
  if (bias_once) bias_cvt_k<<<8192, 256, 0, stream>>>(attn_b, biasT);

  for (int l = 0; l < 6; l++) {
    transpose_all_k<<<3072, 256, 0, stream>>>(Wq, Wk, Wv, Wo, W1, W2, l, wbf);
    if (!bias_once) bias_cvt_k<<<8192, 256, 0, stream>>>(attn_b, biasT);

    if (l == 0)
      adaln_k<false><<<8192, 256, 0, stream>>>(xw, nullptr, ssb + (size_t)(l * 2) * 32768,
                                               ln1_g + l * 512, ln1_b + l * 512, hbuf);
    else  // delta = FF2 delta from layer l-1, lives in hbuf; h also hbuf (safe)
      adaln_k<true><<<8192, 256, 0, stream>>>(xw, hbuf, ssb + (size_t)(l * 2) * 32768,
                                              ln1_g + l * 512, ln1_b + l * 512, hbuf);
    qk_proj_k<<<2048, 256, 0, stream>>>(hbuf, wbf, bqkv + l * 1536, qk);
    v_proj_k<<<1024, 256, 0, stream>>>(hbuf, wbf, bqkv + l * 1536, vtb);
    attn_k<<<2048, 256, 0, stream>>>(qk, vtb, biasT, hbuf);
    // Wo: delta = attn_out @ Wo^T + bo -> vtb (dead V^T); folded IMMEDIATELY
    // by adaln2 (vtb must not outlive FF1 - qf overwrites its region)
    gemm_r3_k<0><<<1024, 256, 0, stream>>>(hbuf, wbf + 786432, bo + l * 512, vtb, 512, 512);
    adaln_k<true><<<8192, 256, 0, stream>>>(xw, vtb, ssb + (size_t)(l * 2 + 1) * 32768,
                                            ln2_g + l * 512, ln2_b + l * 512, hbuf);
    // FF1: ring-3 (exp2-gelu epilogue)
    gemm_r3_k<1><<<4096, 256, 0, stream>>>(hbuf, wbf + 1048576, b1 + l * 2048, qf, 2048, 512);
    // FF2: delta -> hbuf (disjoint from qf); folded by next adaln1 / fln
    gemm_r3_k<0><<<1024, 256, 0, stream>>>(qf, wbf + 2097152, b2 + l * 512, hbuf, 512, 2048);
  }
  fln_k<<<8192, 256, 0, stream>>>(xw, hbuf, fn_g, fn_b, hbuf);
  head_k<<<256, 256, 0, stream>>>(hbuf, hWT, head_b, (float*)d_out);
}

// Round 15
// 2601.016 us; speedup vs baseline: 1.0272x; 1.0239x over previous
//
#include <hip/hip_runtime.h>

// ContinuousLatticeGPT: B=32 S=1024 D=512 H=8 NL=6 DFF=2048 C=128 K=8
// bf16 MFMA; fp32 residual stream with deferred (bf16 delta) residual adds.
// r15 = r11/r14 config + FF1 widened to 128x256 tile (8 waves, ring-3, 72KB LDS,
// 2 blk/CU = 16 waves/CU): halves barrier cost per FLOP, staging bytes/FLOP -25%.
// Same sync structure as the proven ring-3 template (counted vmcnt: 3 loads/thread
// per tile -> vmcnt(3) steady, 0 tail). Wo/FF2/qk_proj/v_proj unchanged.
//  - gelu epilogue (FF1): log2e folded into sigmoid-gelu constants -> raw
//    v_exp_f32 + v_rcp_f32 (r11: -96us, VALUBusy 48->38%).
// All GEMMs: lane-adjacent 64B-row staging + chunk^=((row>>1)&3) swizzle
// (TA-coalesced AND bank-conflict-free).
// attn: swapped-QK (mfma(K,Q)) with in-register P transpose via cvt_pk+permlane;
// exp2-folded softmax (log2e in q-scale & bias). No setprio (r9: +12us).
// Delta routing: Wo-delta -> vtb (dead V^T), folded IMMEDIATELY by adaln2
// (r13 lesson: vtb must NOT outlive FF1 - qf overwrites its region);
// FF2-delta -> hbuf (dead FF1 input, disjoint from qf), folded next adaln1/fln.
// ws layout (bytes): unchanged. REQ 242,814,976 B

typedef short s8v __attribute__((ext_vector_type(8)));
typedef float f4v __attribute__((ext_vector_type(4)));
typedef unsigned u2v __attribute__((ext_vector_type(2)));
typedef unsigned u4v __attribute__((ext_vector_type(4)));

#define Q_SCALE 0.18033688011112042f  // 0.125 * log2(e)
#define LOG2E   1.4426950408889634f

static __device__ __forceinline__ short f2bf(float f) {
  union { float f; unsigned u; } v; v.f = f;
  unsigned r = v.u + 0x7fffu + ((v.u >> 16) & 1u);
  return (short)(r >> 16);
}
static __device__ __forceinline__ float bf2f(unsigned short s) {
  union { unsigned u; float f; } v; v.u = ((unsigned)s) << 16;
  return v.f;
}
static __device__ __forceinline__ unsigned cvtpk(float lo, float hi) {
  unsigned r;
  asm("v_cvt_pk_bf16_f32 %0, %1, %2" : "=v"(r) : "v"(lo), "v"(hi));
  return r;
}
static __device__ __forceinline__ float fexp2(float x) {  // 2^x, single v_exp_f32
  float r;
  asm("v_exp_f32 %0, %1" : "=v"(r) : "v"(x));
  return r;
}
static __device__ __forceinline__ float frcp(float x) {  // ~1ulp reciprocal
  float r;
  asm("v_rcp_f32 %0, %1" : "=v"(r) : "v"(x));
  return r;
}
static __device__ __forceinline__ void gl_lds16(const short* g, short* l) {
  __builtin_amdgcn_global_load_lds(
      (const __attribute__((address_space(1))) unsigned int*)g,
      (__attribute__((address_space(3))) unsigned int*)l, 16, 0, 0);
}

// ---------------- prep kernels ----------------
__global__ void transpose_all_k(const float* __restrict__ Wq, const float* __restrict__ Wk,
                                const float* __restrict__ Wv, const float* __restrict__ Wo,
                                const float* __restrict__ W1, const float* __restrict__ W2,
                                int l, short* __restrict__ wbf) {
  int id = blockIdx.x;
  const float* in; short* out; int K, N, tx, ty;
  if (id < 1024) {
    int m = id >> 8, t = id & 255;
    in = (m == 0 ? Wq : m == 1 ? Wk : m == 2 ? Wv : Wo) + (size_t)l * 262144;
    out = wbf + (size_t)m * 262144;
    K = 512; N = 512; tx = t & 15; ty = t >> 4;
  } else if (id < 2048) {
    int t = id - 1024;
    in = W1 + (size_t)l * 1048576; out = wbf + 1048576;
    K = 512; N = 2048; tx = t & 63; ty = t >> 6;
  } else {
    int t = id - 2048;
    in = W2 + (size_t)l * 1048576; out = wbf + 2097152;
    K = 2048; N = 512; tx = t & 15; ty = t >> 4;
  }
  __shared__ float tb[32][33];
  int n0 = tx * 32, k0 = ty * 32;
  int cx = threadIdx.x & 31, cy = threadIdx.x >> 5;
#pragma unroll
  for (int r = 0; r < 4; r++)
    tb[cy + r * 8][cx] = in[(size_t)(k0 + cy + r * 8) * N + n0 + cx];
  __syncthreads();
#pragma unroll
  for (int r = 0; r < 4; r++)
    out[(size_t)(n0 + cy + r * 8) * K + k0 + cx] = f2bf(tb[cx][cy + r * 8]);
}

// f32 -> bf16 copy of attn_bias, folding log2(e) for the exp2 softmax
__global__ void bias_cvt_k(const float* __restrict__ in, short* __restrict__ out) {
  int i = blockIdx.x * 256 + threadIdx.x;  // float4 index; grid covers 8M floats
  float4 v = ((const float4*)in)[i];
  ushort4 o;
  o.x = (unsigned short)f2bf(v.x * LOG2E);
  o.y = (unsigned short)f2bf(v.y * LOG2E);
  o.z = (unsigned short)f2bf(v.z * LOG2E);
  o.w = (unsigned short)f2bf(v.w * LOG2E);
  ((ushort4*)out)[i] = o;
}

__global__ void hwt_k(const float* __restrict__ hW, short* __restrict__ hWT) {
  int i = blockIdx.x * 256 + threadIdx.x;
  int n = i >> 9, k = i & 511;
  hWT[i] = (n < 24) ? f2bf(hW[(size_t)k * 24 + n]) : (short)0;
}

__global__ void concat_qkvb_k(const float* bq, const float* bk, const float* bv, float* out) {
  int l = blockIdx.x;
  for (int i = threadIdx.x; i < 1536; i += 256) {
    float v = (i < 512) ? bq[l * 512 + i] * Q_SCALE  // fold 1/sqrt(HD)*log2e into q bias
            : (i < 1024 ? bk[l * 512 + i - 512] : bv[l * 512 + i - 1024]);
    out[l * 1536 + i] = v;
  }
}

__global__ void cond_proj_k(const float* __restrict__ cond,
                            const float* __restrict__ a1W, const float* __restrict__ a1b,
                            const float* __restrict__ a2W, const float* __restrict__ a2b,
                            float* __restrict__ ss) {
  int lw = blockIdx.y, which = lw & 1, l = lw >> 1;
  const float* W = (which ? a2W : a1W) + (size_t)l * 128 * 1024;
  const float* bb = (which ? a2b : a1b) + (size_t)l * 1024;
  __shared__ float cs[32 * 128];
  for (int i = threadIdx.x; i < 32 * 128; i += 256) cs[i] = cond[i];
  __syncthreads();
  int n = blockIdx.x * 256 + threadIdx.x;
  float bias = bb[n];
  for (int g = 0; g < 4; g++) {
    float acc[8];
#pragma unroll
    for (int i = 0; i < 8; i++) acc[i] = 0.f;
    for (int c = 0; c < 128; c++) {
      float w = W[(size_t)c * 1024 + n];
#pragma unroll
      for (int i = 0; i < 8; i++) acc[i] += cs[(g * 8 + i) * 128 + c] * w;
    }
#pragma unroll
    for (int i = 0; i < 8; i++)
      ss[((size_t)lw * 32 + g * 8 + i) * 1024 + n] = acc[i] + bias;
  }
}

__global__ void embed_k(const float* __restrict__ theta, const float* __restrict__ eW,
                        const float* __restrict__ eb, float* __restrict__ x) {
  int row = blockIdx.x * 4 + (threadIdx.x >> 6), lane = threadIdx.x & 63;
  float th = theta[row], sn, cn;
  sincosf(th, &sn, &cn);
  int d = lane * 8;
  float* xo = x + (size_t)row * 512 + d;
#pragma unroll
  for (int i = 0; i < 8; i++) xo[i] = cn * eW[d + i] + sn * eW[512 + d + i] + eb[d + i];
}

// AdaLN; optionally folds a deferred bf16 residual delta (may ALIAS h!) and updates xw.
template<bool HASDEL>
__global__ void adaln_k(float* __restrict__ x, const short* delta,
                        const float* __restrict__ ss,
                        const float* __restrict__ g, const float* __restrict__ be,
                        short* h) {
  int row = blockIdx.x * 4 + (threadIdx.x >> 6), lane = threadIdx.x & 63;
  int b = row >> 10;
  float* xr = x + (size_t)row * 512 + lane * 8;
  float4 va = ((const float4*)xr)[0], vb = ((const float4*)xr)[1];
  float v[8] = {va.x, va.y, va.z, va.w, vb.x, vb.y, vb.z, vb.w};
  if (HASDEL) {
    s8v dv = *(const s8v*)(delta + (size_t)row * 512 + lane * 8);
#pragma unroll
    for (int i = 0; i < 8; i++) v[i] += bf2f((unsigned short)dv[i]);
    float4 o0 = {v[0], v[1], v[2], v[3]}, o1 = {v[4], v[5], v[6], v[7]};
    ((float4*)xr)[0] = o0; ((float4*)xr)[1] = o1;
  }
  float sm = 0.f;
#pragma unroll
  for (int i = 0; i < 8; i++) sm += v[i];
#pragma unroll
  for (int off = 1; off < 64; off <<= 1) sm += __shfl_xor(sm, off);
  float mean = sm * (1.f / 512.f);
  float sq = 0.f;
#pragma unroll
  for (int i = 0; i < 8; i++) { float d = v[i] - mean; sq += d * d; }
#pragma unroll
  for (int off = 1; off < 64; off <<= 1) sq += __shfl_xor(sq, off);
  float rs = rsqrtf(sq * (1.f / 512.f) + 1e-5f);
  const float* sb = ss + (size_t)b * 1024 + lane * 8;
  const float* gp = g + lane * 8;
  const float* bp = be + lane * 8;
  s8v o;
#pragma unroll
  for (int i = 0; i < 8; i++) {
    float xh = (v[i] - mean) * rs * gp[i] + bp[i];
    o[i] = f2bf((1.f + sb[i]) * xh + sb[i + 512]);
  }
  *(s8v*)(h + (size_t)row * 512 + lane * 8) = o;
}

// final LN, folding FF2's delta (delta may ALIAS h)
__global__ void fln_k(const float* __restrict__ x, const short* delta,
                      const float* __restrict__ g, const float* __restrict__ be,
                      short* h) {
  int row = blockIdx.x * 4 + (threadIdx.x >> 6), lane = threadIdx.x & 63;
  const float* xr = x + (size_t)row * 512 + lane * 8;
  float4 va = ((const float4*)xr)[0], vb = ((const float4*)xr)[1];
  float v[8] = {va.x, va.y, va.z, va.w, vb.x, vb.y, vb.z, vb.w};
  s8v dv = *(const s8v*)(delta + (size_t)row * 512 + lane * 8);
#pragma unroll
  for (int i = 0; i < 8; i++) v[i] += bf2f((unsigned short)dv[i]);
  float sm = 0.f;
#pragma unroll
  for (int i = 0; i < 8; i++) sm += v[i];
#pragma unroll
  for (int off = 1; off < 64; off <<= 1) sm += __shfl_xor(sm, off);
  float mean = sm * (1.f / 512.f);
  float sq = 0.f;
#pragma unroll
  for (int i = 0; i < 8; i++) { float d = v[i] - mean; sq += d * d; }
#pragma unroll
  for (int off = 1; off < 64; off <<= 1) sq += __shfl_xor(sq, off);
  float rs = rsqrtf(sq * (1.f / 512.f) + 1e-5f);
  const float* gp = g + lane * 8;
  const float* bp = be + lane * 8;
  s8v o;
#pragma unroll
  for (int i = 0; i < 8; i++) o[i] = f2bf((v[i] - mean) * rs * gp[i] + bp[i]);
  *(s8v*)(h + (size_t)row * 512 + lane * 8) = o;
}

// --- GEMM 128x128, BK=32, ring-3 + register-frag prefetch (Wo/FF2) ---
// iter t: STAGE(t+2) -> 16 MFMA on in-reg frags (zero wait) -> counted vmcnt
// -> barrier -> ds_read frags(t+1). EPI 0: bf16 (+bias); 1: gelu bf16.
template<int EPI>
__global__ __launch_bounds__(256, 3) void gemm_r3_k(const short* __restrict__ A,
                                                    const short* __restrict__ BT,
                                                    const float* __restrict__ bias,
                                                    short* __restrict__ outb,
                                                    int N, int K) {
  __shared__ __align__(16) short lsA[3][4096];  // 3 x 8KB
  __shared__ __align__(16) short lsB[3][4096];
  int tid = threadIdx.x, lane = tid & 63, w = tid >> 6;
  int wm = w >> 1, wn = w & 1;
  int l15 = lane & 15, l4 = lane >> 4;
  int lrow = lane >> 2, lchunk = lane & 3;
  int poff = ((l15 << 2) + (l4 ^ ((l15 >> 1) & 3))) << 3;
  int nb = N >> 7;
  int bid = blockIdx.x;
  int xcd = bid & 7, rr = bid >> 3;
  int mloc = rr / nb, nidx = rr - mloc * nb;
  int m0 = (xcd * 32 + mloc) << 7, n0 = nidx << 7;

  f4v z4 = {0.f, 0.f, 0.f, 0.f};
  f4v acc[4][4];
#pragma unroll
  for (int i = 0; i < 4; i++)
#pragma unroll
    for (int j = 0; j < 4; j++) acc[i][j] = z4;

  int co = (lchunk ^ ((lrow >> 1) & 3)) << 3;

  auto STAGE = [&](int t) {
    int slot = t % 3;
    int ko = t << 5;
#pragma unroll
    for (int tt = 0; tt < 2; tt++) {
      int r0 = w * 32 + tt * 16;
      int row = r0 + lrow;
      gl_lds16(A + (size_t)(m0 + row) * K + ko + co, lsA[slot] + r0 * 32);
      gl_lds16(BT + (size_t)(n0 + row) * K + ko + co, lsB[slot] + r0 * 32);
    }
  };
  auto LOADF = [&](int t, s8v* af, s8v* bfr) {
    int slot = t % 3;
    const short* At = lsA[slot] + (wm * 4) * 512 + poff;
    const short* Bt = lsB[slot] + (wn * 4) * 512 + poff;
#pragma unroll
    for (int i = 0; i < 4; i++) {
      af[i] = *(const s8v*)(At + i * 512);
      bfr[i] = *(const s8v*)(Bt + i * 512);
    }
  };

  int NT = K >> 5;
  STAGE(0); STAGE(1);
  asm volatile("s_waitcnt vmcnt(4)" ::: "memory");  // tile 0 landed
  __builtin_amdgcn_s_barrier();
  s8v af[4], bfr[4];
  LOADF(0, af, bfr);
  for (int t = 0; t < NT; ++t) {
    if (t + 2 < NT) STAGE(t + 2);
    __builtin_amdgcn_sched_barrier(0);   // pin VMEM issue before the MFMA burst
#pragma unroll
    for (int i = 0; i < 4; i++)
#pragma unroll
      for (int j = 0; j < 4; j++)
        acc[i][j] = __builtin_amdgcn_mfma_f32_16x16x32_bf16(af[i], bfr[j], acc[i][j], 0, 0, 0);
    if (t + 1 < NT) {
      if (t + 2 < NT) asm volatile("s_waitcnt vmcnt(4)" ::: "memory");  // t+1 landed
      else            asm volatile("s_waitcnt vmcnt(0)" ::: "memory");  // tail
      __builtin_amdgcn_s_barrier();
      LOADF(t + 1, af, bfr);   // frags for next iter; latency covered by backedge
    }
  }
#pragma unroll
  for (int i = 0; i < 4; i++) {
    int gr0 = m0 + wm * 64 + i * 16 + l4 * 4;
#pragma unroll
    for (int j = 0; j < 4; j++) {
      int gc = n0 + wn * 64 + j * 16 + l15;
      float bv = bias[gc];
#pragma unroll
      for (int r = 0; r < 4; r++) {
        float v = acc[i][j][r] + bv;
        if (EPI == 1) {
          float tg = v * (-2.3022083f - 0.10294325f * v * v);
          v = v * frcp(1.f + fexp2(tg));
        }
        outb[(size_t)(gr0 + r) * N + gc] = f2bf(v);
      }
    }
  }
}

// --- FF1 GEMM 128x256, BK=32, ring-3, 512 thr (8 waves 2Mx4N), 72KB LDS ---
// Same sync structure as gemm_r3_k; 32 MFMAs per barrier-pair (2x), staging
// bytes/FLOP -25% (B staged once for 2x compute), 2 blk/CU = 16 waves/CU.
// Staging: 384 rows (128 A + 256 B) x 64B; thread covers 3 lane-adjacent 16B
// chunks; per-(w,tt) A/B choice is wave-uniform (boundary 128 = 2*48+32 exact).
// Counted vmcnt: 3 loads/thread/tile -> vmcnt(3) steady, vmcnt(0) tail.
template<int EPI>
__global__ __launch_bounds__(512, 2) void gemm_ff1_k(const short* __restrict__ A,
                                                     const short* __restrict__ BT,
                                                     const float* __restrict__ bias,
                                                     short* __restrict__ outb,
                                                     int N, int K) {
  __shared__ __align__(16) short lsA[3][4096];  // 3 x 8KB  (128 rows)
  __shared__ __align__(16) short lsB[3][8192];  // 3 x 16KB (256 rows)
  int tid = threadIdx.x, lane = tid & 63, w = tid >> 6;  // w in [0,8)
  int wm = w >> 2, wn = w & 3;                            // 2M x 4N waves
  int l15 = lane & 15, l4 = lane >> 4;
  int lrow = lane >> 2, lchunk = lane & 3;
  int poff = ((l15 << 2) + (l4 ^ ((l15 >> 1) & 3))) << 3;
  int nb = N >> 8;                                        // 256-wide N tiles
  int bid = blockIdx.x;
  int xcd = bid & 7, rr = bid >> 3;
  int mloc = rr / nb, nidx = rr - mloc * nb;
  int m0 = (xcd * 32 + mloc) << 7, n0 = nidx << 8;

  f4v z4 = {0.f, 0.f, 0.f, 0.f};
  f4v acc[4][4];
#pragma unroll
  for (int i = 0; i < 4; i++)
#pragma unroll
    for (int j = 0; j < 4; j++) acc[i][j] = z4;

  int co = (lchunk ^ ((lrow >> 1) & 3)) << 3;

  auto STAGE = [&](int t) {  // 3 DMA ops per thread; 384 rows total
    int slot = t % 3;
    int ko = t << 5;
#pragma unroll
    for (int tt = 0; tt < 3; tt++) {
      int r0 = w * 48 + tt * 16;          // wave-uniform; 0..368 step 16
      int row = r0 + lrow;
      if (r0 < 128) {                      // A rows [0,128)
        gl_lds16(A + (size_t)(m0 + row) * K + ko + co, lsA[slot] + r0 * 32);
      } else {                             // B rows [0,256)
        int rb = row - 128;
        gl_lds16(BT + (size_t)(n0 + rb) * K + ko + co, lsB[slot] + (r0 - 128) * 32);
      }
    }
  };
  auto LOADF = [&](int t, s8v* af, s8v* bfr) {
    int slot = t % 3;
    const short* At = lsA[slot] + (wm * 4) * 512 + poff;
    const short* Bt = lsB[slot] + (wn * 4) * 512 + poff;
#pragma unroll
    for (int i = 0; i < 4; i++) {
      af[i] = *(const s8v*)(At + i * 512);
      bfr[i] = *(const s8v*)(Bt + i * 512);
    }
  };

  int NT = K >> 5;
  STAGE(0); STAGE(1);
  asm volatile("s_waitcnt vmcnt(3)" ::: "memory");  // tile 0 landed
  __builtin_amdgcn_s_barrier();
  s8v af[4], bfr[4];
  LOADF(0, af, bfr);
  for (int t = 0; t < NT; ++t) {
    if (t + 2 < NT) STAGE(t + 2);
    __builtin_amdgcn_sched_barrier(0);   // pin VMEM issue before the MFMA burst
#pragma unroll
    for (int i = 0; i < 4; i++)
#pragma unroll
      for (int j = 0; j < 4; j++)
        acc[i][j] = __builtin_amdgcn_mfma_f32_16x16x32_bf16(af[i], bfr[j], acc[i][j], 0, 0, 0);
    if (t + 1 < NT) {
      if (t + 2 < NT) asm volatile("s_waitcnt vmcnt(3)" ::: "memory");  // t+1 landed
      else            asm volatile("s_waitcnt vmcnt(0)" ::: "memory");  // tail
      __builtin_amdgcn_s_barrier();
      LOADF(t + 1, af, bfr);   // frags for next iter; latency covered by backedge
    }
  }
#pragma unroll
  for (int i = 0; i < 4; i++) {
    int gr0 = m0 + wm * 64 + i * 16 + l4 * 4;
#pragma unroll
    for (int j = 0; j < 4; j++) {
      int gc = n0 + wn * 64 + j * 16 + l15;
      float bv = bias[gc];
#pragma unroll
      for (int r = 0; r < 4; r++) {
        float v = acc[i][j][r] + bv;
        if (EPI == 1) {
          // sigmoid-gelu with log2e prefolded: v * sigmoid(1.5958v + 0.07135v^3)
          float tg = v * (-2.3022083f - 0.10294325f * v * v);
          v = v * frcp(1.f + fexp2(tg));
        }
        outb[(size_t)(gr0 + r) * N + gc] = f2bf(v);
      }
    }
  }
}

// --- QK projection: branch-free ring-3 (FF1-proven body). grid 2048. ---
// n0 in [0,1024); output qk row stride 1024; q cols scaled by Q_SCALE.
__global__ __launch_bounds__(256, 3) void qk_proj_k(const short* __restrict__ A,
                                                    const short* __restrict__ BT,
                                                    const float* __restrict__ bias,
                                                    short* __restrict__ qk) {
  __shared__ __align__(16) short lsA[3][4096];
  __shared__ __align__(16) short lsB[3][4096];
  int tid = threadIdx.x, lane = tid & 63, w = tid >> 6;
  int wm = w >> 1, wn = w & 1;
  int l15 = lane & 15, l4 = lane >> 4;
  int lrow = lane >> 2, lchunk = lane & 3;
  int poff = ((l15 << 2) + (l4 ^ ((l15 >> 1) & 3))) << 3;
  int bid = blockIdx.x;
  int xcd = bid & 7, rr = bid >> 3;
  int mloc = rr >> 3, nidx = rr & 7;
  int m0 = (xcd * 32 + mloc) << 7, n0 = nidx << 7;
  bool isQ = (n0 < 512);

  f4v z4 = {0.f, 0.f, 0.f, 0.f};
  f4v acc[4][4];
#pragma unroll
  for (int i = 0; i < 4; i++)
#pragma unroll
    for (int j = 0; j < 4; j++) acc[i][j] = z4;

  int co = (lchunk ^ ((lrow >> 1) & 3)) << 3;

  auto STAGE = [&](int t) {
    int slot = t % 3;
    int ko = t << 5;
#pragma unroll
    for (int tt = 0; tt < 2; tt++) {
      int r0 = w * 32 + tt * 16;
      int row = r0 + lrow;
      gl_lds16(A + (size_t)(m0 + row) * 512 + ko + co, lsA[slot] + r0 * 32);
      gl_lds16(BT + (size_t)(n0 + row) * 512 + ko + co, lsB[slot] + r0 * 32);
    }
  };
  auto LOADF = [&](int t, s8v* af, s8v* bfr) {
    int slot = t % 3;
    const short* At = lsA[slot] + (wm * 4) * 512 + poff;
    const short* Bt = lsB[slot] + (wn * 4) * 512 + poff;
#pragma unroll
    for (int i = 0; i < 4; i++) {
      af[i] = *(const s8v*)(At + i * 512);
      bfr[i] = *(const s8v*)(Bt + i * 512);
    }
  };

  const int NT = 16;
  STAGE(0); STAGE(1);
  asm volatile("s_waitcnt vmcnt(4)" ::: "memory");
  __builtin_amdgcn_s_barrier();
  s8v af[4], bfr[4];
  LOADF(0, af, bfr);
  for (int t = 0; t < NT; ++t) {
    if (t + 2 < NT) STAGE(t + 2);
    __builtin_amdgcn_sched_barrier(0);
#pragma unroll
    for (int i = 0; i < 4; i++)
#pragma unroll
      for (int j = 0; j < 4; j++)
        acc[i][j] = __builtin_amdgcn_mfma_f32_16x16x32_bf16(af[i], bfr[j], acc[i][j], 0, 0, 0);
    if (t + 1 < NT) {
      if (t + 2 < NT) asm volatile("s_waitcnt vmcnt(4)" ::: "memory");
      else            asm volatile("s_waitcnt vmcnt(0)" ::: "memory");
      __builtin_amdgcn_s_barrier();
      LOADF(t + 1, af, bfr);
    }
  }
  float scl = isQ ? Q_SCALE : 1.f;  // fold 1/sqrt(HD)*log2e into q
#pragma unroll
  for (int i = 0; i < 4; i++) {
    int gr0 = m0 + wm * 64 + i * 16 + l4 * 4;
#pragma unroll
    for (int j = 0; j < 4; j++) {
      int gc = n0 + wn * 64 + j * 16 + l15;
      float bv = bias[gc];
#pragma unroll
      for (int r = 0; r < 4; r++)
        qk[(size_t)(gr0 + r) * 1024 + gc] = f2bf(acc[i][j][r] * scl + bv);
    }
  }
}

// --- V projection: ring-3, operand-swapped MFMA -> V^T scatter. grid 1024. ---
__global__ __launch_bounds__(256, 3) void v_proj_k(const short* __restrict__ A,
                                                   const short* __restrict__ BT,
                                                   const float* __restrict__ bias,
                                                   short* __restrict__ vtb) {
  __shared__ __align__(16) short lsA[3][4096];
  __shared__ __align__(16) short lsB[3][4096];
  int tid = threadIdx.x, lane = tid & 63, w = tid >> 6;
  int wm = w >> 1, wn = w & 1;
  int l15 = lane & 15, l4 = lane >> 4;
  int lrow = lane >> 2, lchunk = lane & 3;
  int poff = ((l15 << 2) + (l4 ^ ((l15 >> 1) & 3))) << 3;
  int bid = blockIdx.x;
  int xcd = bid & 7, rr = bid >> 3;
  int mloc = rr >> 2, nidx = rr & 3;
  int m0 = (xcd * 32 + mloc) << 7, n0 = 1024 + (nidx << 7);

  f4v z4 = {0.f, 0.f, 0.f, 0.f};
  f4v acc[4][4];
#pragma unroll
  for (int i = 0; i < 4; i++)
#pragma unroll
    for (int j = 0; j < 4; j++) acc[i][j] = z4;

  int co = (lchunk ^ ((lrow >> 1) & 3)) << 3;

  auto STAGE = [&](int t) {
    int slot = t % 3;
    int ko = t << 5;
#pragma unroll
    for (int tt = 0; tt < 2; tt++) {
      int r0 = w * 32 + tt * 16;
      int row = r0 + lrow;
      gl_lds16(A + (size_t)(m0 + row) * 512 + ko + co, lsA[slot] + r0 * 32);
      gl_lds16(BT + (size_t)(n0 + row) * 512 + ko + co, lsB[slot] + r0 * 32);
    }
  };
  auto LOADF = [&](int t, s8v* af, s8v* bfr) {
    int slot = t % 3;
    const short* At = lsA[slot] + (wm * 4) * 512 + poff;
    const short* Bt = lsB[slot] + (wn * 4) * 512 + poff;
#pragma unroll
    for (int i = 0; i < 4; i++) {
      af[i] = *(const s8v*)(At + i * 512);
      bfr[i] = *(const s8v*)(Bt + i * 512);
    }
  };

  const int NT = 16;
  STAGE(0); STAGE(1);
  asm volatile("s_waitcnt vmcnt(4)" ::: "memory");
  __builtin_amdgcn_s_barrier();
  s8v af[4], bfr[4];
  LOADF(0, af, bfr);
  for (int t = 0; t < NT; ++t) {
    if (t + 2 < NT) STAGE(t + 2);
    __builtin_amdgcn_sched_barrier(0);
#pragma unroll
    for (int j = 0; j < 4; j++)
#pragma unroll
      for (int i = 0; i < 4; i++)
        acc[j][i] = __builtin_amdgcn_mfma_f32_16x16x32_bf16(bfr[j], af[i], acc[j][i], 0, 0, 0);
    if (t + 1 < NT) {
      if (t + 2 < NT) asm volatile("s_waitcnt vmcnt(4)" ::: "memory");
      else            asm volatile("s_waitcnt vmcnt(0)" ::: "memory");
      __builtin_amdgcn_s_barrier();
      LOADF(t + 1, af, bfr);
    }
  }
  int b = m0 >> 10, s0 = m0 & 1023;
#pragma unroll
  for (int j = 0; j < 4; j++) {
    int col = n0 + wn * 64 + j * 16 + l4 * 4;
#pragma unroll
    for (int i = 0; i < 4; i++) {
      int scol = s0 + wm * 64 + i * 16 + l15;
#pragma unroll
      for (int r = 0; r < 4; r++) {
        float v = acc[j][i][r] + bias[col + r];
        vtb[((size_t)b * 512 + col - 1024 + r) * 1024 + scol] = f2bf(v);
      }
    }
  }
}

// ---------------- flash attention (QBLK=128, no-max exp2 softmax, bias-as-C) ----------------
// Swapped QK^T: s^T = mfma(K, Q, bias); P transposed back in registers via
// cvt_pk_bf16 + permlane{32,16}_swap. K/V double-buffered, counted vmcnt(4).
// q & bias pre-scaled by log2e -> softmax uses raw v_exp_f32 (2^x).
__global__ __launch_bounds__(256, 4) void attn_k(const short* __restrict__ qk,
                                                 const short* __restrict__ vt,
                                                 const short* __restrict__ biasNT,
                                                 short* __restrict__ ao) {
  __shared__ __align__(16) short Kl[2][64 * 64];
  __shared__ __align__(16) short Vl[2][64 * 64];
  int tid = threadIdx.x, lane = tid & 63, w = tid >> 6;
  int bid = blockIdx.x;
  int qt = 7 - (bid >> 8), b = (bid >> 3) & 31, h = bid & 7;
  int l15 = lane & 15, l4 = lane >> 4;
  int lrow = lane >> 3, lchunk = lane & 7;

  f4v z4 = {0.f, 0.f, 0.f, 0.f};
  s8v qf[2][2];
#pragma unroll
  for (int g = 0; g < 2; g++) {
    const short* qp = qk + (size_t)(b * 1024 + qt * 128 + g * 64 + w * 16 + l15) * 1024 + h * 64;
    qf[g][0] = *(const s8v*)(qp + l4 * 8);
    qf[g][1] = *(const s8v*)(qp + 32 + l4 * 8);
  }
  f4v o[2][4], lac[2];
#pragma unroll
  for (int g = 0; g < 2; g++) {
    lac[g] = z4;
#pragma unroll
    for (int j = 0; j < 4; j++) o[g][j] = z4;
  }
  s8v ones;
#pragma unroll
  for (int e = 0; e < 8; e++) ones[e] = (short)0x3F80;

  auto STAGE = [&](int buf, int kt) {
#pragma unroll
    for (int t = 0; t < 2; t++) {
      int r0 = (w * 2 + t) * 8;
      int row = r0 + lrow;
      gl_lds16(qk + (size_t)(b * 1024 + kt * 64 + row) * 1024 + 512 + h * 64 +
                   ((lchunk ^ (row & 7)) << 3),
               &Kl[buf][r0 * 64]);
      gl_lds16(vt + (size_t)(b * 512 + h * 64 + row) * 1024 + kt * 64 +
                   ((lchunk ^ (row & 7)) << 3),
               &Vl[buf][r0 * 64]);
    }
  };

  int nkt = 2 * qt + 2;
  STAGE(0, 0);
  for (int kt = 0; kt < nkt; kt++) {
    int cur = kt & 1;
    ushort4 bh[2][4];
#pragma unroll
    for (int g = 0; g < 2; g++) {
      if (kt > 2 * qt + g) continue;
      const short* bp = biasNT + ((size_t)h * 1024 + qt * 128 + g * 64 + w * 16 + l15) * 1024 +
                        kt * 64 + l4 * 4;
#pragma unroll
      for (int j = 0; j < 4; j++) bh[g][j] = *(const ushort4*)(bp + j * 16);
    }
    __builtin_amdgcn_sched_barrier(0);  // keep bias loads ahead of the staging DMA
    if (kt + 1 < nkt) {
      STAGE(cur ^ 1, kt + 1);
      asm volatile("s_waitcnt vmcnt(4)" ::: "memory");
    } else {
      asm volatile("s_waitcnt vmcnt(0)" ::: "memory");
    }
    __builtin_amdgcn_s_barrier();
    const short* Kc = &Kl[cur][0];
    const short* Vc = &Vl[cur][0];
#pragma unroll
    for (int g = 0; g < 2; g++) {
      int diag = 2 * qt + g;
      if (kt > diag) continue;
      f4v s[4];
#pragma unroll
      for (int j = 0; j < 4; j++) {
        f4v bc;
        bc[0] = bf2f(bh[g][j].x); bc[1] = bf2f(bh[g][j].y);
        bc[2] = bf2f(bh[g][j].z); bc[3] = bf2f(bh[g][j].w);
        int kr = j * 16 + l15;
        s8v kf0 = *(const s8v*)(Kc + kr * 64 + ((l4 ^ (kr & 7)) << 3));
        s8v kf1 = *(const s8v*)(Kc + kr * 64 + (((l4 + 4) ^ (kr & 7)) << 3));
        s[j] = __builtin_amdgcn_mfma_f32_16x16x32_bf16(kf0, qf[g][0], bc, 0, 0, 0);
        s[j] = __builtin_amdgcn_mfma_f32_16x16x32_bf16(kf1, qf[g][1], s[j], 0, 0, 0);
      }
      if (kt == diag) {
#pragma unroll
        for (int j = 0; j < 4; j++)
#pragma unroll
          for (int r = 0; r < 4; r++) {
            int kk = j * 16 + l4 * 4 + r, qq = w * 16 + l15;
            s[j][r] = (kk > qq) ? 0.f : fexp2(s[j][r]);
          }
      } else {
#pragma unroll
        for (int j = 0; j < 4; j++)
#pragma unroll
          for (int r = 0; r < 4; r++) s[j][r] = fexp2(s[j][r]);
      }
      unsigned X0[4], X1[4];
#pragma unroll
      for (int j = 0; j < 4; j++) {
        X0[j] = cvtpk(s[j][0], s[j][1]);
        X1[j] = cvtpk(s[j][2], s[j][3]);
      }
      u2v a0 = __builtin_amdgcn_permlane32_swap(X0[0], X0[1], false, false);
      u2v a1 = __builtin_amdgcn_permlane16_swap(a0[0], a0[1], false, false);
      u2v b0 = __builtin_amdgcn_permlane32_swap(X1[0], X1[1], false, false);
      u2v b1 = __builtin_amdgcn_permlane16_swap(b0[0], b0[1], false, false);
      u2v c0 = __builtin_amdgcn_permlane32_swap(X0[2], X0[3], false, false);
      u2v c1 = __builtin_amdgcn_permlane16_swap(c0[0], c0[1], false, false);
      u2v d0 = __builtin_amdgcn_permlane32_swap(X1[2], X1[3], false, false);
      u2v d1 = __builtin_amdgcn_permlane16_swap(d0[0], d0[1], false, false);
      u4v P0 = {a1[0], b1[0], a1[1], b1[1]};  // k 0..31
      u4v P1 = {c1[0], d1[0], c1[1], d1[1]};  // k 32..63
      s8v pf0 = __builtin_bit_cast(s8v, P0);
      s8v pf1 = __builtin_bit_cast(s8v, P1);
      lac[g] = __builtin_amdgcn_mfma_f32_16x16x32_bf16(pf0, ones, lac[g], 0, 0, 0);
      lac[g] = __builtin_amdgcn_mfma_f32_16x16x32_bf16(pf1, ones, lac[g], 0, 0, 0);
#pragma unroll
      for (int j = 0; j < 4; j++) {
        int dr = j * 16 + l15;
        s8v vf0 = *(const s8v*)(Vc + dr * 64 + ((l4 ^ (dr & 7)) << 3));
        s8v vf1 = *(const s8v*)(Vc + dr * 64 + (((l4 + 4) ^ (dr & 7)) << 3));
        o[g][j] = __builtin_amdgcn_mfma_f32_16x16x32_bf16(pf0, vf0, o[g][j], 0, 0, 0);
        o[g][j] = __builtin_amdgcn_mfma_f32_16x16x32_bf16(pf1, vf1, o[g][j], 0, 0, 0);
      }
    }
    __builtin_amdgcn_s_barrier();
  }
#pragma unroll
  for (int g = 0; g < 2; g++)
#pragma unroll
    for (int r = 0; r < 4; r++) {
      float rl = 1.f / lac[g][r];
      int qr = qt * 128 + g * 64 + w * 16 + l4 * 4 + r;
#pragma unroll
      for (int j = 0; j < 4; j++) {
        int d = j * 16 + l15;
        ao[(size_t)(b * 1024 + qr) * 512 + h * 64 + d] = f2bf(o[g][j][r] * rl);
      }
    }
}

// ---------------- head GEMM ----------------
__global__ __launch_bounds__(256) void head_k(const short* __restrict__ X,
                                              const short* __restrict__ hWT,
                                              const float* __restrict__ hb,
                                              float* __restrict__ out) {
  __shared__ __align__(16) short lA[128 * 64];
  int tid = threadIdx.x, lane = tid & 63, w = tid >> 6;
  int l15 = lane & 15, l4 = lane >> 4;
  int lrow = lane >> 3, lchunk = lane & 7;
  int m0 = blockIdx.x * 128;
  f4v z4 = {0.f, 0.f, 0.f, 0.f};
  f4v acc[2][2];
#pragma unroll
  for (int i = 0; i < 2; i++)
#pragma unroll
    for (int j = 0; j < 2; j++) acc[i][j] = z4;

  for (int k0 = 0; k0 < 512; k0 += 64) {
#pragma unroll
    for (int t = 0; t < 4; t++) {
      int r0 = (w * 4 + t) * 8;
      int row = r0 + lrow;
      gl_lds16(X + (size_t)(m0 + row) * 512 + k0 + ((lchunk ^ (row & 7)) << 3), lA + r0 * 64);
    }
    __syncthreads();
#pragma unroll
    for (int kk = 0; kk < 2; kk++) {
      s8v af[2], bfr[2];
#pragma unroll
      for (int i = 0; i < 2; i++) {
        int ra = w * 32 + i * 16 + l15;
        af[i] = *(const s8v*)(lA + ra * 64 + (((l4 + kk * 4) ^ (ra & 7)) << 3));
      }
#pragma unroll
      for (int j = 0; j < 2; j++)
        bfr[j] = *(const s8v*)(hWT + (size_t)(j * 16 + l15) * 512 + k0 + kk * 32 + l4 * 8);
#pragma unroll
      for (int i = 0; i < 2; i++)
#pragma unroll
        for (int j = 0; j < 2; j++)
          acc[i][j] = __builtin_amdgcn_mfma_f32_16x16x32_bf16(af[i], bfr[j], acc[i][j], 0, 0, 0);
    }
    __syncthreads();
  }
#pragma unroll
  for (int i = 0; i < 2; i++) {
#pragma unroll
    for (int j = 0; j < 2; j++) {
      int col = j * 16 + l15;
      if (col < 24) {
        float bv = hb[col];
#pragma unroll
        for (int r = 0; r < 4; r++) {
          int row = m0 + w * 32 + i * 16 + l4 * 4 + r;
          out[(size_t)row * 24 + col] = acc[i][j][r] + bv;
        }
      }
    }
  }
}

// ---------------- launch ----------------
extern "C" void kernel_launch(void* const* d_in, const int* in_sizes, int n_in,
                              void* d_out, int out_size, void* d_ws, size_t ws_size,
                              hipStream_t stream) {
  (void)in_sizes; (void)n_in; (void)out_size;
  const float* theta   = (const float*)d_in[0];
  const float* cond    = (const float*)d_in[1];
  const float* attn_b  = (const float*)d_in[2];
  const float* embed_W = (const float*)d_in[3];
  const float* embed_b = (const float*)d_in[4];
  const float* ln1_g   = (const float*)d_in[5];
  const float* ln1_b   = (const float*)d_in[6];
  const float* ada1_W  = (const float*)d_in[7];
  const float* ada1_b  = (const float*)d_in[8];
  const float* Wq      = (const float*)d_in[9];
  const float* bq      = (const float*)d_in[10];
  const float* Wk      = (const float*)d_in[11];
  const float* bk      = (const float*)d_in[12];
  const float* Wv      = (const float*)d_in[13];
  const float* bv      = (const float*)d_in[14];
  const float* Wo      = (const float*)d_in[15];
  const float* bo      = (const float*)d_in[16];
  const float* ln2_g   = (const float*)d_in[17];
  const float* ln2_b   = (const float*)d_in[18];
  const float* ada2_W  = (const float*)d_in[19];
  const float* ada2_b  = (const float*)d_in[20];
  const float* W1      = (const float*)d_in[21];
  const float* b1      = (const float*)d_in[22];
  const float* W2      = (const float*)d_in[23];
  const float* b2      = (const float*)d_in[24];
  const float* fn_g    = (const float*)d_in[25];
  const float* fn_b    = (const float*)d_in[26];
  const float* head_W  = (const float*)d_in[27];
  const float* head_b  = (const float*)d_in[28];

  const size_t REQ = 242814976ull;
  const size_t REQ2 = 259592192ull;
  if (ws_size < REQ) return;
  bool bias_once = (ws_size >= REQ2);

  char* ws = (char*)d_ws;
  float* xw    = (float*)(ws + 0ull);
  short* qk    = (short*)(ws + 67108864ull);
  short* vtb   = (short*)(ws + 134217728ull);   // V^T, then Wo-delta
  short* biasT = (short*)(ws + (bias_once ? 242814976ull : 167772160ull));
  short* qf    = (short*)(ws + 67108864ull);
  short* hbuf  = (short*)(ws + 201326592ull);   // adaln out / attn out / FF2 delta
  short* wbf   = (short*)(ws + 234881024ull);
  float* ssb   = (float*)(ws + 241172480ull);
  float* bqkv  = (float*)(ws + 242745344ull);
  short* hWT   = (short*)(ws + 242782208ull);

  concat_qkvb_k<<<6, 256, 0, stream>>>(bq, bk, bv, bqkv);
  cond_proj_k<<<dim3(4, 12), 256, 0, stream>>>(cond, ada1_W, ada1_b, ada2_W, ada2_b, ssb);
  hwt_k<<<64, 256, 0, stream>>>(head_W, hWT);
  embed_k<<<8192, 256, 0, stream>>>(theta, embed_W, embed_b, xw);
  if (bias_once) bias_cvt_k<<<8192, 256, 0, stream>>>(attn_b, biasT);

  for (int l = 0; l < 6; l++) {
    transpose_all_k<<<3072, 256, 0, stream>>>(Wq, Wk, Wv, Wo, W1, W2, l, wbf);
    if (!bias_once) bias_cvt_k<<<8192, 256, 0, stream>>>(attn_b, biasT);

    if (l == 0)
      adaln_k<false><<<8192, 256, 0, stream>>>(xw, nullptr, ssb + (size_t)(l * 2) * 32768,
                                               ln1_g + l * 512, ln1_b + l * 512, hbuf);
    else  // delta = FF2 delta from layer l-1, lives in hbuf; h also hbuf (safe)
      adaln_k<true><<<8192, 256, 0, stream>>>(xw, hbuf, ssb + (size_t)(l * 2) * 32768,
                                              ln1_g + l * 512, ln1_b + l * 512, hbuf);
    qk_proj_k<<<2048, 256, 0, stream>>>(hbuf, wbf, bqkv + l * 1536, qk);
    v_proj_k<<<1024, 256, 0, stream>>>(hbuf, wbf, bqkv + l * 1536, vtb);
    attn_k<<<2048, 256, 0, stream>>>(qk, vtb, biasT, hbuf);
    // Wo: delta = attn_out @ Wo^T + bo -> vtb (dead V^T); folded IMMEDIATELY
    // by adaln2 (vtb must not outlive FF1 - qf overwrites its region)
    gemm_r3_k<0><<<1024, 256, 0, stream>>>(hbuf, wbf + 786432, bo + l * 512, vtb, 512, 512);
    adaln_k<true><<<8192, 256, 0, stream>>>(xw, vtb, ssb + (size_t)(l * 2 + 1) * 32768,
                                            ln2_g + l * 512, ln2_b + l * 512, hbuf);
    // FF1: 128x256 ring-3, 8 waves (exp2-gelu epilogue)
    gemm_ff1_k<1><<<2048, 512, 0, stream>>>(hbuf, wbf + 1048576, b1 + l * 2048, qf, 2048, 512);
    // FF2: delta -> hbuf (disjoint from qf); folded by next adaln1 / fln
    gemm_r3_k<0><<<1024, 256, 0, stream>>>(qf, wbf + 2097152, b2 + l * 512, hbuf, 512, 2048);
  }
  fln_k<<<8192, 256, 0, stream>>>(xw, hbuf, fn_g, fn_b, hbuf);
  head_k<<<256, 256, 0, stream>>>(hbuf, hWT, head_b, (float*)d_out);
}

// Round 16
// 2491.826 us; speedup vs baseline: 1.0722x; 1.0438x over previous
//
#include <hip/hip_runtime.h>

// ContinuousLatticeGPT: B=32 S=1024 D=512 H=8 NL=6 DFF=2048 C=128 K=8
// bf16 MFMA; fp32 residual stream with deferred (bf16 delta) residual adds.
// r16 = r15 + Wo/FF2 moved to the 128x256 8-wave ring-3 template (gemm_w_k):
// grid 512 = 2 blk/CU exactly at 2-blk occupancy -> no straggler tail (r15
// profile: FF2 at grid 1024 had Occ 21.8% = 3+1 wave split), 2x MFMA per
// barrier-pair, staging bytes/FLOP -25%. FF1 already on this template (r15:
// 113->100us). qk_proj/v_proj keep the 128x128 ring-3 bodies.
//  - gelu epilogue (FF1): log2e folded into sigmoid-gelu constants -> raw
//    v_exp_f32 + v_rcp_f32 (r11: -96us).
// All GEMMs: lane-adjacent 64B-row staging + chunk^=((row>>1)&3) swizzle
// (TA-coalesced AND bank-conflict-free).
// attn: swapped-QK (mfma(K,Q)) with in-register P transpose via cvt_pk+permlane;
// exp2-folded softmax (log2e in q-scale & bias). No setprio (r9: +12us).
// Delta routing: Wo-delta -> vtb (dead V^T), folded IMMEDIATELY by adaln2
// (r13 lesson: vtb must NOT outlive FF1 - qf overwrites its region);
// FF2-delta -> hbuf (dead FF1 input, disjoint from qf), folded next adaln1/fln.
// ws layout (bytes): unchanged. REQ 242,814,976 B

typedef short s8v __attribute__((ext_vector_type(8)));
typedef float f4v __attribute__((ext_vector_type(4)));
typedef unsigned u2v __attribute__((ext_vector_type(2)));
typedef unsigned u4v __attribute__((ext_vector_type(4)));

#define Q_SCALE 0.18033688011112042f  // 0.125 * log2(e)
#define LOG2E   1.4426950408889634f

static __device__ __forceinline__ short f2bf(float f) {
  union { float f; unsigned u; } v; v.f = f;
  unsigned r = v.u + 0x7fffu + ((v.u >> 16) & 1u);
  return (short)(r >> 16);
}
static __device__ __forceinline__ float bf2f(unsigned short s) {
  union { unsigned u; float f; } v; v.u = ((unsigned)s) << 16;
  return v.f;
}
static __device__ __forceinline__ unsigned cvtpk(float lo, float hi) {
  unsigned r;
  asm("v_cvt_pk_bf16_f32 %0, %1, %2" : "=v"(r) : "v"(lo), "v"(hi));
  return r;
}
static __device__ __forceinline__ float fexp2(float x) {  // 2^x, single v_exp_f32
  float r;
  asm("v_exp_f32 %0, %1" : "=v"(r) : "v"(x));
  return r;
}
static __device__ __forceinline__ float frcp(float x) {  // ~1ulp reciprocal
  float r;
  asm("v_rcp_f32 %0, %1" : "=v"(r) : "v"(x));
  return r;
}
static __device__ __forceinline__ void gl_lds16(const short* g, short* l) {
  __builtin_amdgcn_global_load_lds(
      (const __attribute__((address_space(1))) unsigned int*)g,
      (__attribute__((address_space(3))) unsigned int*)l, 16, 0, 0);
}

// ---------------- prep kernels ----------------
__global__ void transpose_all_k(const float* __restrict__ Wq, const float* __restrict__ Wk,
                                const float* __restrict__ Wv, const float* __restrict__ Wo,
                                const float* __restrict__ W1, const float* __restrict__ W2,
                                int l, short* __restrict__ wbf) {
  int id = blockIdx.x;
  const float* in; short* out; int K, N, tx, ty;
  if (id < 1024) {
    int m = id >> 8, t = id & 255;
    in = (m == 0 ? Wq : m == 1 ? Wk : m == 2 ? Wv : Wo) + (size_t)l * 262144;
    out = wbf + (size_t)m * 262144;
    K = 512; N = 512; tx = t & 15; ty = t >> 4;
  } else if (id < 2048) {
    int t = id - 1024;
    in = W1 + (size_t)l * 1048576; out = wbf + 1048576;
    K = 512; N = 2048; tx = t & 63; ty = t >> 6;
  } else {
    int t = id - 2048;
    in = W2 + (size_t)l * 1048576; out = wbf + 2097152;
    K = 2048; N = 512; tx = t & 15; ty = t >> 4;
  }
  __shared__ float tb[32][33];
  int n0 = tx * 32, k0 = ty * 32;
  int cx = threadIdx.x & 31, cy = threadIdx.x >> 5;
#pragma unroll
  for (int r = 0; r < 4; r++)
    tb[cy + r * 8][cx] = in[(size_t)(k0 + cy + r * 8) * N + n0 + cx];
  __syncthreads();
#pragma unroll
  for (int r = 0; r < 4; r++)
    out[(size_t)(n0 + cy + r * 8) * K + k0 + cx] = f2bf(tb[cx][cy + r * 8]);
}

// f32 -> bf16 copy of attn_bias, folding log2(e) for the exp2 softmax
__global__ void bias_cvt_k(const float* __restrict__ in, short* __restrict__ out) {
  int i = blockIdx.x * 256 + threadIdx.x;  // float4 index; grid covers 8M floats
  float4 v = ((const float4*)in)[i];
  ushort4 o;
  o.x = (unsigned short)f2bf(v.x * LOG2E);
  o.y = (unsigned short)f2bf(v.y * LOG2E);
  o.z = (unsigned short)f2bf(v.z * LOG2E);
  o.w = (unsigned short)f2bf(v.w * LOG2E);
  ((ushort4*)out)[i] = o;
}

__global__ void hwt_k(const float* __restrict__ hW, short* __restrict__ hWT) {
  int i = blockIdx.x * 256 + threadIdx.x;
  int n = i >> 9, k = i & 511;
  hWT[i] = (n < 24) ? f2bf(hW[(size_t)k * 24 + n]) : (short)0;
}

__global__ void concat_qkvb_k(const float* bq, const float* bk, const float* bv, float* out) {
  int l = blockIdx.x;
  for (int i = threadIdx.x; i < 1536; i += 256) {
    float v = (i < 512) ? bq[l * 512 + i] * Q_SCALE  // fold 1/sqrt(HD)*log2e into q bias
            : (i < 1024 ? bk[l * 512 + i - 512] : bv[l * 512 + i - 1024]);
    out[l * 1536 + i] = v;
  }
}

__global__ void cond_proj_k(const float* __restrict__ cond,
                            const float* __restrict__ a1W, const float* __restrict__ a1b,
                            const float* __restrict__ a2W, const float* __restrict__ a2b,
                            float* __restrict__ ss) {
  int lw = blockIdx.y, which = lw & 1, l = lw >> 1;
  const float* W = (which ? a2W : a1W) + (size_t)l * 128 * 1024;
  const float* bb = (which ? a2b : a1b) + (size_t)l * 1024;
  __shared__ float cs[32 * 128];
  for (int i = threadIdx.x; i < 32 * 128; i += 256) cs[i] = cond[i];
  __syncthreads();
  int n = blockIdx.x * 256 + threadIdx.x;
  float bias = bb[n];
  for (int g = 0; g < 4; g++) {
    float acc[8];
#pragma unroll
    for (int i = 0; i < 8; i++) acc[i] = 0.f;
    for (int c = 0; c < 128; c++) {
      float w = W[(size_t)c * 1024 + n];
#pragma unroll
      for (int i = 0; i < 8; i++) acc[i] += cs[(g * 8 + i) * 128 + c] * w;
    }
#pragma unroll
    for (int i = 0; i < 8; i++)
      ss[((size_t)lw * 32 + g * 8 + i) * 1024 + n] = acc[i] + bias;
  }
}

__global__ void embed_k(const float* __restrict__ theta, const float* __restrict__ eW,
                        const float* __restrict__ eb, float* __restrict__ x) {
  int row = blockIdx.x * 4 + (threadIdx.x >> 6), lane = threadIdx.x & 63;
  float th = theta[row], sn, cn;
  sincosf(th, &sn, &cn);
  int d = lane * 8;
  float* xo = x + (size_t)row * 512 + d;
#pragma unroll
  for (int i = 0; i < 8; i++) xo[i] = cn * eW[d + i] + sn * eW[512 + d + i] + eb[d + i];
}

// AdaLN; optionally folds a deferred bf16 residual delta (may ALIAS h!) and updates xw.
template<bool HASDEL>
__global__ void adaln_k(float* __restrict__ x, const short* delta,
                        const float* __restrict__ ss,
                        const float* __restrict__ g, const float* __restrict__ be,
                        short* h) {
  int row = blockIdx.x * 4 + (threadIdx.x >> 6), lane = threadIdx.x & 63;
  int b = row >> 10;
  float* xr = x + (size_t)row * 512 + lane * 8;
  float4 va = ((const float4*)xr)[0], vb = ((const float4*)xr)[1];
  float v[8] = {va.x, va.y, va.z, va.w, vb.x, vb.y, vb.z, vb.w};
  if (HASDEL) {
    s8v dv = *(const s8v*)(delta + (size_t)row * 512 + lane * 8);
#pragma unroll
    for (int i = 0; i < 8; i++) v[i] += bf2f((unsigned short)dv[i]);
    float4 o0 = {v[0], v[1], v[2], v[3]}, o1 = {v[4], v[5], v[6], v[7]};
    ((float4*)xr)[0] = o0; ((float4*)xr)[1] = o1;
  }
  float sm = 0.f;
#pragma unroll
  for (int i = 0; i < 8; i++) sm += v[i];
#pragma unroll
  for (int off = 1; off < 64; off <<= 1) sm += __shfl_xor(sm, off);
  float mean = sm * (1.f / 512.f);
  float sq = 0.f;
#pragma unroll
  for (int i = 0; i < 8; i++) { float d = v[i] - mean; sq += d * d; }
#pragma unroll
  for (int off = 1; off < 64; off <<= 1) sq += __shfl_xor(sq, off);
  float rs = rsqrtf(sq * (1.f / 512.f) + 1e-5f);
  const float* sb = ss + (size_t)b * 1024 + lane * 8;
  const float* gp = g + lane * 8;
  const float* bp = be + lane * 8;
  s8v o;
#pragma unroll
  for (int i = 0; i < 8; i++) {
    float xh = (v[i] - mean) * rs * gp[i] + bp[i];
    o[i] = f2bf((1.f + sb[i]) * xh + sb[i + 512]);
  }
  *(s8v*)(h + (size_t)row * 512 + lane * 8) = o;
}

// final LN, folding FF2's delta (delta may ALIAS h)
__global__ void fln_k(const float* __restrict__ x, const short* delta,
                      const float* __restrict__ g, const float* __restrict__ be,
                      short* h) {
  int row = blockIdx.x * 4 + (threadIdx.x >> 6), lane = threadIdx.x & 63;
  const float* xr = x + (size_t)row * 512 + lane * 8;
  float4 va = ((const float4*)xr)[0], vb = ((const float4*)xr)[1];
  float v[8] = {va.x, va.y, va.z, va.w, vb.x, vb.y, vb.z, vb.w};
  s8v dv = *(const s8v*)(delta + (size_t)row * 512 + lane * 8);
#pragma unroll
  for (int i = 0; i < 8; i++) v[i] += bf2f((unsigned short)dv[i]);
  float sm = 0.f;
#pragma unroll
  for (int i = 0; i < 8; i++) sm += v[i];
#pragma unroll
  for (int off = 1; off < 64; off <<= 1) sm += __shfl_xor(sm, off);
  float mean = sm * (1.f / 512.f);
  float sq = 0.f;
#pragma unroll
  for (int i = 0; i < 8; i++) { float d = v[i] - mean; sq += d * d; }
#pragma unroll
  for (int off = 1; off < 64; off <<= 1) sq += __shfl_xor(sq, off);
  float rs = rsqrtf(sq * (1.f / 512.f) + 1e-5f);
  const float* gp = g + lane * 8;
  const float* bp = be + lane * 8;
  s8v o;
#pragma unroll
  for (int i = 0; i < 8; i++) o[i] = f2bf((v[i] - mean) * rs * gp[i] + bp[i]);
  *(s8v*)(h + (size_t)row * 512 + lane * 8) = o;
}

// --- GEMM 128x256, BK=32, ring-3, 512 thr (8 waves 2Mx4N), 72KB LDS ---
// (FF1 / Wo / FF2.) Same sync structure as the 128x128 ring-3; 32 MFMAs per
// barrier-pair, staging bytes/FLOP -25%, 2 blk/CU = 16 waves/CU.
// Staging: 384 rows (128 A + 256 B) x 64B; thread covers 3 lane-adjacent 16B
// chunks; per-(w,tt) A/B choice is wave-uniform (boundary 128 = 2*48+32 exact).
// Counted vmcnt: 3 loads/thread/tile -> vmcnt(3) steady, vmcnt(0) tail.
// EPI 0: bf16 (+bias); 1: gelu bf16 (exp2-folded + v_rcp).
template<int EPI>
__global__ __launch_bounds__(512, 2) void gemm_w_k(const short* __restrict__ A,
                                                   const short* __restrict__ BT,
                                                   const float* __restrict__ bias,
                                                   short* __restrict__ outb,
                                                   int N, int K) {
  __shared__ __align__(16) short lsA[3][4096];  // 3 x 8KB  (128 rows)
  __shared__ __align__(16) short lsB[3][8192];  // 3 x 16KB (256 rows)
  int tid = threadIdx.x, lane = tid & 63, w = tid >> 6;  // w in [0,8)
  int wm = w >> 2, wn = w & 3;                            // 2M x 4N waves
  int l15 = lane & 15, l4 = lane >> 4;
  int lrow = lane >> 2, lchunk = lane & 3;
  int poff = ((l15 << 2) + (l4 ^ ((l15 >> 1) & 3))) << 3;
  int nb = N >> 8;                                        // 256-wide N tiles
  int bid = blockIdx.x;
  int xcd = bid & 7, rr = bid >> 3;
  int mloc = rr / nb, nidx = rr - mloc * nb;
  int m0 = (xcd * 32 + mloc) << 7, n0 = nidx << 8;

  f4v z4 = {0.f, 0.f, 0.f, 0.f};
  f4v acc[4][4];
#pragma unroll
  for (int i = 0; i < 4; i++)
#pragma unroll
    for (int j = 0; j < 4; j++) acc[i][j] = z4;

  int co = (lchunk ^ ((lrow >> 1) & 3)) << 3;

  auto STAGE = [&](int t) {  // 3 DMA ops per thread; 384 rows total
    int slot = t % 3;
    int ko = t << 5;
#pragma unroll
    for (int tt = 0; tt < 3; tt++) {
      int r0 = w * 48 + tt * 16;          // wave-uniform; 0..368 step 16
      int row = r0 + lrow;
      if (r0 < 128) {                      // A rows [0,128)
        gl_lds16(A + (size_t)(m0 + row) * K + ko + co, lsA[slot] + r0 * 32);
      } else {                             // B rows [0,256)
        int rb = row - 128;
        gl_lds16(BT + (size_t)(n0 + rb) * K + ko + co, lsB[slot] + (r0 - 128) * 32);
      }
    }
  };
  auto LOADF = [&](int t, s8v* af, s8v* bfr) {
    int slot = t % 3;
    const short* At = lsA[slot] + (wm * 4) * 512 + poff;
    const short* Bt = lsB[slot] + (wn * 4) * 512 + poff;
#pragma unroll
    for (int i = 0; i < 4; i++) {
      af[i] = *(const s8v*)(At + i * 512);
      bfr[i] = *(const s8v*)(Bt + i * 512);
    }
  };

  int NT = K >> 5;
  STAGE(0); STAGE(1);
  asm volatile("s_waitcnt vmcnt(3)" ::: "memory");  // tile 0 landed
  __builtin_amdgcn_s_barrier();
  s8v af[4], bfr[4];
  LOADF(0, af, bfr);
  for (int t = 0; t < NT; ++t) {
    if (t + 2 < NT) STAGE(t + 2);
    __builtin_amdgcn_sched_barrier(0);   // pin VMEM issue before the MFMA burst
#pragma unroll
    for (int i = 0; i < 4; i++)
#pragma unroll
      for (int j = 0; j < 4; j++)
        acc[i][j] = __builtin_amdgcn_mfma_f32_16x16x32_bf16(af[i], bfr[j], acc[i][j], 0, 0, 0);
    if (t + 1 < NT) {
      if (t + 2 < NT) asm volatile("s_waitcnt vmcnt(3)" ::: "memory");  // t+1 landed
      else            asm volatile("s_waitcnt vmcnt(0)" ::: "memory");  // tail
      __builtin_amdgcn_s_barrier();
      LOADF(t + 1, af, bfr);   // frags for next iter; latency covered by backedge
    }
  }
#pragma unroll
  for (int i = 0; i < 4; i++) {
    int gr0 = m0 + wm * 64 + i * 16 + l4 * 4;
#pragma unroll
    for (int j = 0; j < 4; j++) {
      int gc = n0 + wn * 64 + j * 16 + l15;
      float bv = bias[gc];
#pragma unroll
      for (int r = 0; r < 4; r++) {
        float v = acc[i][j][r] + bv;
        if (EPI == 1) {
          // sigmoid-gelu with log2e prefolded: v * sigmoid(1.5958v + 0.07135v^3)
          float tg = v * (-2.3022083f - 0.10294325f * v * v);
          v = v * frcp(1.f + fexp2(tg));
        }
        outb[(size_t)(gr0 + r) * N + gc] = f2bf(v);
      }
    }
  }
}

// --- QK projection: branch-free ring-3 128x128 (proven body). grid 2048. ---
// n0 in [0,1024); output qk row stride 1024; q cols scaled by Q_SCALE.
__global__ __launch_bounds__(256, 3) void qk_proj_k(const short* __restrict__ A,
                                                    const short* __restrict__ BT,
                                                    const float* __restrict__ bias,
                                                    short* __restrict__ qk) {
  __shared__ __align__(16) short lsA[3][4096];
  __shared__ __align__(16) short lsB[3][4096];
  int tid = threadIdx.x, lane = tid & 63, w = tid >> 6;
  int wm = w >> 1, wn = w & 1;
  int l15 = lane & 15, l4 = lane >> 4;
  int lrow = lane >> 2, lchunk = lane & 3;
  int poff = ((l15 << 2) + (l4 ^ ((l15 >> 1) & 3))) << 3;
  int bid = blockIdx.x;
  int xcd = bid & 7, rr = bid >> 3;
  int mloc = rr >> 3, nidx = rr & 7;
  int m0 = (xcd * 32 + mloc) << 7, n0 = nidx << 7;
  bool isQ = (n0 < 512);

  f4v z4 = {0.f, 0.f, 0.f, 0.f};
  f4v acc[4][4];
#pragma unroll
  for (int i = 0; i < 4; i++)
#pragma unroll
    for (int j = 0; j < 4; j++) acc[i][j] = z4;

  int co = (lchunk ^ ((lrow >> 1) & 3)) << 3;

  auto STAGE = [&](int t) {
    int slot = t % 3;
    int ko = t << 5;
#pragma unroll
    for (int tt = 0; tt < 2; tt++) {
      int r0 = w * 32 + tt * 16;
      int row = r0 + lrow;
      gl_lds16(A + (size_t)(m0 + row) * 512 + ko + co, lsA[slot] + r0 * 32);
      gl_lds16(BT + (size_t)(n0 + row) * 512 + ko + co, lsB[slot] + r0 * 32);
    }
  };
  auto LOADF = [&](int t, s8v* af, s8v* bfr) {
    int slot = t % 3;
    const short* At = lsA[slot] + (wm * 4) * 512 + poff;
    const short* Bt = lsB[slot] + (wn * 4) * 512 + poff;
#pragma unroll
    for (int i = 0; i < 4; i++) {
      af[i] = *(const s8v*)(At + i * 512);
      bfr[i] = *(const s8v*)(Bt + i * 512);
    }
  };

  const int NT = 16;
  STAGE(0); STAGE(1);
  asm volatile("s_waitcnt vmcnt(4)" ::: "memory");
  __builtin_amdgcn_s_barrier();
  s8v af[4], bfr[4];
  LOADF(0, af, bfr);
  for (int t = 0; t < NT; ++t) {
    if (t + 2 < NT) STAGE(t + 2);
    __builtin_amdgcn_sched_barrier(0);
#pragma unroll
    for (int i = 0; i < 4; i++)
#pragma unroll
      for (int j = 0; j < 4; j++)
        acc[i][j] = __builtin_amdgcn_mfma_f32_16x16x32_bf16(af[i], bfr[j], acc[i][j], 0, 0, 0);
    if (t + 1 < NT) {
      if (t + 2 < NT) asm volatile("s_waitcnt vmcnt(4)" ::: "memory");
      else            asm volatile("s_waitcnt vmcnt(0)" ::: "memory");
      __builtin_amdgcn_s_barrier();
      LOADF(t + 1, af, bfr);
    }
  }
  float scl = isQ ? Q_SCALE : 1.f;  // fold 1/sqrt(HD)*log2e into q
#pragma unroll
  for (int i = 0; i < 4; i++) {
    int gr0 = m0 + wm * 64 + i * 16 + l4 * 4;
#pragma unroll
    for (int j = 0; j < 4; j++) {
      int gc = n0 + wn * 64 + j * 16 + l15;
      float bv = bias[gc];
#pragma unroll
      for (int r = 0; r < 4; r++)
        qk[(size_t)(gr0 + r) * 1024 + gc] = f2bf(acc[i][j][r] * scl + bv);
    }
  }
}

// --- V projection: ring-3 128x128, operand-swapped MFMA -> V^T scatter. grid 1024. ---
__global__ __launch_bounds__(256, 3) void v_proj_k(const short* __restrict__ A,
                                                   const short* __restrict__ BT,
                                                   const float* __restrict__ bias,
                                                   short* __restrict__ vtb) {
  __shared__ __align__(16) short lsA[3][4096];
  __shared__ __align__(16) short lsB[3][4096];
  int tid = threadIdx.x, lane = tid & 63, w = tid >> 6;
  int wm = w >> 1, wn = w & 1;
  int l15 = lane & 15, l4 = lane >> 4;
  int lrow = lane >> 2, lchunk = lane & 3;
  int poff = ((l15 << 2) + (l4 ^ ((l15 >> 1) & 3))) << 3;
  int bid = blockIdx.x;
  int xcd = bid & 7, rr = bid >> 3;
  int mloc = rr >> 2, nidx = rr & 3;
  int m0 = (xcd * 32 + mloc) << 7, n0 = 1024 + (nidx << 7);

  f4v z4 = {0.f, 0.f, 0.f, 0.f};
  f4v acc[4][4];
#pragma unroll
  for (int i = 0; i < 4; i++)
#pragma unroll
    for (int j = 0; j < 4; j++) acc[i][j] = z4;

  int co = (lchunk ^ ((lrow >> 1) & 3)) << 3;

  auto STAGE = [&](int t) {
    int slot = t % 3;
    int ko = t << 5;
#pragma unroll
    for (int tt = 0; tt < 2; tt++) {
      int r0 = w * 32 + tt * 16;
      int row = r0 + lrow;
      gl_lds16(A + (size_t)(m0 + row) * 512 + ko + co, lsA[slot] + r0 * 32);
      gl_lds16(BT + (size_t)(n0 + row) * 512 + ko + co, lsB[slot] + r0 * 32);
    }
  };
  auto LOADF = [&](int t, s8v* af, s8v* bfr) {
    int slot = t % 3;
    const short* At = lsA[slot] + (wm * 4) * 512 + poff;
    const short* Bt = lsB[slot] + (wn * 4) * 512 + poff;
#pragma unroll
    for (int i = 0; i < 4; i++) {
      af[i] = *(const s8v*)(At + i * 512);
      bfr[i] = *(const s8v*)(Bt + i * 512);
    }
  };

  const int NT = 16;
  STAGE(0); STAGE(1);
  asm volatile("s_waitcnt vmcnt(4)" ::: "memory");
  __builtin_amdgcn_s_barrier();
  s8v af[4], bfr[4];
  LOADF(0, af, bfr);
  for (int t = 0; t < NT; ++t) {
    if (t + 2 < NT) STAGE(t + 2);
    __builtin_amdgcn_sched_barrier(0);
#pragma unroll
    for (int j = 0; j < 4; j++)
#pragma unroll
      for (int i = 0; i < 4; i++)
        acc[j][i] = __builtin_amdgcn_mfma_f32_16x16x32_bf16(bfr[j], af[i], acc[j][i], 0, 0, 0);
    if (t + 1 < NT) {
      if (t + 2 < NT) asm volatile("s_waitcnt vmcnt(4)" ::: "memory");
      else            asm volatile("s_waitcnt vmcnt(0)" ::: "memory");
      __builtin_amdgcn_s_barrier();
      LOADF(t + 1, af, bfr);
    }
  }
  int b = m0 >> 10, s0 = m0 & 1023;
#pragma unroll
  for (int j = 0; j < 4; j++) {
    int col = n0 + wn * 64 + j * 16 + l4 * 4;
#pragma unroll
    for (int i = 0; i < 4; i++) {
      int scol = s0 + wm * 64 + i * 16 + l15;
#pragma unroll
      for (int r = 0; r < 4; r++) {
        float v = acc[j][i][r] + bias[col + r];
        vtb[((size_t)b * 512 + col - 1024 + r) * 1024 + scol] = f2bf(v);
      }
    }
  }
}

// ---------------- flash attention (QBLK=128, no-max exp2 softmax, bias-as-C) ----------------
// Swapped QK^T: s^T = mfma(K, Q, bias); P transposed back in registers via
// cvt_pk_bf16 + permlane{32,16}_swap. K/V double-buffered, counted vmcnt(4).
// q & bias pre-scaled by log2e -> softmax uses raw v_exp_f32 (2^x).
__global__ __launch_bounds__(256, 4) void attn_k(const short* __restrict__ qk,
                                                 const short* __restrict__ vt,
                                                 const short* __restrict__ biasNT,
                                                 short* __restrict__ ao) {
  __shared__ __align__(16) short Kl[2][64 * 64];
  __shared__ __align__(16) short Vl[2][64 * 64];
  int tid = threadIdx.x, lane = tid & 63, w = tid >> 6;
  int bid = blockIdx.x;
  int qt = 7 - (bid >> 8), b = (bid >> 3) & 31, h = bid & 7;
  int l15 = lane & 15, l4 = lane >> 4;
  int lrow = lane >> 3, lchunk = lane & 7;

  f4v z4 = {0.f, 0.f, 0.f, 0.f};
  s8v qf[2][2];
#pragma unroll
  for (int g = 0; g < 2; g++) {
    const short* qp = qk + (size_t)(b * 1024 + qt * 128 + g * 64 + w * 16 + l15) * 1024 + h * 64;
    qf[g][0] = *(const s8v*)(qp + l4 * 8);
    qf[g][1] = *(const s8v*)(qp + 32 + l4 * 8);
  }
  f4v o[2][4], lac[2];
#pragma unroll
  for (int g = 0; g < 2; g++) {
    lac[g] = z4;
#pragma unroll
    for (int j = 0; j < 4; j++) o[g][j] = z4;
  }
  s8v ones;
#pragma unroll
  for (int e = 0; e < 8; e++) ones[e] = (short)0x3F80;

  auto STAGE = [&](int buf, int kt) {
#pragma unroll
    for (int t = 0; t < 2; t++) {
      int r0 = (w * 2 + t) * 8;
      int row = r0 + lrow;
      gl_lds16(qk + (size_t)(b * 1024 + kt * 64 + row) * 1024 + 512 + h * 64 +
                   ((lchunk ^ (row & 7)) << 3),
               &Kl[buf][r0 * 64]);
      gl_lds16(vt + (size_t)(b * 512 + h * 64 + row) * 1024 + kt * 64 +
                   ((lchunk ^ (row & 7)) << 3),
               &Vl[buf][r0 * 64]);
    }
  };

  int nkt = 2 * qt + 2;
  STAGE(0, 0);
  for (int kt = 0; kt < nkt; kt++) {
    int cur = kt & 1;
    ushort4 bh[2][4];
#pragma unroll
    for (int g = 0; g < 2; g++) {
      if (kt > 2 * qt + g) continue;
      const short* bp = biasNT + ((size_t)h * 1024 + qt * 128 + g * 64 + w * 16 + l15) * 1024 +
                        kt * 64 + l4 * 4;
#pragma unroll
      for (int j = 0; j < 4; j++) bh[g][j] = *(const ushort4*)(bp + j * 16);
    }
    __builtin_amdgcn_sched_barrier(0);  // keep bias loads ahead of the staging DMA
    if (kt + 1 < nkt) {
      STAGE(cur ^ 1, kt + 1);
      asm volatile("s_waitcnt vmcnt(4)" ::: "memory");
    } else {
      asm volatile("s_waitcnt vmcnt(0)" ::: "memory");
    }
    __builtin_amdgcn_s_barrier();
    const short* Kc = &Kl[cur][0];
    const short* Vc = &Vl[cur][0];
#pragma unroll
    for (int g = 0; g < 2; g++) {
      int diag = 2 * qt + g;
      if (kt > diag) continue;
      f4v s[4];
#pragma unroll
      for (int j = 0; j < 4; j++) {
        f4v bc;
        bc[0] = bf2f(bh[g][j].x); bc[1] = bf2f(bh[g][j].y);
        bc[2] = bf2f(bh[g][j].z); bc[3] = bf2f(bh[g][j].w);
        int kr = j * 16 + l15;
        s8v kf0 = *(const s8v*)(Kc + kr * 64 + ((l4 ^ (kr & 7)) << 3));
        s8v kf1 = *(const s8v*)(Kc + kr * 64 + (((l4 + 4) ^ (kr & 7)) << 3));
        s[j] = __builtin_amdgcn_mfma_f32_16x16x32_bf16(kf0, qf[g][0], bc, 0, 0, 0);
        s[j] = __builtin_amdgcn_mfma_f32_16x16x32_bf16(kf1, qf[g][1], s[j], 0, 0, 0);
      }
      if (kt == diag) {
#pragma unroll
        for (int j = 0; j < 4; j++)
#pragma unroll
          for (int r = 0; r < 4; r++) {
            int kk = j * 16 + l4 * 4 + r, qq = w * 16 + l15;
            s[j][r] = (kk > qq) ? 0.f : fexp2(s[j][r]);
          }
      } else {
#pragma unroll
        for (int j = 0; j < 4; j++)
#pragma unroll
          for (int r = 0; r < 4; r++) s[j][r] = fexp2(s[j][r]);
      }
      unsigned X0[4], X1[4];
#pragma unroll
      for (int j = 0; j < 4; j++) {
        X0[j] = cvtpk(s[j][0], s[j][1]);
        X1[j] = cvtpk(s[j][2], s[j][3]);
      }
      u2v a0 = __builtin_amdgcn_permlane32_swap(X0[0], X0[1], false, false);
      u2v a1 = __builtin_amdgcn_permlane16_swap(a0[0], a0[1], false, false);
      u2v b0 = __builtin_amdgcn_permlane32_swap(X1[0], X1[1], false, false);
      u2v b1 = __builtin_amdgcn_permlane16_swap(b0[0], b0[1], false, false);
      u2v c0 = __builtin_amdgcn_permlane32_swap(X0[2], X0[3], false, false);
      u2v c1 = __builtin_amdgcn_permlane16_swap(c0[0], c0[1], false, false);
      u2v d0 = __builtin_amdgcn_permlane32_swap(X1[2], X1[3], false, false);
      u2v d1 = __builtin_amdgcn_permlane16_swap(d0[0], d0[1], false, false);
      u4v P0 = {a1[0], b1[0], a1[1], b1[1]};  // k 0..31
      u4v P1 = {c1[0], d1[0], c1[1], d1[1]};  // k 32..63
      s8v pf0 = __builtin_bit_cast(s8v, P0);
      s8v pf1 = __builtin_bit_cast(s8v, P1);
      lac[g] = __builtin_amdgcn_mfma_f32_16x16x32_bf16(pf0, ones, lac[g], 0, 0, 0);
      lac[g] = __builtin_amdgcn_mfma_f32_16x16x32_bf16(pf1, ones, lac[g], 0, 0, 0);
#pragma unroll
      for (int j = 0; j < 4; j++) {
        int dr = j * 16 + l15;
        s8v vf0 = *(const s8v*)(Vc + dr * 64 + ((l4 ^ (dr & 7)) << 3));
        s8v vf1 = *(const s8v*)(Vc + dr * 64 + (((l4 + 4) ^ (dr & 7)) << 3));
        o[g][j] = __builtin_amdgcn_mfma_f32_16x16x32_bf16(pf0, vf0, o[g][j], 0, 0, 0);
        o[g][j] = __builtin_amdgcn_mfma_f32_16x16x32_bf16(pf1, vf1, o[g][j], 0, 0, 0);
      }
    }
    __builtin_amdgcn_s_barrier();
  }
#pragma unroll
  for (int g = 0; g < 2; g++)
#pragma unroll
    for (int r = 0; r < 4; r++) {
      float rl = 1.f / lac[g][r];
      int qr = qt * 128 + g * 64 + w * 16 + l4 * 4 + r;
#pragma unroll
      for (int j = 0; j < 4; j++) {
        int d = j * 16 + l15;
        ao[(size_t)(b * 1024 + qr) * 512 + h * 64 + d] = f2bf(o[g][j][r] * rl);
      }
    }
}

// ---------------- head GEMM ----------------
__global__ __launch_bounds__(256) void head_k(const short* __restrict__ X,
                                              const short* __restrict__ hWT,
                                              const float* __restrict__ hb,
                                              float* __restrict__ out) {
  __shared__ __align__(16) short lA[128 * 64];
  int tid = threadIdx.x, lane = tid & 63, w = tid >> 6;
  int l15 = lane & 15, l4 = lane >> 4;
  int lrow = lane >> 3, lchunk = lane & 7;
  int m0 = blockIdx.x * 128;
  f4v z4 = {0.f, 0.f, 0.f, 0.f};
  f4v acc[2][2];
#pragma unroll
  for (int i = 0; i < 2; i++)
#pragma unroll
    for (int j = 0; j < 2; j++) acc[i][j] = z4;

  for (int k0 = 0; k0 < 512; k0 += 64) {
#pragma unroll
    for (int t = 0; t < 4; t++) {
      int r0 = (w * 4 + t) * 8;
      int row = r0 + lrow;
      gl_lds16(X + (size_t)(m0 + row) * 512 + k0 + ((lchunk ^ (row & 7)) << 3), lA + r0 * 64);
    }
    __syncthreads();
#pragma unroll
    for (int kk = 0; kk < 2; kk++) {
      s8v af[2], bfr[2];
#pragma unroll
      for (int i = 0; i < 2; i++) {
        int ra = w * 32 + i * 16 + l15;
        af[i] = *(const s8v*)(lA + ra * 64 + (((l4 + kk * 4) ^ (ra & 7)) << 3));
      }
#pragma unroll
      for (int j = 0; j < 2; j++)
        bfr[j] = *(const s8v*)(hWT + (size_t)(j * 16 + l15) * 512 + k0 + kk * 32 + l4 * 8);
#pragma unroll
      for (int i = 0; i < 2; i++)
#pragma unroll
        for (int j = 0; j < 2; j++)
          acc[i][j] = __builtin_amdgcn_mfma_f32_16x16x32_bf16(af[i], bfr[j], acc[i][j], 0, 0, 0);
    }
    __syncthreads();
  }
#pragma unroll
  for (int i = 0; i < 2; i++) {
#pragma unroll
    for (int j = 0; j < 2; j++) {
      int col = j * 16 + l15;
      if (col < 24) {
        float bv = hb[col];
#pragma unroll
        for (int r = 0; r < 4; r++) {
          int row = m0 + w * 32 + i * 16 + l4 * 4 + r;
          out[(size_t)row * 24 + col] = acc[i][j][r] + bv;
        }
      }
    }
  }
}

// ---------------- launch ----------------
extern "C" void kernel_launch(void* const* d_in, const int* in_sizes, int n_in,
                              void* d_out, int out_size, void* d_ws, size_t ws_size,
                              hipStream_t stream) {
  (void)in_sizes; (void)n_in; (void)out_size;
  const float* theta   = (const float*)d_in[0];
  const float* cond    = (const float*)d_in[1];
  const float* attn_b  = (const float*)d_in[2];
  const float* embed_W = (const float*)d_in[3];
  const float* embed_b = (const float*)d_in[4];
  const float* ln1_g   = (const float*)d_in[5];
  const float* ln1_b   = (const float*)d_in[6];
  const float* ada1_W  = (const float*)d_in[7];
  const float* ada1_b  = (const float*)d_in[8];
  const float* Wq      = (const float*)d_in[9];
  const float* bq      = (const float*)d_in[10];
  const float* Wk      = (const float*)d_in[11];
  const float* bk      = (const float*)d_in[12];
  const float* Wv      = (const float*)d_in[13];
  const float* bv      = (const float*)d_in[14];
  const float* Wo      = (const float*)d_in[15];
  const float* bo      = (const float*)d_in[16];
  const float* ln2_g   = (const float*)d_in[17];
  const float* ln2_b   = (const float*)d_in[18];
  const float* ada2_W  = (const float*)d_in[19];
  const float* ada2_b  = (const float*)d_in[20];
  const float* W1      = (const float*)d_in[21];
  const float* b1      = (const float*)d_in[22];
  const float* W2      = (const float*)d_in[23];
  const float* b2      = (const float*)d_in[24];
  const float* fn_g    = (const float*)d_in[25];
  const float* fn_b    = (const float*)d_in[26];
  const float* head_W  = (const float*)d_in[27];
  const float* head_b  = (const float*)d_in[28];

  const size_t REQ = 242814976ull;
  const size_t REQ2 = 259592192ull;
  if (ws_size < REQ) return;
  bool bias_once = (ws_size >= REQ2);

  char* ws = (char*)d_ws;
  float* xw    = (float*)(ws + 0ull);
  short* qk    = (short*)(ws + 67108864ull);
  short* vtb   = (short*)(ws + 134217728ull);   // V^T, then Wo-delta
  short* biasT = (short*)(ws + (bias_once ? 242814976ull : 167772160ull));
  short* qf    = (short*)(ws + 67108864ull);
  short* hbuf  = (short*)(ws + 201326592ull);   // adaln out / attn out / FF2 delta
  short* wbf   = (short*)(ws + 234881024ull);
  float* ssb   = (float*)(ws + 241172480ull);
  float* bqkv  = (float*)(ws + 242745344ull);
  short* hWT   = (short*)(ws + 242782208ull);

  concat_qkvb_k<<<6, 256, 0, stream>>>(bq, bk, bv, bqkv);
  cond_proj_k<<<dim3(4, 12), 256, 0, stream>>>(cond, ada1_W, ada1_b, ada2_W, ada2_b, ssb);
  hwt_k<<<64, 256, 0, stream>>>(head_W, hWT);
  embed_k<<<8192, 256, 0, stream>>>(theta, embed_W, embed_b, xw);
  if (bias_once) bias_cvt_k<<<8192, 256, 0, stream>>>(attn_b, biasT);

  for (int l = 0; l < 6; l++) {
    transpose_all_k<<<3072, 256, 0, stream>>>(Wq, Wk, Wv, Wo, W1, W2, l, wbf);
    if (!bias_once) bias_cvt_k<<<8192, 256, 0, stream>>>(attn_b, biasT);

    if (l == 0)
      adaln_k<false><<<8192, 256, 0, stream>>>(xw, nullptr, ssb + (size_t)(l * 2) * 32768,
                                               ln1_g + l * 512, ln1_b + l * 512, hbuf);
    else  // delta = FF2 delta from layer l-1, lives in hbuf; h also hbuf (safe)
      adaln_k<true><<<8192, 256, 0, stream>>>(xw, hbuf, ssb + (size_t)(l * 2) * 32768,
                                              ln1_g + l * 512, ln1_b + l * 512, hbuf);
    qk_proj_k<<<2048, 256, 0, stream>>>(hbuf, wbf, bqkv + l * 1536, qk);
    v_proj_k<<<1024, 256, 0, stream>>>(hbuf, wbf, bqkv + l * 1536, vtb);
    attn_k<<<2048, 256, 0, stream>>>(qk, vtb, biasT, hbuf);
    // Wo: 128x256 8-wave template, grid 512 (2 blk/CU exact); delta -> vtb,
    // folded IMMEDIATELY by adaln2 (vtb must not outlive FF1)
    gemm_w_k<0><<<512, 512, 0, stream>>>(hbuf, wbf + 786432, bo + l * 512, vtb, 512, 512);
    adaln_k<true><<<8192, 256, 0, stream>>>(xw, vtb, ssb + (size_t)(l * 2 + 1) * 32768,
                                            ln2_g + l * 512, ln2_b + l * 512, hbuf);
    // FF1: 128x256 ring-3, 8 waves (exp2-gelu epilogue), grid 2048
    gemm_w_k<1><<<2048, 512, 0, stream>>>(hbuf, wbf + 1048576, b1 + l * 2048, qf, 2048, 512);
    // FF2: 128x256 template, grid 512; delta -> hbuf (disjoint from qf)
    gemm_w_k<0><<<512, 512, 0, stream>>>(qf, wbf + 2097152, b2 + l * 512, hbuf, 512, 2048);
  }
  fln_k<<<8192, 256, 0, stream>>>(xw, hbuf, fn_g, fn_b, hbuf);
  head_k<<<256, 256, 0, stream>>>(hbuf, hWT, head_b, (float*)d_out);
}

// Round 17
// 2475.807 us; speedup vs baseline: 1.0791x; 1.0065x over previous
//
#include <hip/hip_runtime.h>

// ContinuousLatticeGPT: B=32 S=1024 D=512 H=8 NL=6 DFF=2048 C=128 K=8
// bf16 MFMA; fp32 residual stream with deferred (bf16 delta) residual adds.
// r17 = r16 + qk_proj moved onto the 128x256 8-wave ring-3 template (EPI=2:
// block-uniform Q_SCALE epilogue; Q/K col boundary 512 aligns to 256-tiles).
// Template now carries FF1(gelu)/Wo/FF2/qk_proj; grid residency exact at
// 2 blk/CU (512/1024/2048 grids). v_proj keeps the 128x128 ring-3 swapped body.
//  - gelu epilogue: log2e folded constants -> raw v_exp_f32 + v_rcp_f32.
// All GEMMs: lane-adjacent 64B-row staging + chunk^=((row>>1)&3) swizzle
// (TA-coalesced AND bank-conflict-free).
// attn: swapped-QK (mfma(K,Q)) with in-register P transpose via cvt_pk+permlane;
// exp2-folded softmax (log2e in q-scale & bias). No setprio (r9: +12us).
// Delta routing: Wo-delta -> vtb (dead V^T), folded IMMEDIATELY by adaln2
// (r13 lesson: vtb must NOT outlive FF1 - qf overwrites its region);
// FF2-delta -> hbuf (dead FF1 input, disjoint from qf), folded next adaln1/fln.
// ws layout (bytes): unchanged. REQ 242,814,976 B

typedef short s8v __attribute__((ext_vector_type(8)));
typedef float f4v __attribute__((ext_vector_type(4)));
typedef unsigned u2v __attribute__((ext_vector_type(2)));
typedef unsigned u4v __attribute__((ext_vector_type(4)));

#define Q_SCALE 0.18033688011112042f  // 0.125 * log2(e)
#define LOG2E   1.4426950408889634f

static __device__ __forceinline__ short f2bf(float f) {
  union { float f; unsigned u; } v; v.f = f;
  unsigned r = v.u + 0x7fffu + ((v.u >> 16) & 1u);
  return (short)(r >> 16);
}
static __device__ __forceinline__ float bf2f(unsigned short s) {
  union { unsigned u; float f; } v; v.u = ((unsigned)s) << 16;
  return v.f;
}
static __device__ __forceinline__ unsigned cvtpk(float lo, float hi) {
  unsigned r;
  asm("v_cvt_pk_bf16_f32 %0, %1, %2" : "=v"(r) : "v"(lo), "v"(hi));
  return r;
}
static __device__ __forceinline__ float fexp2(float x) {  // 2^x, single v_exp_f32
  float r;
  asm("v_exp_f32 %0, %1" : "=v"(r) : "v"(x));
  return r;
}
static __device__ __forceinline__ float frcp(float x) {  // ~1ulp reciprocal
  float r;
  asm("v_rcp_f32 %0, %1" : "=v"(r) : "v"(x));
  return r;
}
static __device__ __forceinline__ void gl_lds16(const short* g, short* l) {
  __builtin_amdgcn_global_load_lds(
      (const __attribute__((address_space(1))) unsigned int*)g,
      (__attribute__((address_space(3))) unsigned int*)l, 16, 0, 0);
}

// ---------------- prep kernels ----------------
__global__ void transpose_all_k(const float* __restrict__ Wq, const float* __restrict__ Wk,
                                const float* __restrict__ Wv, const float* __restrict__ Wo,
                                const float* __restrict__ W1, const float* __restrict__ W2,
                                int l, short* __restrict__ wbf) {
  int id = blockIdx.x;
  const float* in; short* out; int K, N, tx, ty;
  if (id < 1024) {
    int m = id >> 8, t = id & 255;
    in = (m == 0 ? Wq : m == 1 ? Wk : m == 2 ? Wv : Wo) + (size_t)l * 262144;
    out = wbf + (size_t)m * 262144;
    K = 512; N = 512; tx = t & 15; ty = t >> 4;
  } else if (id < 2048) {
    int t = id - 1024;
    in = W1 + (size_t)l * 1048576; out = wbf + 1048576;
    K = 512; N = 2048; tx = t & 63; ty = t >> 6;
  } else {
    int t = id - 2048;
    in = W2 + (size_t)l * 1048576; out = wbf + 2097152;
    K = 2048; N = 512; tx = t & 15; ty = t >> 4;
  }
  __shared__ float tb[32][33];
  int n0 = tx * 32, k0 = ty * 32;
  int cx = threadIdx.x & 31, cy = threadIdx.x >> 5;
#pragma unroll
  for (int r = 0; r < 4; r++)
    tb[cy + r * 8][cx] = in[(size_t)(k0 + cy + r * 8) * N + n0 + cx];
  __syncthreads();
#pragma unroll
  for (int r = 0; r < 4; r++)
    out[(size_t)(n0 + cy + r * 8) * K + k0 + cx] = f2bf(tb[cx][cy + r * 8]);
}

// f32 -> bf16 copy of attn_bias, folding log2(e) for the exp2 softmax
__global__ void bias_cvt_k(const float* __restrict__ in, short* __restrict__ out) {
  int i = blockIdx.x * 256 + threadIdx.x;  // float4 index; grid covers 8M floats
  float4 v = ((const float4*)in)[i];
  ushort4 o;
  o.x = (unsigned short)f2bf(v.x * LOG2E);
  o.y = (unsigned short)f2bf(v.y * LOG2E);
  o.z = (unsigned short)f2bf(v.z * LOG2E);
  o.w = (unsigned short)f2bf(v.w * LOG2E);
  ((ushort4*)out)[i] = o;
}

__global__ void hwt_k(const float* __restrict__ hW, short* __restrict__ hWT) {
  int i = blockIdx.x * 256 + threadIdx.x;
  int n = i >> 9, k = i & 511;
  hWT[i] = (n < 24) ? f2bf(hW[(size_t)k * 24 + n]) : (short)0;
}

__global__ void concat_qkvb_k(const float* bq, const float* bk, const float* bv, float* out) {
  int l = blockIdx.x;
  for (int i = threadIdx.x; i < 1536; i += 256) {
    float v = (i < 512) ? bq[l * 512 + i] * Q_SCALE  // fold 1/sqrt(HD)*log2e into q bias
            : (i < 1024 ? bk[l * 512 + i - 512] : bv[l * 512 + i - 1024]);
    out[l * 1536 + i] = v;
  }
}

__global__ void cond_proj_k(const float* __restrict__ cond,
                            const float* __restrict__ a1W, const float* __restrict__ a1b,
                            const float* __restrict__ a2W, const float* __restrict__ a2b,
                            float* __restrict__ ss) {
  int lw = blockIdx.y, which = lw & 1, l = lw >> 1;
  const float* W = (which ? a2W : a1W) + (size_t)l * 128 * 1024;
  const float* bb = (which ? a2b : a1b) + (size_t)l * 1024;
  __shared__ float cs[32 * 128];
  for (int i = threadIdx.x; i < 32 * 128; i += 256) cs[i] = cond[i];
  __syncthreads();
  int n = blockIdx.x * 256 + threadIdx.x;
  float bias = bb[n];
  for (int g = 0; g < 4; g++) {
    float acc[8];
#pragma unroll
    for (int i = 0; i < 8; i++) acc[i] = 0.f;
    for (int c = 0; c < 128; c++) {
      float w = W[(size_t)c * 1024 + n];
#pragma unroll
      for (int i = 0; i < 8; i++) acc[i] += cs[(g * 8 + i) * 128 + c] * w;
    }
#pragma unroll
    for (int i = 0; i < 8; i++)
      ss[((size_t)lw * 32 + g * 8 + i) * 1024 + n] = acc[i] + bias;
  }
}

__global__ void embed_k(const float* __restrict__ theta, const float* __restrict__ eW,
                        const float* __restrict__ eb, float* __restrict__ x) {
  int row = blockIdx.x * 4 + (threadIdx.x >> 6), lane = threadIdx.x & 63;
  float th = theta[row], sn, cn;
  sincosf(th, &sn, &cn);
  int d = lane * 8;
  float* xo = x + (size_t)row * 512 + d;
#pragma unroll
  for (int i = 0; i < 8; i++) xo[i] = cn * eW[d + i] + sn * eW[512 + d + i] + eb[d + i];
}

// AdaLN; optionally folds a deferred bf16 residual delta (may ALIAS h!) and updates xw.
template<bool HASDEL>
__global__ void adaln_k(float* __restrict__ x, const short* delta,
                        const float* __restrict__ ss,
                        const float* __restrict__ g, const float* __restrict__ be,
                        short* h) {
  int row = blockIdx.x * 4 + (threadIdx.x >> 6), lane = threadIdx.x & 63;
  int b = row >> 10;
  float* xr = x + (size_t)row * 512 + lane * 8;
  float4 va = ((const float4*)xr)[0], vb = ((const float4*)xr)[1];
  float v[8] = {va.x, va.y, va.z, va.w, vb.x, vb.y, vb.z, vb.w};
  if (HASDEL) {
    s8v dv = *(const s8v*)(delta + (size_t)row * 512 + lane * 8);
#pragma unroll
    for (int i = 0; i < 8; i++) v[i] += bf2f((unsigned short)dv[i]);
    float4 o0 = {v[0], v[1], v[2], v[3]}, o1 = {v[4], v[5], v[6], v[7]};
    ((float4*)xr)[0] = o0; ((float4*)xr)[1] = o1;
  }
  float sm = 0.f;
#pragma unroll
  for (int i = 0; i < 8; i++) sm += v[i];
#pragma unroll
  for (int off = 1; off < 64; off <<= 1) sm += __shfl_xor(sm, off);
  float mean = sm * (1.f / 512.f);
  float sq = 0.f;
#pragma unroll
  for (int i = 0; i < 8; i++) { float d = v[i] - mean; sq += d * d; }
#pragma unroll
  for (int off = 1; off < 64; off <<= 1) sq += __shfl_xor(sq, off);
  float rs = rsqrtf(sq * (1.f / 512.f) + 1e-5f);
  const float* sb = ss + (size_t)b * 1024 + lane * 8;
  const float* gp = g + lane * 8;
  const float* bp = be + lane * 8;
  s8v o;
#pragma unroll
  for (int i = 0; i < 8; i++) {
    float xh = (v[i] - mean) * rs * gp[i] + bp[i];
    o[i] = f2bf((1.f + sb[i]) * xh + sb[i + 512]);
  }
  *(s8v*)(h + (size_t)row * 512 + lane * 8) = o;
}

// final LN, folding FF2's delta (delta may ALIAS h)
__global__ void fln_k(const float* __restrict__ x, const short* delta,
                      const float* __restrict__ g, const float* __restrict__ be,
                      short* h) {
  int row = blockIdx.x * 4 + (threadIdx.x >> 6), lane = threadIdx.x & 63;
  const float* xr = x + (size_t)row * 512 + lane * 8;
  float4 va = ((const float4*)xr)[0], vb = ((const float4*)xr)[1];
  float v[8] = {va.x, va.y, va.z, va.w, vb.x, vb.y, vb.z, vb.w};
  s8v dv = *(const s8v*)(delta + (size_t)row * 512 + lane * 8);
#pragma unroll
  for (int i = 0; i < 8; i++) v[i] += bf2f((unsigned short)dv[i]);
  float sm = 0.f;
#pragma unroll
  for (int i = 0; i < 8; i++) sm += v[i];
#pragma unroll
  for (int off = 1; off < 64; off <<= 1) sm += __shfl_xor(sm, off);
  float mean = sm * (1.f / 512.f);
  float sq = 0.f;
#pragma unroll
  for (int i = 0; i < 8; i++) { float d = v[i] - mean; sq += d * d; }
#pragma unroll
  for (int off = 1; off < 64; off <<= 1) sq += __shfl_xor(sq, off);
  float rs = rsqrtf(sq * (1.f / 512.f) + 1e-5f);
  const float* gp = g + lane * 8;
  const float* bp = be + lane * 8;
  s8v o;
#pragma unroll
  for (int i = 0; i < 8; i++) o[i] = f2bf((v[i] - mean) * rs * gp[i] + bp[i]);
  *(s8v*)(h + (size_t)row * 512 + lane * 8) = o;
}

// --- GEMM 128x256, BK=32, ring-3, 512 thr (8 waves 2Mx4N), 72KB LDS ---
// (FF1 / Wo / FF2 / qk_proj.) 32 MFMAs per barrier-pair, staging bytes/FLOP
// -25% vs 128x128, 2 blk/CU = 16 waves/CU, grids sized for exact residency.
// Staging: 384 rows (128 A + 256 B) x 64B; thread covers 3 lane-adjacent 16B
// chunks; per-(w,tt) A/B choice is wave-uniform (boundary 128 = 2*48+32 exact).
// Counted vmcnt: 3 loads/thread/tile -> vmcnt(3) steady, vmcnt(0) tail.
// EPI 0: bf16 (+bias); 1: gelu bf16 (exp2-folded + v_rcp);
// EPI 2: qk epilogue - block-uniform scale (Q_SCALE if n0<512) then +bias.
template<int EPI>
__global__ __launch_bounds__(512, 2) void gemm_w_k(const short* __restrict__ A,
                                                   const short* __restrict__ BT,
                                                   const float* __restrict__ bias,
                                                   short* __restrict__ outb,
                                                   int N, int K) {
  __shared__ __align__(16) short lsA[3][4096];  // 3 x 8KB  (128 rows)
  __shared__ __align__(16) short lsB[3][8192];  // 3 x 16KB (256 rows)
  int tid = threadIdx.x, lane = tid & 63, w = tid >> 6;  // w in [0,8)
  int wm = w >> 2, wn = w & 3;                            // 2M x 4N waves
  int l15 = lane & 15, l4 = lane >> 4;
  int lrow = lane >> 2, lchunk = lane & 3;
  int poff = ((l15 << 2) + (l4 ^ ((l15 >> 1) & 3))) << 3;
  int nb = N >> 8;                                        // 256-wide N tiles
  int bid = blockIdx.x;
  int xcd = bid & 7, rr = bid >> 3;
  int mloc = rr / nb, nidx = rr - mloc * nb;
  int m0 = (xcd * 32 + mloc) << 7, n0 = nidx << 8;

  f4v z4 = {0.f, 0.f, 0.f, 0.f};
  f4v acc[4][4];
#pragma unroll
  for (int i = 0; i < 4; i++)
#pragma unroll
    for (int j = 0; j < 4; j++) acc[i][j] = z4;

  int co = (lchunk ^ ((lrow >> 1) & 3)) << 3;

  auto STAGE = [&](int t) {  // 3 DMA ops per thread; 384 rows total
    int slot = t % 3;
    int ko = t << 5;
#pragma unroll
    for (int tt = 0; tt < 3; tt++) {
      int r0 = w * 48 + tt * 16;          // wave-uniform; 0..368 step 16
      int row = r0 + lrow;
      if (r0 < 128) {                      // A rows [0,128)
        gl_lds16(A + (size_t)(m0 + row) * K + ko + co, lsA[slot] + r0 * 32);
      } else {                             // B rows [0,256)
        int rb = row - 128;
        gl_lds16(BT + (size_t)(n0 + rb) * K + ko + co, lsB[slot] + (r0 - 128) * 32);
      }
    }
  };
  auto LOADF = [&](int t, s8v* af, s8v* bfr) {
    int slot = t % 3;
    const short* At = lsA[slot] + (wm * 4) * 512 + poff;
    const short* Bt = lsB[slot] + (wn * 4) * 512 + poff;
#pragma unroll
    for (int i = 0; i < 4; i++) {
      af[i] = *(const s8v*)(At + i * 512);
      bfr[i] = *(const s8v*)(Bt + i * 512);
    }
  };

  int NT = K >> 5;
  STAGE(0); STAGE(1);
  asm volatile("s_waitcnt vmcnt(3)" ::: "memory");  // tile 0 landed
  __builtin_amdgcn_s_barrier();
  s8v af[4], bfr[4];
  LOADF(0, af, bfr);
  for (int t = 0; t < NT; ++t) {
    if (t + 2 < NT) STAGE(t + 2);
    __builtin_amdgcn_sched_barrier(0);   // pin VMEM issue before the MFMA burst
#pragma unroll
    for (int i = 0; i < 4; i++)
#pragma unroll
      for (int j = 0; j < 4; j++)
        acc[i][j] = __builtin_amdgcn_mfma_f32_16x16x32_bf16(af[i], bfr[j], acc[i][j], 0, 0, 0);
    if (t + 1 < NT) {
      if (t + 2 < NT) asm volatile("s_waitcnt vmcnt(3)" ::: "memory");  // t+1 landed
      else            asm volatile("s_waitcnt vmcnt(0)" ::: "memory");  // tail
      __builtin_amdgcn_s_barrier();
      LOADF(t + 1, af, bfr);   // frags for next iter; latency covered by backedge
    }
  }
  float scl = (EPI == 2) ? ((n0 < 512) ? Q_SCALE : 1.f) : 1.f;
#pragma unroll
  for (int i = 0; i < 4; i++) {
    int gr0 = m0 + wm * 64 + i * 16 + l4 * 4;
#pragma unroll
    for (int j = 0; j < 4; j++) {
      int gc = n0 + wn * 64 + j * 16 + l15;
      float bv = bias[gc];
#pragma unroll
      for (int r = 0; r < 4; r++) {
        float v;
        if (EPI == 2) {
          v = acc[i][j][r] * scl + bv;
        } else {
          v = acc[i][j][r] + bv;
          if (EPI == 1) {
            // sigmoid-gelu with log2e prefolded: v * sigmoid(1.5958v + 0.07135v^3)
            float tg = v * (-2.3022083f - 0.10294325f * v * v);
            v = v * frcp(1.f + fexp2(tg));
          }
        }
        outb[(size_t)(gr0 + r) * N + gc] = f2bf(v);
      }
    }
  }
}

// --- V projection: ring-3 128x128, operand-swapped MFMA -> V^T scatter. grid 1024. ---
__global__ __launch_bounds__(256, 3) void v_proj_k(const short* __restrict__ A,
                                                   const short* __restrict__ BT,
                                                   const float* __restrict__ bias,
                                                   short* __restrict__ vtb) {
  __shared__ __align__(16) short lsA[3][4096];
  __shared__ __align__(16) short lsB[3][4096];
  int tid = threadIdx.x, lane = tid & 63, w = tid >> 6;
  int wm = w >> 1, wn = w & 1;
  int l15 = lane & 15, l4 = lane >> 4;
  int lrow = lane >> 2, lchunk = lane & 3;
  int poff = ((l15 << 2) + (l4 ^ ((l15 >> 1) & 3))) << 3;
  int bid = blockIdx.x;
  int xcd = bid & 7, rr = bid >> 3;
  int mloc = rr >> 2, nidx = rr & 3;
  int m0 = (xcd * 32 + mloc) << 7, n0 = 1024 + (nidx << 7);

  f4v z4 = {0.f, 0.f, 0.f, 0.f};
  f4v acc[4][4];
#pragma unroll
  for (int i = 0; i < 4; i++)
#pragma unroll
    for (int j = 0; j < 4; j++) acc[i][j] = z4;

  int co = (lchunk ^ ((lrow >> 1) & 3)) << 3;

  auto STAGE = [&](int t) {
    int slot = t % 3;
    int ko = t << 5;
#pragma unroll
    for (int tt = 0; tt < 2; tt++) {
      int r0 = w * 32 + tt * 16;
      int row = r0 + lrow;
      gl_lds16(A + (size_t)(m0 + row) * 512 + ko + co, lsA[slot] + r0 * 32);
      gl_lds16(BT + (size_t)(n0 + row) * 512 + ko + co, lsB[slot] + r0 * 32);
    }
  };
  auto LOADF = [&](int t, s8v* af, s8v* bfr) {
    int slot = t % 3;
    const short* At = lsA[slot] + (wm * 4) * 512 + poff;
    const short* Bt = lsB[slot] + (wn * 4) * 512 + poff;
#pragma unroll
    for (int i = 0; i < 4; i++) {
      af[i] = *(const s8v*)(At + i * 512);
      bfr[i] = *(const s8v*)(Bt + i * 512);
    }
  };

  const int NT = 16;
  STAGE(0); STAGE(1);
  asm volatile("s_waitcnt vmcnt(4)" ::: "memory");
  __builtin_amdgcn_s_barrier();
  s8v af[4], bfr[4];
  LOADF(0, af, bfr);
  for (int t = 0; t < NT; ++t) {
    if (t + 2 < NT) STAGE(t + 2);
    __builtin_amdgcn_sched_barrier(0);
#pragma unroll
    for (int j = 0; j < 4; j++)
#pragma unroll
      for (int i = 0; i < 4; i++)
        acc[j][i] = __builtin_amdgcn_mfma_f32_16x16x32_bf16(bfr[j], af[i], acc[j][i], 0, 0, 0);
    if (t + 1 < NT) {
      if (t + 2 < NT) asm volatile("s_waitcnt vmcnt(4)" ::: "memory");
      else            asm volatile("s_waitcnt vmcnt(0)" ::: "memory");
      __builtin_amdgcn_s_barrier();
      LOADF(t + 1, af, bfr);
    }
  }
  int b = m0 >> 10, s0 = m0 & 1023;
#pragma unroll
  for (int j = 0; j < 4; j++) {
    int col = n0 + wn * 64 + j * 16 + l4 * 4;
#pragma unroll
    for (int i = 0; i < 4; i++) {
      int scol = s0 + wm * 64 + i * 16 + l15;
#pragma unroll
      for (int r = 0; r < 4; r++) {
        float v = acc[j][i][r] + bias[col + r];
        vtb[((size_t)b * 512 + col - 1024 + r) * 1024 + scol] = f2bf(v);
      }
    }
  }
}

// ---------------- flash attention (QBLK=128, no-max exp2 softmax, bias-as-C) ----------------
// Swapped QK^T: s^T = mfma(K, Q, bias); P transposed back in registers via
// cvt_pk_bf16 + permlane{32,16}_swap. K/V double-buffered, counted vmcnt(4).
// q & bias pre-scaled by log2e -> softmax uses raw v_exp_f32 (2^x).
__global__ __launch_bounds__(256, 4) void attn_k(const short* __restrict__ qk,
                                                 const short* __restrict__ vt,
                                                 const short* __restrict__ biasNT,
                                                 short* __restrict__ ao) {
  __shared__ __align__(16) short Kl[2][64 * 64];
  __shared__ __align__(16) short Vl[2][64 * 64];
  int tid = threadIdx.x, lane = tid & 63, w = tid >> 6;
  int bid = blockIdx.x;
  int qt = 7 - (bid >> 8), b = (bid >> 3) & 31, h = bid & 7;
  int l15 = lane & 15, l4 = lane >> 4;
  int lrow = lane >> 3, lchunk = lane & 7;

  f4v z4 = {0.f, 0.f, 0.f, 0.f};
  s8v qf[2][2];
#pragma unroll
  for (int g = 0; g < 2; g++) {
    const short* qp = qk + (size_t)(b * 1024 + qt * 128 + g * 64 + w * 16 + l15) * 1024 + h * 64;
    qf[g][0] = *(const s8v*)(qp + l4 * 8);
    qf[g][1] = *(const s8v*)(qp + 32 + l4 * 8);
  }
  f4v o[2][4], lac[2];
#pragma unroll
  for (int g = 0; g < 2; g++) {
    lac[g] = z4;
#pragma unroll
    for (int j = 0; j < 4; j++) o[g][j] = z4;
  }
  s8v ones;
#pragma unroll
  for (int e = 0; e < 8; e++) ones[e] = (short)0x3F80;

  auto STAGE = [&](int buf, int kt) {
#pragma unroll
    for (int t = 0; t < 2; t++) {
      int r0 = (w * 2 + t) * 8;
      int row = r0 + lrow;
      gl_lds16(qk + (size_t)(b * 1024 + kt * 64 + row) * 1024 + 512 + h * 64 +
                   ((lchunk ^ (row & 7)) << 3),
               &Kl[buf][r0 * 64]);
      gl_lds16(vt + (size_t)(b * 512 + h * 64 + row) * 1024 + kt * 64 +
                   ((lchunk ^ (row & 7)) << 3),
               &Vl[buf][r0 * 64]);
    }
  };

  int nkt = 2 * qt + 2;
  STAGE(0, 0);
  for (int kt = 0; kt < nkt; kt++) {
    int cur = kt & 1;
    ushort4 bh[2][4];
#pragma unroll
    for (int g = 0; g < 2; g++) {
      if (kt > 2 * qt + g) continue;
      const short* bp = biasNT + ((size_t)h * 1024 + qt * 128 + g * 64 + w * 16 + l15) * 1024 +
                        kt * 64 + l4 * 4;
#pragma unroll
      for (int j = 0; j < 4; j++) bh[g][j] = *(const ushort4*)(bp + j * 16);
    }
    __builtin_amdgcn_sched_barrier(0);  // keep bias loads ahead of the staging DMA
    if (kt + 1 < nkt) {
      STAGE(cur ^ 1, kt + 1);
      asm volatile("s_waitcnt vmcnt(4)" ::: "memory");
    } else {
      asm volatile("s_waitcnt vmcnt(0)" ::: "memory");
    }
    __builtin_amdgcn_s_barrier();
    const short* Kc = &Kl[cur][0];
    const short* Vc = &Vl[cur][0];
#pragma unroll
    for (int g = 0; g < 2; g++) {
      int diag = 2 * qt + g;
      if (kt > diag) continue;
      f4v s[4];
#pragma unroll
      for (int j = 0; j < 4; j++) {
        f4v bc;
        bc[0] = bf2f(bh[g][j].x); bc[1] = bf2f(bh[g][j].y);
        bc[2] = bf2f(bh[g][j].z); bc[3] = bf2f(bh[g][j].w);
        int kr = j * 16 + l15;
        s8v kf0 = *(const s8v*)(Kc + kr * 64 + ((l4 ^ (kr & 7)) << 3));
        s8v kf1 = *(const s8v*)(Kc + kr * 64 + (((l4 + 4) ^ (kr & 7)) << 3));
        s[j] = __builtin_amdgcn_mfma_f32_16x16x32_bf16(kf0, qf[g][0], bc, 0, 0, 0);
        s[j] = __builtin_amdgcn_mfma_f32_16x16x32_bf16(kf1, qf[g][1], s[j], 0, 0, 0);
      }
      if (kt == diag) {
#pragma unroll
        for (int j = 0; j < 4; j++)
#pragma unroll
          for (int r = 0; r < 4; r++) {
            int kk = j * 16 + l4 * 4 + r, qq = w * 16 + l15;
            s[j][r] = (kk > qq) ? 0.f : fexp2(s[j][r]);
          }
      } else {
#pragma unroll
        for (int j = 0; j < 4; j++)
#pragma unroll
          for (int r = 0; r < 4; r++) s[j][r] = fexp2(s[j][r]);
      }
      unsigned X0[4], X1[4];
#pragma unroll
      for (int j = 0; j < 4; j++) {
        X0[j] = cvtpk(s[j][0], s[j][1]);
        X1[j] = cvtpk(s[j][2], s[j][3]);
      }
      u2v a0 = __builtin_amdgcn_permlane32_swap(X0[0], X0[1], false, false);
      u2v a1 = __builtin_amdgcn_permlane16_swap(a0[0], a0[1], false, false);
      u2v b0 = __builtin_amdgcn_permlane32_swap(X1[0], X1[1], false, false);
      u2v b1 = __builtin_amdgcn_permlane16_swap(b0[0], b0[1], false, false);
      u2v c0 = __builtin_amdgcn_permlane32_swap(X0[2], X0[3], false, false);
      u2v c1 = __builtin_amdgcn_permlane16_swap(c0[0], c0[1], false, false);
      u2v d0 = __builtin_amdgcn_permlane32_swap(X1[2], X1[3], false, false);
      u2v d1 = __builtin_amdgcn_permlane16_swap(d0[0], d0[1], false, false);
      u4v P0 = {a1[0], b1[0], a1[1], b1[1]};  // k 0..31
      u4v P1 = {c1[0], d1[0], c1[1], d1[1]};  // k 32..63
      s8v pf0 = __builtin_bit_cast(s8v, P0);
      s8v pf1 = __builtin_bit_cast(s8v, P1);
      lac[g] = __builtin_amdgcn_mfma_f32_16x16x32_bf16(pf0, ones, lac[g], 0, 0, 0);
      lac[g] = __builtin_amdgcn_mfma_f32_16x16x32_bf16(pf1, ones, lac[g], 0, 0, 0);
#pragma unroll
      for (int j = 0; j < 4; j++) {
        int dr = j * 16 + l15;
        s8v vf0 = *(const s8v*)(Vc + dr * 64 + ((l4 ^ (dr & 7)) << 3));
        s8v vf1 = *(const s8v*)(Vc + dr * 64 + (((l4 + 4) ^ (dr & 7)) << 3));
        o[g][j] = __builtin_amdgcn_mfma_f32_16x16x32_bf16(pf0, vf0, o[g][j], 0, 0, 0);
        o[g][j] = __builtin_amdgcn_mfma_f32_16x16x32_bf16(pf1, vf1, o[g][j], 0, 0, 0);
      }
    }
    __builtin_amdgcn_s_barrier();
  }
#pragma unroll
  for (int g = 0; g < 2; g++)
#pragma unroll
    for (int r = 0; r < 4; r++) {
      float rl = 1.f / lac[g][r];
      int qr = qt * 128 + g * 64 + w * 16 + l4 * 4 + r;
#pragma unroll
      for (int j = 0; j < 4; j++) {
        int d = j * 16 + l15;
        ao[(size_t)(b * 1024 + qr) * 512 + h * 64 + d] = f2bf(o[g][j][r] * rl);
      }
    }
}

// ---------------- head GEMM ----------------
__global__ __launch_bounds__(256) void head_k(const short* __restrict__ X,
                                              const short* __restrict__ hWT,
                                              const float* __restrict__ hb,
                                              float* __restrict__ out) {
  __shared__ __align__(16) short lA[128 * 64];
  int tid = threadIdx.x, lane = tid & 63, w = tid >> 6;
  int l15 = lane & 15, l4 = lane >> 4;
  int lrow = lane >> 3, lchunk = lane & 7;
  int m0 = blockIdx.x * 128;
  f4v z4 = {0.f, 0.f, 0.f, 0.f};
  f4v acc[2][2];
#pragma unroll
  for (int i = 0; i < 2; i++)
#pragma unroll
    for (int j = 0; j < 2; j++) acc[i][j] = z4;

  for (int k0 = 0; k0 < 512; k0 += 64) {
#pragma unroll
    for (int t = 0; t < 4; t++) {
      int r0 = (w * 4 + t) * 8;
      int row = r0 + lrow;
      gl_lds16(X + (size_t)(m0 + row) * 512 + k0 + ((lchunk ^ (row & 7)) << 3), lA + r0 * 64);
    }
    __syncthreads();
#pragma unroll
    for (int kk = 0; kk < 2; kk++) {
      s8v af[2], bfr[2];
#pragma unroll
      for (int i = 0; i < 2; i++) {
        int ra = w * 32 + i * 16 + l15;
        af[i] = *(const s8v*)(lA + ra * 64 + (((l4 + kk * 4) ^ (ra & 7)) << 3));
      }
#pragma unroll
      for (int j = 0; j < 2; j++)
        bfr[j] = *(const s8v*)(hWT + (size_t)(j * 16 + l15) * 512 + k0 + kk * 32 + l4 * 8);
#pragma unroll
      for (int i = 0; i < 2; i++)
#pragma unroll
        for (int j = 0; j < 2; j++)
          acc[i][j] = __builtin_amdgcn_mfma_f32_16x16x32_bf16(af[i], bfr[j], acc[i][j], 0, 0, 0);
    }
    __syncthreads();
  }
#pragma unroll
  for (int i = 0; i < 2; i++) {
#pragma unroll
    for (int j = 0; j < 2; j++) {
      int col = j * 16 + l15;
      if (col < 24) {
        float bv = hb[col];
#pragma unroll
        for (int r = 0; r < 4; r++) {
          int row = m0 + w * 32 + i * 16 + l4 * 4 + r;
          out[(size_t)row * 24 + col] = acc[i][j][r] + bv;
        }
      }
    }
  }
}

// ---------------- launch ----------------
extern "C" void kernel_launch(void* const* d_in, const int* in_sizes, int n_in,
                              void* d_out, int out_size, void* d_ws, size_t ws_size,
                              hipStream_t stream) {
  (void)in_sizes; (void)n_in; (void)out_size;
  const float* theta   = (const float*)d_in[0];
  const float* cond    = (const float*)d_in[1];
  const float* attn_b  = (const float*)d_in[2];
  const float* embed_W = (const float*)d_in[3];
  const float* embed_b = (const float*)d_in[4];
  const float* ln1_g   = (const float*)d_in[5];
  const float* ln1_b   = (const float*)d_in[6];
  const float* ada1_W  = (const float*)d_in[7];
  const float* ada1_b  = (const float*)d_in[8];
  const float* Wq      = (const float*)d_in[9];
  const float* bq      = (const float*)d_in[10];
  const float* Wk      = (const float*)d_in[11];
  const float* bk      = (const float*)d_in[12];
  const float* Wv      = (const float*)d_in[13];
  const float* bv      = (const float*)d_in[14];
  const float* Wo      = (const float*)d_in[15];
  const float* bo      = (const float*)d_in[16];
  const float* ln2_g   = (const float*)d_in[17];
  const float* ln2_b   = (const float*)d_in[18];
  const float* ada2_W  = (const float*)d_in[19];
  const float* ada2_b  = (const float*)d_in[20];
  const float* W1      = (const float*)d_in[21];
  const float* b1      = (const float*)d_in[22];
  const float* W2      = (const float*)d_in[23];
  const float* b2      = (const float*)d_in[24];
  const float* fn_g    = (const float*)d_in[25];
  const float* fn_b    = (const float*)d_in[26];
  const float* head_W  = (const float*)d_in[27];
  const float* head_b  = (const float*)d_in[28];

  const size_t REQ = 242814976ull;
  const size_t REQ2 = 259592192ull;
  if (ws_size < REQ) return;
  bool bias_once = (ws_size >= REQ2);

  char* ws = (char*)d_ws;
  float* xw    = (float*)(ws + 0ull);
  short* qk    = (short*)(ws + 67108864ull);
  short* vtb   = (short*)(ws + 134217728ull);   // V^T, then Wo-delta
  short* biasT = (short*)(ws + (bias_once ? 242814976ull : 167772160ull));
  short* qf    = (short*)(ws + 67108864ull);
  short* hbuf  = (short*)(ws + 201326592ull);   // adaln out / attn out / FF2 delta
  short* wbf   = (short*)(ws + 234881024ull);
  float* ssb   = (float*)(ws + 241172480ull);
  float* bqkv  = (float*)(ws + 242745344ull);
  short* hWT   = (short*)(ws + 242782208ull);

  concat_qkvb_k<<<6, 256, 0, stream>>>(bq, bk, bv, bqkv);
  cond_proj_k<<<dim3(4, 12), 256, 0, stream>>>(cond, ada1_W, ada1_b, ada2_W, ada2_b, ssb);
  hwt_k<<<64, 256, 0, stream>>>(head_W, hWT);
  embed_k<<<8192, 256, 0, stream>>>(theta, embed_W, embed_b, xw);
  if (bias_once) bias_cvt_k<<<8192, 256, 0, stream>>>(attn_b, biasT);

  for (int l = 0; l < 6; l++) {
    transpose_all_k<<<3072, 256, 0, stream>>>(Wq, Wk, Wv, Wo, W1, W2, l, wbf);
    if (!bias_once) bias_cvt_k<<<8192, 256, 0, stream>>>(attn_b, biasT);

    if (l == 0)
      adaln_k<false><<<8192, 256, 0, stream>>>(xw, nullptr, ssb + (size_t)(l * 2) * 32768,
                                               ln1_g + l * 512, ln1_b + l * 512, hbuf);
    else  // delta = FF2 delta from layer l-1, lives in hbuf; h also hbuf (safe)
      adaln_k<true><<<8192, 256, 0, stream>>>(xw, hbuf, ssb + (size_t)(l * 2) * 32768,
                                              ln1_g + l * 512, ln1_b + l * 512, hbuf);
    // QK projection: 128x256 template, grid 1024, EPI=2 (block-uniform Q scale)
    gemm_w_k<2><<<1024, 512, 0, stream>>>(hbuf, wbf, bqkv + l * 1536, qk, 1024, 512);
    v_proj_k<<<1024, 256, 0, stream>>>(hbuf, wbf, bqkv + l * 1536, vtb);
    attn_k<<<2048, 256, 0, stream>>>(qk, vtb, biasT, hbuf);
    // Wo: 128x256 template, grid 512; delta -> vtb, folded IMMEDIATELY by adaln2
    gemm_w_k<0><<<512, 512, 0, stream>>>(hbuf, wbf + 786432, bo + l * 512, vtb, 512, 512);
    adaln_k<true><<<8192, 256, 0, stream>>>(xw, vtb, ssb + (size_t)(l * 2 + 1) * 32768,
                                            ln2_g + l * 512, ln2_b + l * 512, hbuf);
    // FF1: 128x256 template, grid 2048 (exp2-gelu epilogue)
    gemm_w_k<1><<<2048, 512, 0, stream>>>(hbuf, wbf + 1048576, b1 + l * 2048, qf, 2048, 512);
    // FF2: 128x256 template, grid 512; delta -> hbuf (disjoint from qf)
    gemm_w_k<0><<<512, 512, 0, stream>>>(qf, wbf + 2097152, b2 + l * 512, hbuf, 512, 2048);
  }
  fln_k<<<8192, 256, 0, stream>>>(xw, hbuf, fn_g, fn_b, hbuf);
  head_k<<<256, 256, 0, stream>>>(hbuf, hWT, head_b, (float*)d_out);
}

// Round 18
// 2474.634 us; speedup vs baseline: 1.0796x; 1.0005x over previous
//
#include <hip/hip_runtime.h>

// ContinuousLatticeGPT: B=32 S=1024 D=512 H=8 NL=6 DFF=2048 C=128 K=8
// bf16 MFMA; fp32 residual stream with deferred (bf16 delta) residual adds.
// r18 = r17 + attn widened to QBLK=256 (8 waves, 512 thr, grid 1024): each
// wave keeps the exact r17 per-wave layout (2 g x 16 q-rows, VGPR ~64); the
// two 4-wave halves (h2=w>>2) own 128-row Q segments. One barrier-pair per kt
// now serves 256 q-rows (2x amortization) and K/V are staged once per 256
// q-rows (staging HBM ~halved). Same counted-vmcnt discipline (2 loads/thread
// -> vmcnt(2) steady). Causal skip/mask on 64-row blocks qb=qt*4+h2*2+g vs kt.
// GEMMs: 128x256 8-wave ring-3 template (FF1 gelu / Wo / FF2 / qk_proj EPI=2);
// v_proj keeps the 128x128 ring-3 swapped body.
// All GEMMs: lane-adjacent 64B-row staging + chunk^=((row>>1)&3) swizzle.
// attn softmax exp2-folded (log2e in q-scale & bias). No setprio (r9).
// Delta routing: Wo-delta -> vtb (folded IMMEDIATELY by adaln2; r13: vtb must
// not outlive FF1); FF2-delta -> hbuf (disjoint from qf), folded next adaln1/fln.
// ws layout (bytes): unchanged. REQ 242,814,976 B

typedef short s8v __attribute__((ext_vector_type(8)));
typedef float f4v __attribute__((ext_vector_type(4)));
typedef unsigned u2v __attribute__((ext_vector_type(2)));
typedef unsigned u4v __attribute__((ext_vector_type(4)));

#define Q_SCALE 0.18033688011112042f  // 0.125 * log2(e)
#define LOG2E   1.4426950408889634f

static __device__ __forceinline__ short f2bf(float f) {
  union { float f; unsigned u; } v; v.f = f;
  unsigned r = v.u + 0x7fffu + ((v.u >> 16) & 1u);
  return (short)(r >> 16);
}
static __device__ __forceinline__ float bf2f(unsigned short s) {
  union { unsigned u; float f; } v; v.u = ((unsigned)s) << 16;
  return v.f;
}
static __device__ __forceinline__ unsigned cvtpk(float lo, float hi) {
  unsigned r;
  asm("v_cvt_pk_bf16_f32 %0, %1, %2" : "=v"(r) : "v"(lo), "v"(hi));
  return r;
}
static __device__ __forceinline__ float fexp2(float x) {  // 2^x, single v_exp_f32
  float r;
  asm("v_exp_f32 %0, %1" : "=v"(r) : "v"(x));
  return r;
}
static __device__ __forceinline__ float frcp(float x) {  // ~1ulp reciprocal
  float r;
  asm("v_rcp_f32 %0, %1" : "=v"(r) : "v"(x));
  return r;
}
static __device__ __forceinline__ void gl_lds16(const short* g, short* l) {
  __builtin_amdgcn_global_load_lds(
      (const __attribute__((address_space(1))) unsigned int*)g,
      (__attribute__((address_space(3))) unsigned int*)l, 16, 0, 0);
}

// ---------------- prep kernels ----------------
__global__ void transpose_all_k(const float* __restrict__ Wq, const float* __restrict__ Wk,
                                const float* __restrict__ Wv, const float* __restrict__ Wo,
                                const float* __restrict__ W1, const float* __restrict__ W2,
                                int l, short* __restrict__ wbf) {
  int id = blockIdx.x;
  const float* in; short* out; int K, N, tx, ty;
  if (id < 1024) {
    int m = id >> 8, t = id & 255;
    in = (m == 0 ? Wq : m == 1 ? Wk : m == 2 ? Wv : Wo) + (size_t)l * 262144;
    out = wbf + (size_t)m * 262144;
    K = 512; N = 512; tx = t & 15; ty = t >> 4;
  } else if (id < 2048) {
    int t = id - 1024;
    in = W1 + (size_t)l * 1048576; out = wbf + 1048576;
    K = 512; N = 2048; tx = t & 63; ty = t >> 6;
  } else {
    int t = id - 2048;
    in = W2 + (size_t)l * 1048576; out = wbf + 2097152;
    K = 2048; N = 512; tx = t & 15; ty = t >> 4;
  }
  __shared__ float tb[32][33];
  int n0 = tx * 32, k0 = ty * 32;
  int cx = threadIdx.x & 31, cy = threadIdx.x >> 5;
#pragma unroll
  for (int r = 0; r < 4; r++)
    tb[cy + r * 8][cx] = in[(size_t)(k0 + cy + r * 8) * N + n0 + cx];
  __syncthreads();
#pragma unroll
  for (int r = 0; r < 4; r++)
    out[(size_t)(n0 + cy + r * 8) * K + k0 + cx] = f2bf(tb[cx][cy + r * 8]);
}

// f32 -> bf16 copy of attn_bias, folding log2(e) for the exp2 softmax
__global__ void bias_cvt_k(const float* __restrict__ in, short* __restrict__ out) {
  int i = blockIdx.x * 256 + threadIdx.x;  // float4 index; grid covers 8M floats
  float4 v = ((const float4*)in)[i];
  ushort4 o;
  o.x = (unsigned short)f2bf(v.x * LOG2E);
  o.y = (unsigned short)f2bf(v.y * LOG2E);
  o.z = (unsigned short)f2bf(v.z * LOG2E);
  o.w = (unsigned short)f2bf(v.w * LOG2E);
  ((ushort4*)out)[i] = o;
}

__global__ void hwt_k(const float* __restrict__ hW, short* __restrict__ hWT) {
  int i = blockIdx.x * 256 + threadIdx.x;
  int n = i >> 9, k = i & 511;
  hWT[i] = (n < 24) ? f2bf(hW[(size_t)k * 24 + n]) : (short)0;
}

__global__ void concat_qkvb_k(const float* bq, const float* bk, const float* bv, float* out) {
  int l = blockIdx.x;
  for (int i = threadIdx.x; i < 1536; i += 256) {
    float v = (i < 512) ? bq[l * 512 + i] * Q_SCALE  // fold 1/sqrt(HD)*log2e into q bias
            : (i < 1024 ? bk[l * 512 + i - 512] : bv[l * 512 + i - 1024]);
    out[l * 1536 + i] = v;
  }
}

__global__ void cond_proj_k(const float* __restrict__ cond,
                            const float* __restrict__ a1W, const float* __restrict__ a1b,
                            const float* __restrict__ a2W, const float* __restrict__ a2b,
                            float* __restrict__ ss) {
  int lw = blockIdx.y, which = lw & 1, l = lw >> 1;
  const float* W = (which ? a2W : a1W) + (size_t)l * 128 * 1024;
  const float* bb = (which ? a2b : a1b) + (size_t)l * 1024;
  __shared__ float cs[32 * 128];
  for (int i = threadIdx.x; i < 32 * 128; i += 256) cs[i] = cond[i];
  __syncthreads();
  int n = blockIdx.x * 256 + threadIdx.x;
  float bias = bb[n];
  for (int g = 0; g < 4; g++) {
    float acc[8];
#pragma unroll
    for (int i = 0; i < 8; i++) acc[i] = 0.f;
    for (int c = 0; c < 128; c++) {
      float w = W[(size_t)c * 1024 + n];
#pragma unroll
      for (int i = 0; i < 8; i++) acc[i] += cs[(g * 8 + i) * 128 + c] * w;
    }
#pragma unroll
    for (int i = 0; i < 8; i++)
      ss[((size_t)lw * 32 + g * 8 + i) * 1024 + n] = acc[i] + bias;
  }
}

__global__ void embed_k(const float* __restrict__ theta, const float* __restrict__ eW,
                        const float* __restrict__ eb, float* __restrict__ x) {
  int row = blockIdx.x * 4 + (threadIdx.x >> 6), lane = threadIdx.x & 63;
  float th = theta[row], sn, cn;
  sincosf(th, &sn, &cn);
  int d = lane * 8;
  float* xo = x + (size_t)row * 512 + d;
#pragma unroll
  for (int i = 0; i < 8; i++) xo[i] = cn * eW[d + i] + sn * eW[512 + d + i] + eb[d + i];
}

// AdaLN; optionally folds a deferred bf16 residual delta (may ALIAS h!) and updates xw.
template<bool HASDEL>
__global__ void adaln_k(float* __restrict__ x, const short* delta,
                        const float* __restrict__ ss,
                        const float* __restrict__ g, const float* __restrict__ be,
                        short* h) {
  int row = blockIdx.x * 4 + (threadIdx.x >> 6), lane = threadIdx.x & 63;
  int b = row >> 10;
  float* xr = x + (size_t)row * 512 + lane * 8;
  float4 va = ((const float4*)xr)[0], vb = ((const float4*)xr)[1];
  float v[8] = {va.x, va.y, va.z, va.w, vb.x, vb.y, vb.z, vb.w};
  if (HASDEL) {
    s8v dv = *(const s8v*)(delta + (size_t)row * 512 + lane * 8);
#pragma unroll
    for (int i = 0; i < 8; i++) v[i] += bf2f((unsigned short)dv[i]);
    float4 o0 = {v[0], v[1], v[2], v[3]}, o1 = {v[4], v[5], v[6], v[7]};
    ((float4*)xr)[0] = o0; ((float4*)xr)[1] = o1;
  }
  float sm = 0.f;
#pragma unroll
  for (int i = 0; i < 8; i++) sm += v[i];
#pragma unroll
  for (int off = 1; off < 64; off <<= 1) sm += __shfl_xor(sm, off);
  float mean = sm * (1.f / 512.f);
  float sq = 0.f;
#pragma unroll
  for (int i = 0; i < 8; i++) { float d = v[i] - mean; sq += d * d; }
#pragma unroll
  for (int off = 1; off < 64; off <<= 1) sq += __shfl_xor(sq, off);
  float rs = rsqrtf(sq * (1.f / 512.f) + 1e-5f);
  const float* sb = ss + (size_t)b * 1024 + lane * 8;
  const float* gp = g + lane * 8;
  const float* bp = be + lane * 8;
  s8v o;
#pragma unroll
  for (int i = 0; i < 8; i++) {
    float xh = (v[i] - mean) * rs * gp[i] + bp[i];
    o[i] = f2bf((1.f + sb[i]) * xh + sb[i + 512]);
  }
  *(s8v*)(h + (size_t)row * 512 + lane * 8) = o;
}

// final LN, folding FF2's delta (delta may ALIAS h)
__global__ void fln_k(const float* __restrict__ x, const short* delta,
                      const float* __restrict__ g, const float* __restrict__ be,
                      short* h) {
  int row = blockIdx.x * 4 + (threadIdx.x >> 6), lane = threadIdx.x & 63;
  const float* xr = x + (size_t)row * 512 + lane * 8;
  float4 va = ((const float4*)xr)[0], vb = ((const float4*)xr)[1];
  float v[8] = {va.x, va.y, va.z, va.w, vb.x, vb.y, vb.z, vb.w};
  s8v dv = *(const s8v*)(delta + (size_t)row * 512 + lane * 8);
#pragma unroll
  for (int i = 0; i < 8; i++) v[i] += bf2f((unsigned short)dv[i]);
  float sm = 0.f;
#pragma unroll
  for (int i = 0; i < 8; i++) sm += v[i];
#pragma unroll
  for (int off = 1; off < 64; off <<= 1) sm += __shfl_xor(sm, off);
  float mean = sm * (1.f / 512.f);
  float sq = 0.f;
#pragma unroll
  for (int i = 0; i < 8; i++) { float d = v[i] - mean; sq += d * d; }
#pragma unroll
  for (int off = 1; off < 64; off <<= 1) sq += __shfl_xor(sq, off);
  float rs = rsqrtf(sq * (1.f / 512.f) + 1e-5f);
  const float* gp = g + lane * 8;
  const float* bp = be + lane * 8;
  s8v o;
#pragma unroll
  for (int i = 0; i < 8; i++) o[i] = f2bf((v[i] - mean) * rs * gp[i] + bp[i]);
  *(s8v*)(h + (size_t)row * 512 + lane * 8) = o;
}

// --- GEMM 128x256, BK=32, ring-3, 512 thr (8 waves 2Mx4N), 72KB LDS ---
// (FF1 / Wo / FF2 / qk_proj.) 32 MFMAs per barrier-pair, staging bytes/FLOP
// -25% vs 128x128, 2 blk/CU = 16 waves/CU, grids sized for exact residency.
// EPI 0: bf16 (+bias); 1: gelu bf16 (exp2-folded + v_rcp);
// EPI 2: qk epilogue - block-uniform scale (Q_SCALE if n0<512) then +bias.
template<int EPI>
__global__ __launch_bounds__(512, 2) void gemm_w_k(const short* __restrict__ A,
                                                   const short* __restrict__ BT,
                                                   const float* __restrict__ bias,
                                                   short* __restrict__ outb,
                                                   int N, int K) {
  __shared__ __align__(16) short lsA[3][4096];  // 3 x 8KB  (128 rows)
  __shared__ __align__(16) short lsB[3][8192];  // 3 x 16KB (256 rows)
  int tid = threadIdx.x, lane = tid & 63, w = tid >> 6;  // w in [0,8)
  int wm = w >> 2, wn = w & 3;                            // 2M x 4N waves
  int l15 = lane & 15, l4 = lane >> 4;
  int lrow = lane >> 2, lchunk = lane & 3;
  int poff = ((l15 << 2) + (l4 ^ ((l15 >> 1) & 3))) << 3;
  int nb = N >> 8;                                        // 256-wide N tiles
  int bid = blockIdx.x;
  int xcd = bid & 7, rr = bid >> 3;
  int mloc = rr / nb, nidx = rr - mloc * nb;
  int m0 = (xcd * 32 + mloc) << 7, n0 = nidx << 8;

  f4v z4 = {0.f, 0.f, 0.f, 0.f};
  f4v acc[4][4];
#pragma unroll
  for (int i = 0; i < 4; i++)
#pragma unroll
    for (int j = 0; j < 4; j++) acc[i][j] = z4;

  int co = (lchunk ^ ((lrow >> 1) & 3)) << 3;

  auto STAGE = [&](int t) {  // 3 DMA ops per thread; 384 rows total
    int slot = t % 3;
    int ko = t << 5;
#pragma unroll
    for (int tt = 0; tt < 3; tt++) {
      int r0 = w * 48 + tt * 16;          // wave-uniform; 0..368 step 16
      int row = r0 + lrow;
      if (r0 < 128) {                      // A rows [0,128)
        gl_lds16(A + (size_t)(m0 + row) * K + ko + co, lsA[slot] + r0 * 32);
      } else {                             // B rows [0,256)
        int rb = row - 128;
        gl_lds16(BT + (size_t)(n0 + rb) * K + ko + co, lsB[slot] + (r0 - 128) * 32);
      }
    }
  };
  auto LOADF = [&](int t, s8v* af, s8v* bfr) {
    int slot = t % 3;
    const short* At = lsA[slot] + (wm * 4) * 512 + poff;
    const short* Bt = lsB[slot] + (wn * 4) * 512 + poff;
#pragma unroll
    for (int i = 0; i < 4; i++) {
      af[i] = *(const s8v*)(At + i * 512);
      bfr[i] = *(const s8v*)(Bt + i * 512);
    }
  };

  int NT = K >> 5;
  STAGE(0); STAGE(1);
  asm volatile("s_waitcnt vmcnt(3)" ::: "memory");  // tile 0 landed
  __builtin_amdgcn_s_barrier();
  s8v af[4], bfr[4];
  LOADF(0, af, bfr);
  for (int t = 0; t < NT; ++t) {
    if (t + 2 < NT) STAGE(t + 2);
    __builtin_amdgcn_sched_barrier(0);   // pin VMEM issue before the MFMA burst
#pragma unroll
    for (int i = 0; i < 4; i++)
#pragma unroll
      for (int j = 0; j < 4; j++)
        acc[i][j] = __builtin_amdgcn_mfma_f32_16x16x32_bf16(af[i], bfr[j], acc[i][j], 0, 0, 0);
    if (t + 1 < NT) {
      if (t + 2 < NT) asm volatile("s_waitcnt vmcnt(3)" ::: "memory");  // t+1 landed
      else            asm volatile("s_waitcnt vmcnt(0)" ::: "memory");  // tail
      __builtin_amdgcn_s_barrier();
      LOADF(t + 1, af, bfr);   // frags for next iter; latency covered by backedge
    }
  }
  float scl = (EPI == 2) ? ((n0 < 512) ? Q_SCALE : 1.f) : 1.f;
#pragma unroll
  for (int i = 0; i < 4; i++) {
    int gr0 = m0 + wm * 64 + i * 16 + l4 * 4;
#pragma unroll
    for (int j = 0; j < 4; j++) {
      int gc = n0 + wn * 64 + j * 16 + l15;
      float bv = bias[gc];
#pragma unroll
      for (int r = 0; r < 4; r++) {
        float v;
        if (EPI == 2) {
          v = acc[i][j][r] * scl + bv;
        } else {
          v = acc[i][j][r] + bv;
          if (EPI == 1) {
            // sigmoid-gelu with log2e prefolded: v * sigmoid(1.5958v + 0.07135v^3)
            float tg = v * (-2.3022083f - 0.10294325f * v * v);
            v = v * frcp(1.f + fexp2(tg));
          }
        }
        outb[(size_t)(gr0 + r) * N + gc] = f2bf(v);
      }
    }
  }
}

// --- V projection: ring-3 128x128, operand-swapped MFMA -> V^T scatter. grid 1024. ---
__global__ __launch_bounds__(256, 3) void v_proj_k(const short* __restrict__ A,
                                                   const short* __restrict__ BT,
                                                   const float* __restrict__ bias,
                                                   short* __restrict__ vtb) {
  __shared__ __align__(16) short lsA[3][4096];
  __shared__ __align__(16) short lsB[3][4096];
  int tid = threadIdx.x, lane = tid & 63, w = tid >> 6;
  int wm = w >> 1, wn = w & 1;
  int l15 = lane & 15, l4 = lane >> 4;
  int lrow = lane >> 2, lchunk = lane & 3;
  int poff = ((l15 << 2) + (l4 ^ ((l15 >> 1) & 3))) << 3;
  int bid = blockIdx.x;
  int xcd = bid & 7, rr = bid >> 3;
  int mloc = rr >> 2, nidx = rr & 3;
  int m0 = (xcd * 32 + mloc) << 7, n0 = 1024 + (nidx << 7);

  f4v z4 = {0.f, 0.f, 0.f, 0.f};
  f4v acc[4][4];
#pragma unroll
  for (int i = 0; i < 4; i++)
#pragma unroll
    for (int j = 0; j < 4; j++) acc[i][j] = z4;

  int co = (lchunk ^ ((lrow >> 1) & 3)) << 3;

  auto STAGE = [&](int t) {
    int slot = t % 3;
    int ko = t << 5;
#pragma unroll
    for (int tt = 0; tt < 2; tt++) {
      int r0 = w * 32 + tt * 16;
      int row = r0 + lrow;
      gl_lds16(A + (size_t)(m0 + row) * 512 + ko + co, lsA[slot] + r0 * 32);
      gl_lds16(BT + (size_t)(n0 + row) * 512 + ko + co, lsB[slot] + r0 * 32);
    }
  };
  auto LOADF = [&](int t, s8v* af, s8v* bfr) {
    int slot = t % 3;
    const short* At = lsA[slot] + (wm * 4) * 512 + poff;
    const short* Bt = lsB[slot] + (wn * 4) * 512 + poff;
#pragma unroll
    for (int i = 0; i < 4; i++) {
      af[i] = *(const s8v*)(At + i * 512);
      bfr[i] = *(const s8v*)(Bt + i * 512);
    }
  };

  const int NT = 16;
  STAGE(0); STAGE(1);
  asm volatile("s_waitcnt vmcnt(4)" ::: "memory");
  __builtin_amdgcn_s_barrier();
  s8v af[4], bfr[4];
  LOADF(0, af, bfr);
  for (int t = 0; t < NT; ++t) {
    if (t + 2 < NT) STAGE(t + 2);
    __builtin_amdgcn_sched_barrier(0);
#pragma unroll
    for (int j = 0; j < 4; j++)
#pragma unroll
      for (int i = 0; i < 4; i++)
        acc[j][i] = __builtin_amdgcn_mfma_f32_16x16x32_bf16(bfr[j], af[i], acc[j][i], 0, 0, 0);
    if (t + 1 < NT) {
      if (t + 2 < NT) asm volatile("s_waitcnt vmcnt(4)" ::: "memory");
      else            asm volatile("s_waitcnt vmcnt(0)" ::: "memory");
      __builtin_amdgcn_s_barrier();
      LOADF(t + 1, af, bfr);
    }
  }
  int b = m0 >> 10, s0 = m0 & 1023;
#pragma unroll
  for (int j = 0; j < 4; j++) {
    int col = n0 + wn * 64 + j * 16 + l4 * 4;
#pragma unroll
    for (int i = 0; i < 4; i++) {
      int scol = s0 + wm * 64 + i * 16 + l15;
#pragma unroll
      for (int r = 0; r < 4; r++) {
        float v = acc[j][i][r] + bias[col + r];
        vtb[((size_t)b * 512 + col - 1024 + r) * 1024 + scol] = f2bf(v);
      }
    }
  }
}

// ---------------- flash attention (QBLK=256, 8 waves, no-max exp2 softmax) ----------------
// Swapped QK^T: s^T = mfma(K, Q, bias); P transposed back in registers via
// cvt_pk_bf16 + permlane{32,16}_swap. K/V double-buffered, counted vmcnt(2).
// 8 waves = 2 halves (h2) x 4 waves; each wave keeps the r17 per-wave layout
// (2 g-groups x 16 q-rows). Causal skip on 64-row blocks qb = qt*4 + h2*2 + g.
// q & bias pre-scaled by log2e -> softmax uses raw v_exp_f32 (2^x).
__global__ __launch_bounds__(512, 4) void attn_k(const short* __restrict__ qk,
                                                 const short* __restrict__ vt,
                                                 const short* __restrict__ biasNT,
                                                 short* __restrict__ ao) {
  __shared__ __align__(16) short Kl[2][64 * 64];
  __shared__ __align__(16) short Vl[2][64 * 64];
  int tid = threadIdx.x, lane = tid & 63, w = tid >> 6;  // w in [0,8)
  int h2 = w >> 2, wl = w & 3;
  int bid = blockIdx.x;
  int qt = 3 - (bid >> 8), b = (bid >> 3) & 31, h = bid & 7;  // LPT: qt=3 first
  int l15 = lane & 15, l4 = lane >> 4;
  int lrow = lane >> 3, lchunk = lane & 7;

  f4v z4 = {0.f, 0.f, 0.f, 0.f};
  s8v qf[2][2];
#pragma unroll
  for (int g = 0; g < 2; g++) {
    const short* qp = qk + (size_t)(b * 1024 + qt * 256 + h2 * 128 + g * 64 + wl * 16 + l15) * 1024 + h * 64;
    qf[g][0] = *(const s8v*)(qp + l4 * 8);
    qf[g][1] = *(const s8v*)(qp + 32 + l4 * 8);
  }
  f4v o[2][4], lac[2];
#pragma unroll
  for (int g = 0; g < 2; g++) {
    lac[g] = z4;
#pragma unroll
    for (int j = 0; j < 4; j++) o[g][j] = z4;
  }
  s8v ones;
#pragma unroll
  for (int e = 0; e < 8; e++) ones[e] = (short)0x3F80;

  auto STAGE = [&](int buf, int kt) {  // 8 waves x 8 rows; 2 DMA ops per thread
    int r0 = w * 8;
    int row = r0 + lrow;
    gl_lds16(qk + (size_t)(b * 1024 + kt * 64 + row) * 1024 + 512 + h * 64 +
                 ((lchunk ^ (row & 7)) << 3),
             &Kl[buf][r0 * 64]);
    gl_lds16(vt + (size_t)(b * 512 + h * 64 + row) * 1024 + kt * 64 +
                 ((lchunk ^ (row & 7)) << 3),
             &Vl[buf][r0 * 64]);
  };

  int nkt = 4 * qt + 4;
  STAGE(0, 0);
  for (int kt = 0; kt < nkt; kt++) {
    int cur = kt & 1;
    ushort4 bh[2][4];
#pragma unroll
    for (int g = 0; g < 2; g++) {
      if (kt > qt * 4 + h2 * 2 + g) continue;
      const short* bp = biasNT + ((size_t)h * 1024 + qt * 256 + h2 * 128 + g * 64 + wl * 16 + l15) * 1024 +
                        kt * 64 + l4 * 4;
#pragma unroll
      for (int j = 0; j < 4; j++) bh[g][j] = *(const ushort4*)(bp + j * 16);
    }
    __builtin_amdgcn_sched_barrier(0);  // keep bias loads ahead of the staging DMA
    if (kt + 1 < nkt) {
      STAGE(cur ^ 1, kt + 1);
      asm volatile("s_waitcnt vmcnt(2)" ::: "memory");
    } else {
      asm volatile("s_waitcnt vmcnt(0)" ::: "memory");
    }
    __builtin_amdgcn_s_barrier();
    const short* Kc = &Kl[cur][0];
    const short* Vc = &Vl[cur][0];
#pragma unroll
    for (int g = 0; g < 2; g++) {
      int diag = qt * 4 + h2 * 2 + g;
      if (kt > diag) continue;
      f4v s[4];
#pragma unroll
      for (int j = 0; j < 4; j++) {
        f4v bc;
        bc[0] = bf2f(bh[g][j].x); bc[1] = bf2f(bh[g][j].y);
        bc[2] = bf2f(bh[g][j].z); bc[3] = bf2f(bh[g][j].w);
        int kr = j * 16 + l15;
        s8v kf0 = *(const s8v*)(Kc + kr * 64 + ((l4 ^ (kr & 7)) << 3));
        s8v kf1 = *(const s8v*)(Kc + kr * 64 + (((l4 + 4) ^ (kr & 7)) << 3));
        s[j] = __builtin_amdgcn_mfma_f32_16x16x32_bf16(kf0, qf[g][0], bc, 0, 0, 0);
        s[j] = __builtin_amdgcn_mfma_f32_16x16x32_bf16(kf1, qf[g][1], s[j], 0, 0, 0);
      }
      if (kt == diag) {
#pragma unroll
        for (int j = 0; j < 4; j++)
#pragma unroll
          for (int r = 0; r < 4; r++) {
            int kk = j * 16 + l4 * 4 + r, qq = wl * 16 + l15;
            s[j][r] = (kk > qq) ? 0.f : fexp2(s[j][r]);
          }
      } else {
#pragma unroll
        for (int j = 0; j < 4; j++)
#pragma unroll
          for (int r = 0; r < 4; r++) s[j][r] = fexp2(s[j][r]);
      }
      unsigned X0[4], X1[4];
#pragma unroll
      for (int j = 0; j < 4; j++) {
        X0[j] = cvtpk(s[j][0], s[j][1]);
        X1[j] = cvtpk(s[j][2], s[j][3]);
      }
      u2v a0 = __builtin_amdgcn_permlane32_swap(X0[0], X0[1], false, false);
      u2v a1 = __builtin_amdgcn_permlane16_swap(a0[0], a0[1], false, false);
      u2v b0 = __builtin_amdgcn_permlane32_swap(X1[0], X1[1], false, false);
      u2v b1 = __builtin_amdgcn_permlane16_swap(b0[0], b0[1], false, false);
      u2v c0 = __builtin_amdgcn_permlane32_swap(X0[2], X0[3], false, false);
      u2v c1 = __builtin_amdgcn_permlane16_swap(c0[0], c0[1], false, false);
      u2v d0 = __builtin_amdgcn_permlane32_swap(X1[2], X1[3], false, false);
      u2v d1 = __builtin_amdgcn_permlane16_swap(d0[0], d0[1], false, false);
      u4v P0 = {a1[0], b1[0], a1[1], b1[1]};  // k 0..31
      u4v P1 = {c1[0], d1[0], c1[1], d1[1]};  // k 32..63
      s8v pf0 = __builtin_bit_cast(s8v, P0);
      s8v pf1 = __builtin_bit_cast(s8v, P1);
      lac[g] = __builtin_amdgcn_mfma_f32_16x16x32_bf16(pf0, ones, lac[g], 0, 0, 0);
      lac[g] = __builtin_amdgcn_mfma_f32_16x16x32_bf16(pf1, ones, lac[g], 0, 0, 0);
#pragma unroll
      for (int j = 0; j < 4; j++) {
        int dr = j * 16 + l15;
        s8v vf0 = *(const s8v*)(Vc + dr * 64 + ((l4 ^ (dr & 7)) << 3));
        s8v vf1 = *(const s8v*)(Vc + dr * 64 + (((l4 + 4) ^ (dr & 7)) << 3));
        o[g][j] = __builtin_amdgcn_mfma_f32_16x16x32_bf16(pf0, vf0, o[g][j], 0, 0, 0);
        o[g][j] = __builtin_amdgcn_mfma_f32_16x16x32_bf16(pf1, vf1, o[g][j], 0, 0, 0);
      }
    }
    __builtin_amdgcn_s_barrier();
  }
#pragma unroll
  for (int g = 0; g < 2; g++)
#pragma unroll
    for (int r = 0; r < 4; r++) {
      float rl = frcp(lac[g][r]);
      int qr = qt * 256 + h2 * 128 + g * 64 + wl * 16 + l4 * 4 + r;
#pragma unroll
      for (int j = 0; j < 4; j++) {
        int d = j * 16 + l15;
        ao[(size_t)(b * 1024 + qr) * 512 + h * 64 + d] = f2bf(o[g][j][r] * rl);
      }
    }
}

// ---------------- head GEMM ----------------
__global__ __launch_bounds__(256) void head_k(const short* __restrict__ X,
                                              const short* __restrict__ hWT,
                                              const float* __restrict__ hb,
                                              float* __restrict__ out) {
  __shared__ __align__(16) short lA[128 * 64];
  int tid = threadIdx.x, lane = tid & 63, w = tid >> 6;
  int l15 = lane & 15, l4 = lane >> 4;
  int lrow = lane >> 3, lchunk = lane & 7;
  int m0 = blockIdx.x * 128;
  f4v z4 = {0.f, 0.f, 0.f, 0.f};
  f4v acc[2][2];
#pragma unroll
  for (int i = 0; i < 2; i++)
#pragma unroll
    for (int j = 0; j < 2; j++) acc[i][j] = z4;

  for (int k0 = 0; k0 < 512; k0 += 64) {
#pragma unroll
    for (int t = 0; t < 4; t++) {
      int r0 = (w * 4 + t) * 8;
      int row = r0 + lrow;
      gl_lds16(X + (size_t)(m0 + row) * 512 + k0 + ((lchunk ^ (row & 7)) << 3), lA + r0 * 64);
    }
    __syncthreads();
#pragma unroll
    for (int kk = 0; kk < 2; kk++) {
      s8v af[2], bfr[2];
#pragma unroll
      for (int i = 0; i < 2; i++) {
        int ra = w * 32 + i * 16 + l15;
        af[i] = *(const s8v*)(lA + ra * 64 + (((l4 + kk * 4) ^ (ra & 7)) << 3));
      }
#pragma unroll
      for (int j = 0; j < 2; j++)
        bfr[j] = *(const s8v*)(hWT + (size_t)(j * 16 + l15) * 512 + k0 + kk * 32 + l4 * 8);
#pragma unroll
      for (int i = 0; i < 2; i++)
#pragma unroll
        for (int j = 0; j < 2; j++)
          acc[i][j] = __builtin_amdgcn_mfma_f32_16x16x32_bf16(af[i], bfr[j], acc[i][j], 0, 0, 0);
    }
    __syncthreads();
  }
#pragma unroll
  for (int i = 0; i < 2; i++) {
#pragma unroll
    for (int j = 0; j < 2; j++) {
      int col = j * 16 + l15;
      if (col < 24) {
        float bv = hb[col];
#pragma unroll
        for (int r = 0; r < 4; r++) {
          int row = m0 + w * 32 + i * 16 + l4 * 4 + r;
          out[(size_t)row * 24 + col] = acc[i][j][r] + bv;
        }
      }
    }
  }
}

// ---------------- launch ----------------
extern "C" void kernel_launch(void* const* d_in, const int* in_sizes, int n_in,
                              void* d_out, int out_size, void* d_ws, size_t ws_size,
                              hipStream_t stream) {
  (void)in_sizes; (void)n_in; (void)out_size;
  const float* theta   = (const float*)d_in[0];
  const float* cond    = (const float*)d_in[1];
  const float* attn_b  = (const float*)d_in[2];
  const float* embed_W = (const float*)d_in[3];
  const float* embed_b = (const float*)d_in[4];
  const float* ln1_g   = (const float*)d_in[5];
  const float* ln1_b   = (const float*)d_in[6];
  const float* ada1_W  = (const float*)d_in[7];
  const float* ada1_b  = (const float*)d_in[8];
  const float* Wq      = (const float*)d_in[9];
  const float* bq      = (const float*)d_in[10];
  const float* Wk      = (const float*)d_in[11];
  const float* bk      = (const float*)d_in[12];
  const float* Wv      = (const float*)d_in[13];
  const float* bv      = (const float*)d_in[14];
  const float* Wo      = (const float*)d_in[15];
  const float* bo      = (const float*)d_in[16];
  const float* ln2_g   = (const float*)d_in[17];
  const float* ln2_b   = (const float*)d_in[18];
  const float* ada2_W  = (const float*)d_in[19];
  const float* ada2_b  = (const float*)d_in[20];
  const float* W1      = (const float*)d_in[21];
  const float* b1      = (const float*)d_in[22];
  const float* W2      = (const float*)d_in[23];
  const float* b2      = (const float*)d_in[24];
  const float* fn_g    = (const float*)d_in[25];
  const float* fn_b    = (const float*)d_in[26];
  const float* head_W  = (const float*)d_in[27];
  const float* head_b  = (const float*)d_in[28];

  const size_t REQ = 242814976ull;
  const size_t REQ2 = 259592192ull;
  if (ws_size < REQ) return;
  bool bias_once = (ws_size >= REQ2);

  char* ws = (char*)d_ws;
  float* xw    = (float*)(ws + 0ull);
  short* qk    = (short*)(ws + 67108864ull);
  short* vtb   = (short*)(ws + 134217728ull);   // V^T, then Wo-delta
  short* biasT = (short*)(ws + (bias_once ? 242814976ull : 167772160ull));
  short* qf    = (short*)(ws + 67108864ull);
  short* hbuf  = (short*)(ws + 201326592ull);   // adaln out / attn out / FF2 delta
  short* wbf   = (short*)(ws + 234881024ull);
  float* ssb   = (float*)(ws + 241172480ull);
  float* bqkv  = (float*)(ws + 242745344ull);
  short* hWT   = (short*)(ws + 242782208ull);

  concat_qkvb_k<<<6, 256, 0, stream>>>(bq, bk, bv, bqkv);
  cond_proj_k<<<dim3(4, 12), 256, 0, stream>>>(cond, ada1_W, ada1_b, ada2_W, ada2_b, ssb);
  hwt_k<<<64, 256, 0, stream>>>(head_W, hWT);
  embed_k<<<8192, 256, 0, stream>>>(theta, embed_W, embed_b, xw);
  if (bias_once) bias_cvt_k<<<8192, 256, 0, stream>>>(attn_b, biasT);

  for (int l = 0; l < 6; l++) {
    transpose_all_k<<<3072, 256, 0, stream>>>(Wq, Wk, Wv, Wo, W1, W2, l, wbf);
    if (!bias_once) bias_cvt_k<<<8192, 256, 0, stream>>>(attn_b, biasT);

    if (l == 0)
      adaln_k<false><<<8192, 256, 0, stream>>>(xw, nullptr, ssb + (size_t)(l * 2) * 32768,
                                               ln1_g + l * 512, ln1_b + l * 512, hbuf);
    else  // delta = FF2 delta from layer l-1, lives in hbuf; h also hbuf (safe)
      adaln_k<true><<<8192, 256, 0, stream>>>(xw, hbuf, ssb + (size_t)(l * 2) * 32768,
                                              ln1_g + l * 512, ln1_b + l * 512, hbuf);
    // QK projection: 128x256 template, grid 1024, EPI=2 (block-uniform Q scale)
    gemm_w_k<2><<<1024, 512, 0, stream>>>(hbuf, wbf, bqkv + l * 1536, qk, 1024, 512);
    v_proj_k<<<1024, 256, 0, stream>>>(hbuf, wbf, bqkv + l * 1536, vtb);
    // attn: QBLK=256, 8 waves, grid 1024
    attn_k<<<1024, 512, 0, stream>>>(qk, vtb, biasT, hbuf);
    // Wo: 128x256 template, grid 512; delta -> vtb, folded IMMEDIATELY by adaln2
    gemm_w_k<0><<<512, 512, 0, stream>>>(hbuf, wbf + 786432, bo + l * 512, vtb, 512, 512);
    adaln_k<true><<<8192, 256, 0, stream>>>(xw, vtb, ssb + (size_t)(l * 2 + 1) * 32768,
                                            ln2_g + l * 512, ln2_b + l * 512, hbuf);
    // FF1: 128x256 template, grid 2048 (exp2-gelu epilogue)
    gemm_w_k<1><<<2048, 512, 0, stream>>>(hbuf, wbf + 1048576, b1 + l * 2048, qf, 2048, 512);
    // FF2: 128x256 template, grid 512; delta -> hbuf (disjoint from qf)
    gemm_w_k<0><<<512, 512, 0, stream>>>(qf, wbf + 2097152, b2 + l * 512, hbuf, 512, 2048);
  }
  fln_k<<<8192, 256, 0, stream>>>(xw, hbuf, fn_g, fn_b, hbuf);
  head_k<<<256, 256, 0, stream>>>(hbuf, hWT, head_b, (float*)d_out);
}